// Round 4
// baseline (1155.104 us; speedup 1.0000x reference)
//
#include <hip/hip_runtime.h>
#include <hip/hip_bf16.h>

// Problem constants
#define NBL 6      // B*LEN
#define NC 64
#define NC3 192
#define NHW 4096   // 64*64
#define NDI 128
#define NNS 16
#define NDR 4
#define NK 4
#define NL 4096
#define NCH 64     // scan chunks
#define SCLEN 64   // chunk length
#define NSTATE 49152  // 24 bk * 128 d * 16 n

// workspace offsets in floats
static const size_t F_XCAT  = 0;          // 6*192*4096 = 4,718,592
static const size_t F_ACT1  = 4718592;    // 4,718,592
static const size_t F_H1    = 9437184;    // 1,572,864
static const size_t F_ACT2  = 11010048;   // 1,572,864
static const size_t F_H2    = 12582912;   // 1,572,864
static const size_t F_XRES  = 14155776;   // 1,572,864
static const size_t F_XXIN  = 15728640;   // 3,145,728  (dead after dwconv -> chunkP)
static const size_t F_Z     = 18874368;   // 3,145,728
static const size_t F_XXC   = 22020096;   // 3,145,728
static const size_t F_XDBL  = 25165824;   // 6*4*36*4096 = 3,538,944
static const size_t F_YS    = 28704768;   // 12,582,912 (stats partials + conv partials early, ys later)
static const size_t F_YCOMB = 41287680;   // 3,145,728  (chunkH during scan)
static const size_t F_X1    = 44433408;   // 1,572,864  (X1+X2 -> chunkHS during scan)
static const size_t F_X2    = 46006272;   // 1,572,864
static const size_t F_STATS = 47579136;   // 48
static const size_t F_TOTAL = 47579184;   // floats (~190.3 MB)

__device__ __forceinline__ float wred64(float v) {
#pragma unroll
  for (int m = 32; m; m >>= 1) v += __shfl_xor(v, m, 64);
  return v;
}

__device__ __forceinline__ float silu(float v) {
  return v / (1.f + __expf(-v));
}

__device__ __forceinline__ int map_pos(int k, int l) {
  // k0: hw order, k1: wh order, k2: hw reversed, k3: wh reversed
  if (k == 0) return l;
  if (k == 1) return ((l & 63) << 6) | (l >> 6);
  if (k == 2) return 4095 - l;
  int lp = 4095 - l;
  return ((lp & 63) << 6) | (lp >> 6);
}

// ---- two-stage per-sample mean/rstd (f64 accumulate) ----
__global__ __launch_bounds__(256) void stats1_kernel(const float* __restrict__ in, int n,
                                                     double* __restrict__ part) {
  int bi = blockIdx.x;
  int s = bi >> 5, j = bi & 31;
  int slice = n >> 5;
  const float4* p = (const float4*)(in + (size_t)s * n + (size_t)j * slice);
  int n4 = slice >> 2;
  double dsum = 0.0, dsq = 0.0;
  for (int i = threadIdx.x; i < n4; i += 256) {
    float4 v = p[i];
    dsum += (double)((v.x + v.y) + (v.z + v.w));
    dsq += (double)v.x * v.x + (double)v.y * v.y + (double)v.z * v.z + (double)v.w * v.w;
  }
  __shared__ double s1[256], s2[256];
  s1[threadIdx.x] = dsum; s2[threadIdx.x] = dsq;
  __syncthreads();
  for (int off = 128; off; off >>= 1) {
    if (threadIdx.x < off) { s1[threadIdx.x] += s1[threadIdx.x + off]; s2[threadIdx.x] += s2[threadIdx.x + off]; }
    __syncthreads();
  }
  if (threadIdx.x == 0) { part[2 * bi] = s1[0]; part[2 * bi + 1] = s2[0]; }
}

__global__ __launch_bounds__(64) void stats2_kernel(const double* __restrict__ part, int n,
                                                    float* __restrict__ mean_out,
                                                    float* __restrict__ rstd_out) {
  int s = blockIdx.x;
  int lane = threadIdx.x;
  double sum = 0.0, sq = 0.0;
  if (lane < 32) { sum = part[2 * (s * 32 + lane)]; sq = part[2 * (s * 32 + lane) + 1]; }
#pragma unroll
  for (int m = 16; m; m >>= 1) { sum += __shfl_xor(sum, m, 64); sq += __shfl_xor(sq, m, 64); }
  if (lane == 0) {
    double mean = sum / n;
    double var = sq / n - mean * mean;
    mean_out[s] = (float)mean;
    rstd_out[s] = (float)(1.0 / sqrt(var + 1e-5));
  }
}

// x_cat[bl][ch][p]: ch<64 dz, 64..127 instance-normed img, 128..191 sigma
__global__ __launch_bounds__(256) void build_xcat_kernel(const float* __restrict__ img,
                                                         const float* __restrict__ dz,
                                                         const float* __restrict__ sg,
                                                         const float* __restrict__ stats,
                                                         float* __restrict__ xcat) {
  size_t gid = (size_t)blockIdx.x * 256 + threadIdx.x;  // 6*192*4096 total
  int p = gid & 4095;
  size_t r = gid >> 12;
  int ch = (int)(r % NC3);
  int bl = (int)(r / NC3);
  int b = bl / 3;  // LEN=3
  float v;
  if (ch < 64) {
    v = dz[((size_t)b * NC + ch) * NHW + p];
  } else if (ch < 128) {
    float m = stats[bl], rs = stats[8 + bl];
    v = (img[((size_t)bl * NC + (ch - 64)) * NHW + p] - m) * rs;
  } else {
    v = sg[((size_t)b * NC + (ch - 128)) * NHW + p];
  }
  xcat[gid] = v;
}

// out = silu((in - mean)*rstd*g[ch] + b[ch]), NCHW flat
template <int CCH>
__global__ __launch_bounds__(256) void gn_silu_kernel(const float* __restrict__ in,
                                                      const float* __restrict__ g,
                                                      const float* __restrict__ b,
                                                      const float* __restrict__ stats,
                                                      float* __restrict__ out) {
  size_t gid = (size_t)blockIdx.x * 256 + threadIdx.x;
  size_t r = gid >> 12;
  int ch = (int)(r % CCH);
  int bl = (int)(r / CCH);
  float m = stats[bl], rs = stats[8 + bl];
  float v = (in[gid] - m) * rs * g[ch] + b[ch];
  out[gid] = silu(v);
}

// 3x3 SAME conv partial: ic slice of 32, oc half of 32.
// grid bi = ((bl*64 + h)*2 + och)*S + ics ; block 256 = 32 oc x 8 wgroups(8 w)
// part[ics][bl][oc(64)][p] — fp32 partial sums (no bias)
__global__ __launch_bounds__(256) void conv3x3_part_kernel(const float* __restrict__ in,
                                                           const float* __restrict__ wgt,
                                                           float* __restrict__ part,
                                                           int Cin, int S) {
  int bi = blockIdx.x;
  int ics = bi % S; bi /= S;
  int och = bi & 1; bi >>= 1;
  int h = bi & 63, bl = bi >> 6;
  const int t = threadIdx.x;
  const int oc = (och << 5) + (t & 31);
  const int w0 = (t >> 5) << 3;
  __shared__ float lds[3][32][66];
  float acc[8];
#pragma unroll
  for (int i = 0; i < 8; ++i) acc[i] = 0.f;
  // stage 3 rows x 32 ch x 64 w
  for (int idx = t; idx < 3 * 32 * 64; idx += 256) {
    int r = idx >> 11;
    int rem = idx & 2047;
    int ch = rem >> 6, w = rem & 63;
    int hh = h + r - 1;
    float v = 0.f;
    if (hh >= 0 && hh < 64)
      v = in[(((size_t)bl * Cin + (ics << 5) + ch) << 12) + (hh << 6) + w];
    lds[r][ch][w + 1] = v;
  }
  if (t < 96) { int r = t / 32, ch = t % 32; lds[r][ch][0] = 0.f; lds[r][ch][65] = 0.f; }
  __syncthreads();
  for (int ch = 0; ch < 32; ++ch) {
    const float* wp = wgt + ((size_t)oc * Cin + (ics << 5) + ch) * 9;
    float wv[9];
#pragma unroll
    for (int j = 0; j < 9; ++j) wv[j] = wp[j];
#pragma unroll
    for (int r = 0; r < 3; ++r) {
      float xv[10];
#pragma unroll
      for (int j = 0; j < 10; ++j) xv[j] = lds[r][ch][w0 + j];
#pragma unroll
      for (int i = 0; i < 8; ++i)
        acc[i] += wv[r * 3 + 0] * xv[i] + wv[r * 3 + 1] * xv[i + 1] + wv[r * 3 + 2] * xv[i + 2];
    }
  }
  size_t ob = ((((size_t)ics * NBL + bl) * 64 + oc) << 12) + (h << 6) + w0;
#pragma unroll
  for (int i = 0; i < 8; ++i) part[ob + i] = acc[i];
}

// out[bl][oc][p] = sum_s part[s][bl][oc][p] + bias[oc]
__global__ __launch_bounds__(256) void conv_reduce_kernel(const float* __restrict__ part,
                                                          const float* __restrict__ bias,
                                                          float* __restrict__ out, int S) {
  size_t gid = (size_t)blockIdx.x * 256 + threadIdx.x;  // 6*64*4096
  int p = (int)(gid & 4095);
  size_t r = gid >> 12;
  int oc = (int)(r & 63);
  size_t blr = r >> 6;
  float acc = bias[oc];
  for (int s = 0; s < S; ++s)
    acc += part[((((size_t)s * NBL + blr) * 64 + oc) << 12) + p];
  out[gid] = acc;
}

// x_res[bl][p][oc] = h2[bl][oc][p] + 1x1skip(xcat)[oc] + skb[oc]   (NHWC out)
__global__ __launch_bounds__(256) void skip_kernel(const float* __restrict__ xcat,
                                                   const float* __restrict__ h2,
                                                   const float* __restrict__ skw,
                                                   const float* __restrict__ skb,
                                                   float* __restrict__ xres) {
  int bi = blockIdx.x;
  int bl = bi >> 6, h = bi & 63;
  int t = threadIdx.x;
  int oc = t & 63, w0 = (t >> 6) << 4;
  __shared__ float lds[64][64];
  float acc[16];
#pragma unroll
  for (int i = 0; i < 16; ++i) acc[i] = 0.f;
  for (int cc = 0; cc < 3; ++cc) {
    __syncthreads();
    for (int idx = t; idx < 4096; idx += 256) {
      int ch = idx >> 6, w = idx & 63;
      lds[ch][w] = xcat[(((size_t)bl * NC3 + cc * 64 + ch) << 12) + (h << 6) + w];
    }
    __syncthreads();
    for (int ch = 0; ch < 64; ++ch) {
      float wv = skw[oc * NC3 + cc * 64 + ch];
#pragma unroll
      for (int i = 0; i < 16; ++i) acc[i] += wv * lds[ch][w0 + i];
    }
  }
  float bv = skb[oc];
  int p0 = (h << 6) + w0;
#pragma unroll
  for (int i = 0; i < 16; ++i) {
    float hv = h2[(((size_t)bl * 64 + oc) << 12) + p0 + i];
    xres[((size_t)bl * NHW + p0 + i) * 64 + oc] = acc[i] + bv + hv;
  }
}

// per position: LN(ln1) then 64->256 proj; xx part -> xxin (NHWC [pi][128]), z part -> z
__global__ __launch_bounds__(256) void inproj_kernel(const float* __restrict__ xres,
                                                     const float* __restrict__ g,
                                                     const float* __restrict__ b,
                                                     const float* __restrict__ w,
                                                     float* __restrict__ xxin,
                                                     float* __restrict__ z) {
  int wv = threadIdx.x >> 6, lane = threadIdx.x & 63;
  size_t pi = (size_t)blockIdx.x * 4 + wv;  // [0, 6*4096)
  float x = xres[pi * 64 + lane];
  float s = wred64(x);
  float s2 = wred64(x * x);
  float m = s * (1.f / 64), var = s2 * (1.f / 64) - m * m;
  float rstd = rsqrtf(var + 1e-5f);
  float xln = (x - m) * rstd * g[lane] + b[lane];
  __shared__ float xb[4][64];
  xb[wv][lane] = xln;
  __syncthreads();
  float acc[4] = {0.f, 0.f, 0.f, 0.f};
  for (int c4 = 0; c4 < 16; ++c4) {
    float4 xv4 = *(const float4*)&xb[wv][c4 << 2];
#pragma unroll
    for (int q = 0; q < 4; ++q) {
      float4 w4 = *(const float4*)&w[(size_t)((lane + (q << 6)) << 6) + (c4 << 2)];
      acc[q] += w4.x * xv4.x + w4.y * xv4.y + w4.z * xv4.z + w4.w * xv4.w;
    }
  }
  xxin[(pi << 7) + lane] = acc[0];
  xxin[(pi << 7) + 64 + lane] = acc[1];
  z[(pi << 7) + lane] = acc[2];
  z[(pi << 7) + 64 + lane] = acc[3];
}

// depthwise 3x3 SAME + bias + silu on NHWC [bl][p][128]
__global__ __launch_bounds__(256) void dwconv_kernel(const float* __restrict__ xx,
                                                     const float* __restrict__ w,
                                                     const float* __restrict__ b,
                                                     float* __restrict__ out) {
  size_t gid = (size_t)blockIdx.x * 256 + threadIdx.x;  // 6*4096*128
  int d = gid & 127;
  size_t pi = gid >> 7;
  int p = (int)(pi & 4095);
  int bl = (int)(pi >> 12);
  int h = p >> 6, wq = p & 63;
  float acc = b[d];
  const float* wr = w + d * 9;
#pragma unroll
  for (int dy = -1; dy <= 1; ++dy) {
    int hh = h + dy;
    if (hh < 0 || hh >= 64) continue;
#pragma unroll
    for (int dx = -1; dx <= 1; ++dx) {
      int ww = wq + dx;
      if (ww < 0 || ww >= 64) continue;
      acc += wr[(dy + 1) * 3 + (dx + 1)] * xx[(((size_t)bl << 12) + (hh << 6) + ww) * 128 + d];
    }
  }
  out[pi * 128 + d] = silu(acc);
}

// x_dbl[bk][c][l] = sum_d xpw[k][c][d] * xs[bk][d][l]  (xs gathered via map_pos)
__global__ __launch_bounds__(256) void xdbl_kernel(const float* __restrict__ xxc,
                                                   const float* __restrict__ xpw,
                                                   float* __restrict__ xdbl) {
  int bi = blockIdx.x;               // NBL*NK*64
  int lt = bi & 63;
  int k = (bi >> 6) & 3;
  int bl = bi >> 8;
  int lbase = lt << 6;
  __shared__ float lds[64][132];
  int t = threadIdx.x;
  for (int idx = t; idx < 64 * 128; idx += 256) {
    int i = idx >> 7, d = idx & 127;
    int pos = map_pos(k, lbase + i);
    lds[i][d] = xxc[((size_t)bl * NHW + pos) * 128 + d];
  }
  __syncthreads();
  for (int oi = t; oi < 36 * 64; oi += 256) {
    int c = oi >> 6, l = oi & 63;
    const float* wrow = xpw + (k * 36 + c) * 128;
    float acc = 0.f;
    for (int d4 = 0; d4 < 32; ++d4) {
      float4 w4 = *(const float4*)&wrow[d4 << 2];
      float4 x4 = *(const float4*)&lds[l][d4 << 2];
      acc += w4.x * x4.x + w4.y * x4.y + w4.z * x4.z + w4.w * x4.w;
    }
    xdbl[(((size_t)(bl * 4 + k)) * 36 + c) * (size_t)NL + lbase + l] = acc;
  }
}

// ---- chunked selective scan, per-thread 16-state version ----
// grid = 24 bk * 64 chunks; block 128 (one thread per d). dt computed inline.
__global__ __launch_bounds__(128) void scan_pass1_kernel(const float* __restrict__ xdbl,
                                                         const float* __restrict__ xxc,
                                                         const float* __restrict__ dtw,
                                                         const float* __restrict__ dtb,
                                                         const float* __restrict__ Alog,
                                                         float* __restrict__ chunkP,
                                                         float* __restrict__ chunkH) {
  int bi = blockIdx.x;
  int chunk = bi & 63;
  int bk = bi >> 6;            // 0..23
  int k = bk & 3, bl = bk >> 2;
  int d = threadIdx.x;
  float4 wv = *(const float4*)(dtw + (size_t)(((k << 7) + d) << 2));
  float bias = dtb[(k << 7) + d];
  float An2[16];
  {
    const float* ar = Alog + (size_t)(((k << 7) + d) << 4);
#pragma unroll
    for (int n = 0; n < 16; ++n) An2[n] = -__expf(ar[n]) * 1.44269504f;
  }
  __shared__ float xd[SCLEN][36];
  int l0 = chunk << 6;
  for (int idx = threadIdx.x; idx < 36 * SCLEN; idx += 128) {
    int c = idx >> 6, li = idx & 63;
    xd[li][c] = xdbl[((size_t)bk * 36 + c) * (size_t)NL + l0 + li];
  }
  __syncthreads();
  const float* uB = xxc + ((size_t)bl << 19) + d;
  float h[16];
#pragma unroll
  for (int n = 0; n < 16; ++n) h[n] = 0.f;
  float sdt = 0.f;
#pragma unroll 2
  for (int li = 0; li < SCLEN; ++li) {
    int l = l0 + li;
    int pos = map_pos(k, l);
    const float4* row = (const float4*)&xd[li][0];
    float4 q0 = row[0];
    float acc = bias + wv.x * q0.x + wv.y * q0.y + wv.z * q0.z + wv.w * q0.w;
    float dt = (acc > 20.f) ? acc : log1pf(__expf(acc));
    float u = uB[(size_t)pos << 7];
    float dtu = dt * u;
    sdt += dt;
    float4 b0 = row[1], b1 = row[2], b2 = row[3], b3 = row[4];
    float Bv[16];
    Bv[0] = b0.x; Bv[1] = b0.y; Bv[2] = b0.z; Bv[3] = b0.w;
    Bv[4] = b1.x; Bv[5] = b1.y; Bv[6] = b1.z; Bv[7] = b1.w;
    Bv[8] = b2.x; Bv[9] = b2.y; Bv[10] = b2.z; Bv[11] = b2.w;
    Bv[12] = b3.x; Bv[13] = b3.y; Bv[14] = b3.z; Bv[15] = b3.w;
#pragma unroll
    for (int n = 0; n < 16; ++n) h[n] = exp2f(An2[n] * dt) * h[n] + dtu * Bv[n];
  }
  size_t base = (size_t)chunk * NSTATE + (((size_t)bk << 7) + (size_t)d) * 16;
#pragma unroll
  for (int n = 0; n < 16; ++n) {
    chunkP[base + n] = exp2f(An2[n] * sdt);
    chunkH[base + n] = h[n];
  }
}

// Pass 2: sequential combine over 64 chunks per state. grid 192 x 256.
__global__ __launch_bounds__(256) void scan_pass2_kernel(const float* __restrict__ chunkP,
                                                         const float* __restrict__ chunkH,
                                                         float* __restrict__ chunkHS) {
  size_t state = (size_t)blockIdx.x * 256 + threadIdx.x;  // < 49152
  float h = 0.f;
#pragma unroll 4
  for (int j = 0; j < NCH; ++j) {
    size_t idx = (size_t)j * NSTATE + state;
    chunkHS[idx] = h;
    h = chunkP[idx] * h + chunkH[idx];
  }
}

// Pass 3: re-run local scan seeded with h_start; emit y (no cross-lane ops).
__global__ __launch_bounds__(128) void scan_pass3_kernel(const float* __restrict__ xdbl,
                                                         const float* __restrict__ xxc,
                                                         const float* __restrict__ dtw,
                                                         const float* __restrict__ dtb,
                                                         const float* __restrict__ Alog,
                                                         const float* __restrict__ chunkHS,
                                                         float* __restrict__ ys) {
  int bi = blockIdx.x;
  int chunk = bi & 63;
  int bk = bi >> 6;
  int k = bk & 3, bl = bk >> 2;
  int d = threadIdx.x;
  float4 wv = *(const float4*)(dtw + (size_t)(((k << 7) + d) << 2));
  float bias = dtb[(k << 7) + d];
  float An2[16];
  {
    const float* ar = Alog + (size_t)(((k << 7) + d) << 4);
#pragma unroll
    for (int n = 0; n < 16; ++n) An2[n] = -__expf(ar[n]) * 1.44269504f;
  }
  __shared__ float xd[SCLEN][36];
  int l0 = chunk << 6;
  for (int idx = threadIdx.x; idx < 36 * SCLEN; idx += 128) {
    int c = idx >> 6, li = idx & 63;
    xd[li][c] = xdbl[((size_t)bk * 36 + c) * (size_t)NL + l0 + li];
  }
  __syncthreads();
  const float* uB = xxc + ((size_t)bl << 19) + d;
  float* yB = ys + ((size_t)bk << 19) + d;
  size_t base = (size_t)chunk * NSTATE + (((size_t)bk << 7) + (size_t)d) * 16;
  float h[16];
  {
    const float4* hp = (const float4*)(chunkHS + base);
    float4 h0 = hp[0], h1 = hp[1], h2 = hp[2], h3 = hp[3];
    h[0] = h0.x; h[1] = h0.y; h[2] = h0.z; h[3] = h0.w;
    h[4] = h1.x; h[5] = h1.y; h[6] = h1.z; h[7] = h1.w;
    h[8] = h2.x; h[9] = h2.y; h[10] = h2.z; h[11] = h2.w;
    h[12] = h3.x; h[13] = h3.y; h[14] = h3.z; h[15] = h3.w;
  }
#pragma unroll 2
  for (int li = 0; li < SCLEN; ++li) {
    int l = l0 + li;
    int pos = map_pos(k, l);
    const float4* row = (const float4*)&xd[li][0];
    float4 q0 = row[0];
    float acc = bias + wv.x * q0.x + wv.y * q0.y + wv.z * q0.z + wv.w * q0.w;
    float dt = (acc > 20.f) ? acc : log1pf(__expf(acc));
    float u = uB[(size_t)pos << 7];
    float dtu = dt * u;
    float4 b0 = row[1], b1 = row[2], b2 = row[3], b3 = row[4];
    float4 c0 = row[5], c1 = row[6], c2 = row[7], c3 = row[8];
    float Bv[16], Cv[16];
    Bv[0] = b0.x; Bv[1] = b0.y; Bv[2] = b0.z; Bv[3] = b0.w;
    Bv[4] = b1.x; Bv[5] = b1.y; Bv[6] = b1.z; Bv[7] = b1.w;
    Bv[8] = b2.x; Bv[9] = b2.y; Bv[10] = b2.z; Bv[11] = b2.w;
    Bv[12] = b3.x; Bv[13] = b3.y; Bv[14] = b3.z; Bv[15] = b3.w;
    Cv[0] = c0.x; Cv[1] = c0.y; Cv[2] = c0.z; Cv[3] = c0.w;
    Cv[4] = c1.x; Cv[5] = c1.y; Cv[6] = c1.z; Cv[7] = c1.w;
    Cv[8] = c2.x; Cv[9] = c2.y; Cv[10] = c2.z; Cv[11] = c2.w;
    Cv[12] = c3.x; Cv[13] = c3.y; Cv[14] = c3.z; Cv[15] = c3.w;
    float y = 0.f;
#pragma unroll
    for (int n = 0; n < 16; ++n) {
      h[n] = exp2f(An2[n] * dt) * h[n] + dtu * Bv[n];
      y += h[n] * Cv[n];
    }
    yB[(size_t)l << 7] = y;
  }
}

// ycomb[bl][p][d] = sum of 4 direction outputs (mapped) + xxc * sum_k Ds
__global__ __launch_bounds__(256) void combine_kernel(const float* __restrict__ ys,
                                                      const float* __restrict__ xxc,
                                                      const float* __restrict__ Ds,
                                                      float* __restrict__ ycomb) {
  size_t gid = (size_t)blockIdx.x * 256 + threadIdx.x;  // 6*4096*128
  int d = gid & 127;
  size_t pi = gid >> 7;
  int p = (int)(pi & 4095);
  int bl = (int)(pi >> 12);
  int h = p >> 6, w = p & 63;
  int l1 = (w << 6) | h;
  size_t base = ((size_t)bl * 4) << 12;
  float v = ys[((base + p) << 7) + d]
          + ys[((base + 4096 + l1) << 7) + d]
          + ys[((base + 2 * 4096 + (4095 - p)) << 7) + d]
          + ys[((base + 3 * 4096 + (4095 - l1)) << 7) + d];
  float ds = Ds[d] + Ds[128 + d] + Ds[256 + d] + Ds[384 + d];
  v += xxc[(pi << 7) + d] * ds;
  ycomb[(pi << 7) + d] = v;
}

// out_norm LN(128) -> *silu(z) -> out_proj 128->64 -> + x_res
__global__ __launch_bounds__(256) void outproj_kernel(const float* __restrict__ ycomb,
                                                      const float* __restrict__ z,
                                                      const float* __restrict__ ong,
                                                      const float* __restrict__ onb,
                                                      const float* __restrict__ opw,
                                                      const float* __restrict__ xres,
                                                      float* __restrict__ x1) {
  int wv = threadIdx.x >> 6, lane = threadIdx.x & 63;
  size_t pi = (size_t)blockIdx.x * 4 + wv;
  float y0 = ycomb[(pi << 7) + lane], y1 = ycomb[(pi << 7) + 64 + lane];
  float s = wred64(y0 + y1);
  float s2 = wred64(y0 * y0 + y1 * y1);
  float m = s * (1.f / 128), var = s2 * (1.f / 128) - m * m;
  float rstd = rsqrtf(var + 1e-5f);
  float z0 = z[(pi << 7) + lane], z1 = z[(pi << 7) + 64 + lane];
  float g0 = ((y0 - m) * rstd * ong[lane] + onb[lane]) * silu(z0);
  float g1 = ((y1 - m) * rstd * ong[64 + lane] + onb[64 + lane]) * silu(z1);
  __shared__ float gb[4][128];
  gb[wv][lane] = g0;
  gb[wv][64 + lane] = g1;
  __syncthreads();
  float acc = 0.f;
  const float* wrow = opw + (size_t)(lane << 7);
  for (int i4 = 0; i4 < 32; ++i4) {
    float4 w4 = *(const float4*)&wrow[i4 << 2];
    float4 g4 = *(const float4*)&gb[wv][i4 << 2];
    acc += w4.x * g4.x + w4.y * g4.y + w4.z * g4.z + w4.w * g4.w;
  }
  x1[pi * 64 + lane] = xres[pi * 64 + lane] + acc;
}

// ln2 -> fc1 -> gelu(tanh) -> fc2 -> residual; NHWC
__global__ __launch_bounds__(256) void mlp_kernel(const float* __restrict__ x1,
                                                  const float* __restrict__ g2,
                                                  const float* __restrict__ b2,
                                                  const float* __restrict__ w1,
                                                  const float* __restrict__ bb1,
                                                  const float* __restrict__ w2,
                                                  const float* __restrict__ bb2,
                                                  float* __restrict__ x2) {
  int wv = threadIdx.x >> 6, lane = threadIdx.x & 63;
  size_t pi = (size_t)blockIdx.x * 4 + wv;
  float xv = x1[pi * 64 + lane];
  float s = wred64(xv), s2 = wred64(xv * xv);
  float m = s * (1.f / 64), var = s2 * (1.f / 64) - m * m;
  float rstd = rsqrtf(var + 1e-5f);
  float xm = (xv - m) * rstd * g2[lane] + b2[lane];
  __shared__ float xb[4][64], tb[4][64];
  xb[wv][lane] = xm;
  __syncthreads();
  float acc = bb1[lane];
  const float* wr = w1 + (size_t)(lane << 6);
  for (int i4 = 0; i4 < 16; ++i4) {
    float4 w4 = *(const float4*)&wr[i4 << 2];
    float4 x4 = *(const float4*)&xb[wv][i4 << 2];
    acc += w4.x * x4.x + w4.y * x4.y + w4.z * x4.z + w4.w * x4.w;
  }
  float u = acc;
  float tt = tanhf(0.7978845608028654f * (u + 0.044715f * u * u * u));
  float t1 = 0.5f * u * (1.f + tt);
  tb[wv][lane] = t1;
  __syncthreads();
  float acc2 = bb2[lane];
  const float* wr2 = w2 + (size_t)(lane << 6);
  for (int i4 = 0; i4 < 16; ++i4) {
    float4 w4 = *(const float4*)&wr2[i4 << 2];
    float4 t4 = *(const float4*)&tb[wv][i4 << 2];
    acc2 += w4.x * t4.x + w4.y * t4.y + w4.z * t4.z + w4.w * t4.w;
  }
  x2[pi * 64 + lane] = xv + acc2;
}

// NHWC (bl,p,c) -> NCHW (bl,c,p) tiled transpose into d_out
__global__ __launch_bounds__(256) void transpose_out_kernel(const float* __restrict__ x2,
                                                            float* __restrict__ out) {
  int bi = blockIdx.x;  // NBL * 2 * 128
  int pt = bi & 127;
  int ct = (bi >> 7) & 1;
  int bl = bi >> 8;
  __shared__ float lds[32][33];
  int t = threadIdx.x;
  int j = t & 31, i0 = t >> 5;
  int p0 = pt << 5, c0 = ct << 5;
#pragma unroll
  for (int q = 0; q < 4; ++q) {
    int i = i0 + (q << 3);
    lds[i][j] = x2[((size_t)bl * NHW + p0 + i) * 64 + c0 + j];
  }
  __syncthreads();
#pragma unroll
  for (int q = 0; q < 4; ++q) {
    int i = i0 + (q << 3);
    out[((size_t)bl * 64 + c0 + i) * (size_t)NHW + p0 + j] = lds[j][i];
  }
}

extern "C" void kernel_launch(void* const* d_in, const int* in_sizes, int n_in,
                              void* d_out, int out_size, void* d_ws, size_t ws_size,
                              hipStream_t stream) {
  const float* img  = (const float*)d_in[0];
  const float* dz   = (const float*)d_in[1];
  const float* sg   = (const float*)d_in[2];
  const float* gn1g = (const float*)d_in[3];
  const float* gn1b = (const float*)d_in[4];
  const float* c1w  = (const float*)d_in[5];
  const float* c1b  = (const float*)d_in[6];
  const float* gn2g = (const float*)d_in[7];
  const float* gn2b = (const float*)d_in[8];
  const float* c2w  = (const float*)d_in[9];
  const float* c2b  = (const float*)d_in[10];
  const float* skw  = (const float*)d_in[11];
  const float* skb  = (const float*)d_in[12];
  const float* ln1g = (const float*)d_in[13];
  const float* ln1b = (const float*)d_in[14];
  const float* ln2g = (const float*)d_in[15];
  const float* ln2b = (const float*)d_in[16];
  const float* ipw  = (const float*)d_in[17];
  const float* dww  = (const float*)d_in[18];
  const float* dwb  = (const float*)d_in[19];
  const float* xpw  = (const float*)d_in[20];
  const float* dtw  = (const float*)d_in[21];
  const float* dtb  = (const float*)d_in[22];
  const float* Alog = (const float*)d_in[23];
  const float* Dsp  = (const float*)d_in[24];
  const float* ong  = (const float*)d_in[25];
  const float* onb  = (const float*)d_in[26];
  const float* opw  = (const float*)d_in[27];
  const float* f1w  = (const float*)d_in[28];
  const float* f1b  = (const float*)d_in[29];
  const float* f2w  = (const float*)d_in[30];
  const float* f2b  = (const float*)d_in[31];

  float* out = (float*)d_out;
  float* ws = (float*)d_ws;
  if (ws_size < F_TOTAL * sizeof(float)) return;

  float* xcat  = ws + F_XCAT;
  float* act1  = ws + F_ACT1;
  float* h1    = ws + F_H1;
  float* act2  = ws + F_ACT2;
  float* h2    = ws + F_H2;
  float* xres  = ws + F_XRES;
  float* xxin  = ws + F_XXIN;
  float* zbuf  = ws + F_Z;
  float* xxc   = ws + F_XXC;
  float* xdbl  = ws + F_XDBL;
  float* ysb   = ws + F_YS;
  float* ycomb = ws + F_YCOMB;
  float* x1    = ws + F_X1;
  float* x2    = ws + F_X2;
  float* stats = ws + F_STATS;
  // scan chunk arrays alias buffers that are dead during the scan
  float* chunkP  = ws + F_XXIN;   // 3,145,728 (xxin dead after dwconv)
  float* chunkH  = ws + F_YCOMB;  // 3,145,728 (ycomb written after scan)
  float* chunkHS = ws + F_X1;     // 3,145,728 (x1/x2 written after scan)
  // stats partials + conv partials live in the (still-dead) YS region
  double* part = (double*)(ws + F_YS);
  float* convpart = ws + F_YS;    // up to 6*6*64*4096 = 9.4M floats < 12.58M

  // stage 0: instance-norm stats over image per (b,l)
  stats1_kernel<<<NBL * 32, 256, 0, stream>>>(img, NC * NHW, part);
  stats2_kernel<<<NBL, 64, 0, stream>>>(part, NC * NHW, stats + 0, stats + 8);
  build_xcat_kernel<<<18432, 256, 0, stream>>>(img, dz, sg, stats, xcat);
  // gn1 + silu
  stats1_kernel<<<NBL * 32, 256, 0, stream>>>(xcat, NC3 * NHW, part);
  stats2_kernel<<<NBL, 64, 0, stream>>>(part, NC3 * NHW, stats + 16, stats + 24);
  gn_silu_kernel<NC3><<<18432, 256, 0, stream>>>(xcat, gn1g, gn1b, stats + 16, act1);
  // conv1 192->64 split: 6 ic-slices x 2 oc-halves
  conv3x3_part_kernel<<<NBL * 64 * 2 * 6, 256, 0, stream>>>(act1, c1w, convpart, NC3, 6);
  conv_reduce_kernel<<<6144, 256, 0, stream>>>(convpart, c1b, h1, 6);
  // gn2 + silu
  stats1_kernel<<<NBL * 32, 256, 0, stream>>>(h1, NC * NHW, part);
  stats2_kernel<<<NBL, 64, 0, stream>>>(part, NC * NHW, stats + 32, stats + 40);
  gn_silu_kernel<NC><<<6144, 256, 0, stream>>>(h1, gn2g, gn2b, stats + 32, act2);
  // conv2 64->64 split: 2 ic-slices x 2 oc-halves
  conv3x3_part_kernel<<<NBL * 64 * 2 * 2, 256, 0, stream>>>(act2, c2w, convpart, NC, 2);
  conv_reduce_kernel<<<6144, 256, 0, stream>>>(convpart, c2b, h2, 2);
  // skip 1x1 + residual + NHWC transpose
  skip_kernel<<<NBL * 64, 256, 0, stream>>>(xcat, h2, skw, skb, xres);
  // SS2D
  inproj_kernel<<<6144, 256, 0, stream>>>(xres, ln1g, ln1b, ipw, xxin, zbuf);
  dwconv_kernel<<<12288, 256, 0, stream>>>(xxin, dww, dwb, xxc);
  xdbl_kernel<<<NBL * NK * 64, 256, 0, stream>>>(xxc, xpw, xdbl);
  // chunked scan (dt computed inline; no delta buffer)
  scan_pass1_kernel<<<24 * 64, 128, 0, stream>>>(xdbl, xxc, dtw, dtb, Alog, chunkP, chunkH);
  scan_pass2_kernel<<<192, 256, 0, stream>>>(chunkP, chunkH, chunkHS);
  scan_pass3_kernel<<<24 * 64, 128, 0, stream>>>(xdbl, xxc, dtw, dtb, Alog, chunkHS, ysb);
  combine_kernel<<<12288, 256, 0, stream>>>(ysb, xxc, Dsp, ycomb);
  outproj_kernel<<<6144, 256, 0, stream>>>(ycomb, zbuf, ong, onb, opw, xres, x1);
  // MLP + residual
  mlp_kernel<<<6144, 256, 0, stream>>>(x1, ln2g, ln2b, f1w, f1b, f2w, f2b, x2);
  // final transpose to NCHW output
  transpose_out_kernel<<<NBL * 256, 256, 0, stream>>>(x2, out);
}

// Round 5
// 907.398 us; speedup vs baseline: 1.2730x; 1.2730x over previous
//
#include <hip/hip_runtime.h>
#include <hip/hip_bf16.h>

typedef unsigned short ushortT;
typedef short short8v __attribute__((ext_vector_type(8)));
typedef float float4v __attribute__((ext_vector_type(4)));

// Problem constants
#define NBL 6      // B*LEN
#define NC 64
#define NC3 192
#define NHW 4096   // 64*64
#define NDI 128
#define NNS 16
#define NDR 4
#define NK 4
#define NL 4096
#define NCH 64     // scan chunks
#define SCLEN 64   // chunk length
#define NSTATE 49152  // 24 bk * 128 d * 16 n

// workspace offsets in floats
static const size_t F_XCAT  = 0;          // 6*192*4096 = 4,718,592
static const size_t F_ACT1  = 4718592;    // act1b bf16 NHWC (4.72M ushorts) lives here
static const size_t F_H1    = 9437184;    // 1,572,864
static const size_t F_ACT2  = 11010048;   // act2b bf16 NHWC (1.57M ushorts)
static const size_t F_H2    = 12582912;   // 1,572,864
static const size_t F_XRES  = 14155776;   // 1,572,864
static const size_t F_XXIN  = 15728640;   // 3,145,728  (dead after dwconv -> chunkP)
static const size_t F_Z     = 18874368;   // 3,145,728
static const size_t F_XXC   = 22020096;   // 3,145,728
static const size_t F_XDBL  = 25165824;   // 6*4*36*4096 = 3,538,944
static const size_t F_YS    = 28704768;   // 12,582,912 (stats partials + weight packs early, ys later)
static const size_t F_YCOMB = 41287680;   // 3,145,728  (chunkH during scan)
static const size_t F_X1    = 44433408;   // 1,572,864  (X1+X2 -> chunkHS during scan)
static const size_t F_X2    = 46006272;   // 1,572,864
static const size_t F_STATS = 47579136;   // 48
static const size_t F_TOTAL = 47579184;   // floats (~190.3 MB)

__device__ __forceinline__ float wred64(float v) {
#pragma unroll
  for (int m = 32; m; m >>= 1) v += __shfl_xor(v, m, 64);
  return v;
}

__device__ __forceinline__ float silu(float v) {
  return v / (1.f + __expf(-v));
}

__device__ __forceinline__ ushortT f2bf(float f) {
  unsigned int u = __builtin_bit_cast(unsigned int, f);
  unsigned int r = (u + 0x7FFFu + ((u >> 16) & 1u)) >> 16;
  return (ushortT)r;
}

__device__ __forceinline__ int map_pos(int k, int l) {
  // k0: hw order, k1: wh order, k2: hw reversed, k3: wh reversed
  if (k == 0) return l;
  if (k == 1) return ((l & 63) << 6) | (l >> 6);
  if (k == 2) return 4095 - l;
  int lp = 4095 - l;
  return ((lp & 63) << 6) | (lp >> 6);
}

// ---- two-stage per-sample mean/rstd (f64 accumulate) ----
__global__ __launch_bounds__(256) void stats1_kernel(const float* __restrict__ in, int n,
                                                     double* __restrict__ part) {
  int bi = blockIdx.x;
  int s = bi >> 5, j = bi & 31;
  int slice = n >> 5;
  const float4* p = (const float4*)(in + (size_t)s * n + (size_t)j * slice);
  int n4 = slice >> 2;
  double dsum = 0.0, dsq = 0.0;
  for (int i = threadIdx.x; i < n4; i += 256) {
    float4 v = p[i];
    dsum += (double)((v.x + v.y) + (v.z + v.w));
    dsq += (double)v.x * v.x + (double)v.y * v.y + (double)v.z * v.z + (double)v.w * v.w;
  }
  __shared__ double s1[256], s2[256];
  s1[threadIdx.x] = dsum; s2[threadIdx.x] = dsq;
  __syncthreads();
  for (int off = 128; off; off >>= 1) {
    if (threadIdx.x < off) { s1[threadIdx.x] += s1[threadIdx.x + off]; s2[threadIdx.x] += s2[threadIdx.x + off]; }
    __syncthreads();
  }
  if (threadIdx.x == 0) { part[2 * bi] = s1[0]; part[2 * bi + 1] = s2[0]; }
}

__global__ __launch_bounds__(64) void stats2_kernel(const double* __restrict__ part, int n,
                                                    float* __restrict__ mean_out,
                                                    float* __restrict__ rstd_out) {
  int s = blockIdx.x;
  int lane = threadIdx.x;
  double sum = 0.0, sq = 0.0;
  if (lane < 32) { sum = part[2 * (s * 32 + lane)]; sq = part[2 * (s * 32 + lane) + 1]; }
#pragma unroll
  for (int m = 16; m; m >>= 1) { sum += __shfl_xor(sum, m, 64); sq += __shfl_xor(sq, m, 64); }
  if (lane == 0) {
    double mean = sum / n;
    double var = sq / n - mean * mean;
    mean_out[s] = (float)mean;
    rstd_out[s] = (float)(1.0 / sqrt(var + 1e-5));
  }
}

// x_cat[bl][ch][p]: ch<64 dz, 64..127 instance-normed img, 128..191 sigma
__global__ __launch_bounds__(256) void build_xcat_kernel(const float* __restrict__ img,
                                                         const float* __restrict__ dz,
                                                         const float* __restrict__ sg,
                                                         const float* __restrict__ stats,
                                                         float* __restrict__ xcat) {
  size_t gid = (size_t)blockIdx.x * 256 + threadIdx.x;  // 6*192*4096 total
  int p = gid & 4095;
  size_t r = gid >> 12;
  int ch = (int)(r % NC3);
  int bl = (int)(r / NC3);
  int b = bl / 3;  // LEN=3
  float v;
  if (ch < 64) {
    v = dz[((size_t)b * NC + ch) * NHW + p];
  } else if (ch < 128) {
    float m = stats[bl], rs = stats[8 + bl];
    v = (img[((size_t)bl * NC + (ch - 64)) * NHW + p] - m) * rs;
  } else {
    v = sg[((size_t)b * NC + (ch - 128)) * NHW + p];
  }
  xcat[gid] = v;
}

// GN + SiLU + NCHW->NHWC transpose + f32->bf16. grid NBL*64, block 256.
template <int CCH>
__global__ __launch_bounds__(256) void gnsilu_t_kernel(const float* __restrict__ in,
                                                       const float* __restrict__ g,
                                                       const float* __restrict__ b,
                                                       const float* __restrict__ stats,
                                                       ushortT* __restrict__ outb) {
  int bi = blockIdx.x;
  int bl = bi >> 6, h = bi & 63;
  __shared__ ushortT tile[CCH][66];
  float m = stats[bl], rs = stats[8 + bl];
  int t = threadIdx.x;
  for (int idx = t; idx < CCH * 64; idx += 256) {
    int ch = idx >> 6, w = idx & 63;
    float v = in[(((size_t)bl * CCH + ch) << 12) + (h << 6) + w];
    v = (v - m) * rs * g[ch] + b[ch];
    v = silu(v);
    tile[ch][w] = f2bf(v);
  }
  __syncthreads();
  constexpr int C8 = CCH / 8;
  for (int idx = t; idx < 64 * C8; idx += 256) {
    int w = idx / C8, c8 = idx % C8;
    short8v v;
#pragma unroll
    for (int j = 0; j < 8; ++j) v[j] = (short)tile[c8 * 8 + j][w];
    *(short8v*)&outb[(size_t)(bl * 4096 + h * 64 + w) * CCH + c8 * 8] = v;
  }
}

// Pre-pack conv weights into per-lane MFMA B-fragments (bf16).
// layout [tap(9)][kt(CIN/32)][nt(4)][lane(64)][j(8)]; element =
// w[oc = nt*16 + (lane&15)][ic = kt*32 + (lane>>4)*8 + j][r][s], tap = r*3+s.
__global__ __launch_bounds__(256) void wprep_kernel(const float* __restrict__ w,
                                                    ushortT* __restrict__ out,
                                                    int CIN, int KT) {
  int id = blockIdx.x * 256 + threadIdx.x;
  int j = id & 7;
  int lane = (id >> 3) & 63;
  int nt = (id >> 9) & 3;
  int rest = id >> 11;
  int kt = rest % KT;
  int tap = rest / KT;
  int oc = nt * 16 + (lane & 15);
  int ic = kt * 32 + ((lane >> 4) << 3) + j;
  int r = tap / 3, s = tap % 3;
  out[id] = f2bf(w[(((size_t)oc * CIN + ic) * 3 + r) * 3 + s]);
}

// Implicit-GEMM 3x3 SAME conv via bf16 MFMA, f32 accumulate.
// grid = NBL*64*2 (bl, h, n-half); block 256 = 4 waves; wave wv owns mtile wv (16 w),
// both ntiles of its n-half (2x16 oc). Input NHWC bf16, output NCHW f32 (+bias).
template <int CIN>
__global__ __launch_bounds__(256) void conv_mfma_kernel(const ushortT* __restrict__ actb,
                                                        const ushortT* __restrict__ wb,
                                                        const float* __restrict__ bias,
                                                        float* __restrict__ out) {
  constexpr int KT = CIN / 32;
  constexpr int STRIDE = CIN + 8;  // ushorts; 400B/144B row stride, 16B aligned
  constexpr int C8 = CIN / 8;
  int bi = blockIdx.x;
  int nh = bi & 1;
  int h = (bi >> 1) & 63;
  int bl = bi >> 7;
  int t = threadIdx.x;
  int wv = t >> 6, lane = t & 63;
  __shared__ ushortT lds[66 * STRIDE];
  float4v acc0 = {0.f, 0.f, 0.f, 0.f};
  float4v acc1 = {0.f, 0.f, 0.f, 0.f};
  int lrow = lane & 15;
  int lk = (lane >> 4) << 3;
  for (int dy = 0; dy < 3; ++dy) {
    int hh = h + dy - 1;
    bool valid = (hh >= 0) && (hh < 64);
    int hc = valid ? hh : 0;
    if (dy) __syncthreads();
    const ushortT* src = actb + (size_t)(bl * 4096 + hc * 64) * CIN;
    for (int idx = t; idx < 64 * C8; idx += 256) {
      int w = idx / C8, c8 = idx % C8;
      short8v v = {0, 0, 0, 0, 0, 0, 0, 0};
      if (valid) v = *(const short8v*)&src[(size_t)w * CIN + c8 * 8];
      *(short8v*)&lds[(w + 1) * STRIDE + c8 * 8] = v;
    }
    if (t < 2 * C8) {
      int which = t / C8, c8 = t % C8;
      short8v z = {0, 0, 0, 0, 0, 0, 0, 0};
      *(short8v*)&lds[(which ? 65 : 0) * STRIDE + c8 * 8] = z;
    }
    __syncthreads();
    for (int dx = 0; dx < 3; ++dx) {
      int tap = dy * 3 + dx;
      int wl = (wv << 4) + lrow + dx;
#pragma unroll
      for (int kt = 0; kt < KT; ++kt) {
        short8v a = *(const short8v*)&lds[wl * STRIDE + kt * 32 + lk];
        const ushortT* wp = wb + ((size_t)(((tap * KT + kt) * 4 + (nh << 1)) * 64 + lane) << 3);
        short8v b0 = *(const short8v*)&wp[0];
        short8v b1 = *(const short8v*)&wp[512];
        acc0 = __builtin_amdgcn_mfma_f32_16x16x32_bf16(a, b0, acc0, 0, 0, 0);
        acc1 = __builtin_amdgcn_mfma_f32_16x16x32_bf16(a, b1, acc1, 0, 0, 0);
      }
    }
  }
  // C/D layout: col = lane&15 (oc), row = (lane>>4)*4 + reg (w) [m89]
  int oc0 = (nh << 5) + lrow;
  int oc1 = oc0 + 16;
  int w0 = (wv << 4) + ((lane >> 4) << 2);
  float bv0 = bias[oc0], bv1 = bias[oc1];
  float4 o0 = make_float4(acc0[0] + bv0, acc0[1] + bv0, acc0[2] + bv0, acc0[3] + bv0);
  float4 o1 = make_float4(acc1[0] + bv1, acc1[1] + bv1, acc1[2] + bv1, acc1[3] + bv1);
  *(float4*)&out[(((size_t)bl * 64 + oc0) << 12) + (h << 6) + w0] = o0;
  *(float4*)&out[(((size_t)bl * 64 + oc1) << 12) + (h << 6) + w0] = o1;
}

// x_res[bl][p][oc] = h2[bl][oc][p] + 1x1skip(xcat)[oc] + skb[oc]   (NHWC out)
__global__ __launch_bounds__(256) void skip_kernel(const float* __restrict__ xcat,
                                                   const float* __restrict__ h2,
                                                   const float* __restrict__ skw,
                                                   const float* __restrict__ skb,
                                                   float* __restrict__ xres) {
  int bi = blockIdx.x;
  int bl = bi >> 6, h = bi & 63;
  int t = threadIdx.x;
  int oc = t & 63, w0 = (t >> 6) << 4;
  __shared__ float lds[64][64];
  float acc[16];
#pragma unroll
  for (int i = 0; i < 16; ++i) acc[i] = 0.f;
  for (int cc = 0; cc < 3; ++cc) {
    __syncthreads();
    for (int idx = t; idx < 4096; idx += 256) {
      int ch = idx >> 6, w = idx & 63;
      lds[ch][w] = xcat[(((size_t)bl * NC3 + cc * 64 + ch) << 12) + (h << 6) + w];
    }
    __syncthreads();
    for (int ch = 0; ch < 64; ++ch) {
      float wv = skw[oc * NC3 + cc * 64 + ch];
#pragma unroll
      for (int i = 0; i < 16; ++i) acc[i] += wv * lds[ch][w0 + i];
    }
  }
  float bv = skb[oc];
  int p0 = (h << 6) + w0;
#pragma unroll
  for (int i = 0; i < 16; ++i) {
    float hv = h2[(((size_t)bl * 64 + oc) << 12) + p0 + i];
    xres[((size_t)bl * NHW + p0 + i) * 64 + oc] = acc[i] + bv + hv;
  }
}

// per position: LN(ln1) then 64->256 proj; xx part -> xxin (NHWC [pi][128]), z part -> z
__global__ __launch_bounds__(256) void inproj_kernel(const float* __restrict__ xres,
                                                     const float* __restrict__ g,
                                                     const float* __restrict__ b,
                                                     const float* __restrict__ w,
                                                     float* __restrict__ xxin,
                                                     float* __restrict__ z) {
  int wv = threadIdx.x >> 6, lane = threadIdx.x & 63;
  size_t pi = (size_t)blockIdx.x * 4 + wv;  // [0, 6*4096)
  float x = xres[pi * 64 + lane];
  float s = wred64(x);
  float s2 = wred64(x * x);
  float m = s * (1.f / 64), var = s2 * (1.f / 64) - m * m;
  float rstd = rsqrtf(var + 1e-5f);
  float xln = (x - m) * rstd * g[lane] + b[lane];
  __shared__ float xb[4][64];
  xb[wv][lane] = xln;
  __syncthreads();
  float acc[4] = {0.f, 0.f, 0.f, 0.f};
  for (int c4 = 0; c4 < 16; ++c4) {
    float4 xv4 = *(const float4*)&xb[wv][c4 << 2];
#pragma unroll
    for (int q = 0; q < 4; ++q) {
      float4 w4 = *(const float4*)&w[(size_t)((lane + (q << 6)) << 6) + (c4 << 2)];
      acc[q] += w4.x * xv4.x + w4.y * xv4.y + w4.z * xv4.z + w4.w * xv4.w;
    }
  }
  xxin[(pi << 7) + lane] = acc[0];
  xxin[(pi << 7) + 64 + lane] = acc[1];
  z[(pi << 7) + lane] = acc[2];
  z[(pi << 7) + 64 + lane] = acc[3];
}

// depthwise 3x3 SAME + bias + silu on NHWC [bl][p][128]
__global__ __launch_bounds__(256) void dwconv_kernel(const float* __restrict__ xx,
                                                     const float* __restrict__ w,
                                                     const float* __restrict__ b,
                                                     float* __restrict__ out) {
  size_t gid = (size_t)blockIdx.x * 256 + threadIdx.x;  // 6*4096*128
  int d = gid & 127;
  size_t pi = gid >> 7;
  int p = (int)(pi & 4095);
  int bl = (int)(pi >> 12);
  int h = p >> 6, wq = p & 63;
  float acc = b[d];
  const float* wr = w + d * 9;
#pragma unroll
  for (int dy = -1; dy <= 1; ++dy) {
    int hh = h + dy;
    if (hh < 0 || hh >= 64) continue;
#pragma unroll
    for (int dx = -1; dx <= 1; ++dx) {
      int ww = wq + dx;
      if (ww < 0 || ww >= 64) continue;
      acc += wr[(dy + 1) * 3 + (dx + 1)] * xx[(((size_t)bl << 12) + (hh << 6) + ww) * 128 + d];
    }
  }
  out[pi * 128 + d] = silu(acc);
}

// x_dbl[bk][c][l] = sum_d xpw[k][c][d] * xs[bk][d][l]  (xs gathered via map_pos)
__global__ __launch_bounds__(256) void xdbl_kernel(const float* __restrict__ xxc,
                                                   const float* __restrict__ xpw,
                                                   float* __restrict__ xdbl) {
  int bi = blockIdx.x;               // NBL*NK*64
  int lt = bi & 63;
  int k = (bi >> 6) & 3;
  int bl = bi >> 8;
  int lbase = lt << 6;
  __shared__ float lds[64][132];
  int t = threadIdx.x;
  for (int idx = t; idx < 64 * 128; idx += 256) {
    int i = idx >> 7, d = idx & 127;
    int pos = map_pos(k, lbase + i);
    lds[i][d] = xxc[((size_t)bl * NHW + pos) * 128 + d];
  }
  __syncthreads();
  for (int oi = t; oi < 36 * 64; oi += 256) {
    int c = oi >> 6, l = oi & 63;
    const float* wrow = xpw + (k * 36 + c) * 128;
    float acc = 0.f;
    for (int d4 = 0; d4 < 32; ++d4) {
      float4 w4 = *(const float4*)&wrow[d4 << 2];
      float4 x4 = *(const float4*)&lds[l][d4 << 2];
      acc += w4.x * x4.x + w4.y * x4.y + w4.z * x4.z + w4.w * x4.w;
    }
    xdbl[(((size_t)(bl * 4 + k)) * 36 + c) * (size_t)NL + lbase + l] = acc;
  }
}

// ---- chunked selective scan, per-thread 16-state version ----
__global__ __launch_bounds__(128) void scan_pass1_kernel(const float* __restrict__ xdbl,
                                                         const float* __restrict__ xxc,
                                                         const float* __restrict__ dtw,
                                                         const float* __restrict__ dtb,
                                                         const float* __restrict__ Alog,
                                                         float* __restrict__ chunkP,
                                                         float* __restrict__ chunkH) {
  int bi = blockIdx.x;
  int chunk = bi & 63;
  int bk = bi >> 6;            // 0..23
  int k = bk & 3, bl = bk >> 2;
  int d = threadIdx.x;
  float4 wv = *(const float4*)(dtw + (size_t)(((k << 7) + d) << 2));
  float bias = dtb[(k << 7) + d];
  float An2[16];
  {
    const float* ar = Alog + (size_t)(((k << 7) + d) << 4);
#pragma unroll
    for (int n = 0; n < 16; ++n) An2[n] = -__expf(ar[n]) * 1.44269504f;
  }
  __shared__ float xd[SCLEN][36];
  int l0 = chunk << 6;
  for (int idx = threadIdx.x; idx < 36 * SCLEN; idx += 128) {
    int c = idx >> 6, li = idx & 63;
    xd[li][c] = xdbl[((size_t)bk * 36 + c) * (size_t)NL + l0 + li];
  }
  __syncthreads();
  const float* uB = xxc + ((size_t)bl << 19) + d;
  float h[16];
#pragma unroll
  for (int n = 0; n < 16; ++n) h[n] = 0.f;
  float sdt = 0.f;
#pragma unroll 2
  for (int li = 0; li < SCLEN; ++li) {
    int l = l0 + li;
    int pos = map_pos(k, l);
    const float4* row = (const float4*)&xd[li][0];
    float4 q0 = row[0];
    float acc = bias + wv.x * q0.x + wv.y * q0.y + wv.z * q0.z + wv.w * q0.w;
    float dt = (acc > 20.f) ? acc : log1pf(__expf(acc));
    float u = uB[(size_t)pos << 7];
    float dtu = dt * u;
    sdt += dt;
    float4 b0 = row[1], b1 = row[2], b2 = row[3], b3 = row[4];
    float Bv[16];
    Bv[0] = b0.x; Bv[1] = b0.y; Bv[2] = b0.z; Bv[3] = b0.w;
    Bv[4] = b1.x; Bv[5] = b1.y; Bv[6] = b1.z; Bv[7] = b1.w;
    Bv[8] = b2.x; Bv[9] = b2.y; Bv[10] = b2.z; Bv[11] = b2.w;
    Bv[12] = b3.x; Bv[13] = b3.y; Bv[14] = b3.z; Bv[15] = b3.w;
#pragma unroll
    for (int n = 0; n < 16; ++n) h[n] = exp2f(An2[n] * dt) * h[n] + dtu * Bv[n];
  }
  size_t base = (size_t)chunk * NSTATE + (((size_t)bk << 7) + (size_t)d) * 16;
#pragma unroll
  for (int n = 0; n < 16; ++n) {
    chunkP[base + n] = exp2f(An2[n] * sdt);
    chunkH[base + n] = h[n];
  }
}

__global__ __launch_bounds__(256) void scan_pass2_kernel(const float* __restrict__ chunkP,
                                                         const float* __restrict__ chunkH,
                                                         float* __restrict__ chunkHS) {
  size_t state = (size_t)blockIdx.x * 256 + threadIdx.x;  // < 49152
  float h = 0.f;
#pragma unroll 4
  for (int j = 0; j < NCH; ++j) {
    size_t idx = (size_t)j * NSTATE + state;
    chunkHS[idx] = h;
    h = chunkP[idx] * h + chunkH[idx];
  }
}

__global__ __launch_bounds__(128) void scan_pass3_kernel(const float* __restrict__ xdbl,
                                                         const float* __restrict__ xxc,
                                                         const float* __restrict__ dtw,
                                                         const float* __restrict__ dtb,
                                                         const float* __restrict__ Alog,
                                                         const float* __restrict__ chunkHS,
                                                         float* __restrict__ ys) {
  int bi = blockIdx.x;
  int chunk = bi & 63;
  int bk = bi >> 6;
  int k = bk & 3, bl = bk >> 2;
  int d = threadIdx.x;
  float4 wv = *(const float4*)(dtw + (size_t)(((k << 7) + d) << 2));
  float bias = dtb[(k << 7) + d];
  float An2[16];
  {
    const float* ar = Alog + (size_t)(((k << 7) + d) << 4);
#pragma unroll
    for (int n = 0; n < 16; ++n) An2[n] = -__expf(ar[n]) * 1.44269504f;
  }
  __shared__ float xd[SCLEN][36];
  int l0 = chunk << 6;
  for (int idx = threadIdx.x; idx < 36 * SCLEN; idx += 128) {
    int c = idx >> 6, li = idx & 63;
    xd[li][c] = xdbl[((size_t)bk * 36 + c) * (size_t)NL + l0 + li];
  }
  __syncthreads();
  const float* uB = xxc + ((size_t)bl << 19) + d;
  float* yB = ys + ((size_t)bk << 19) + d;
  size_t base = (size_t)chunk * NSTATE + (((size_t)bk << 7) + (size_t)d) * 16;
  float h[16];
  {
    const float4* hp = (const float4*)(chunkHS + base);
    float4 h0 = hp[0], h1 = hp[1], h2 = hp[2], h3 = hp[3];
    h[0] = h0.x; h[1] = h0.y; h[2] = h0.z; h[3] = h0.w;
    h[4] = h1.x; h[5] = h1.y; h[6] = h1.z; h[7] = h1.w;
    h[8] = h2.x; h[9] = h2.y; h[10] = h2.z; h[11] = h2.w;
    h[12] = h3.x; h[13] = h3.y; h[14] = h3.z; h[15] = h3.w;
  }
#pragma unroll 2
  for (int li = 0; li < SCLEN; ++li) {
    int l = l0 + li;
    int pos = map_pos(k, l);
    const float4* row = (const float4*)&xd[li][0];
    float4 q0 = row[0];
    float acc = bias + wv.x * q0.x + wv.y * q0.y + wv.z * q0.z + wv.w * q0.w;
    float dt = (acc > 20.f) ? acc : log1pf(__expf(acc));
    float u = uB[(size_t)pos << 7];
    float dtu = dt * u;
    float4 b0 = row[1], b1 = row[2], b2 = row[3], b3 = row[4];
    float4 c0 = row[5], c1 = row[6], c2 = row[7], c3 = row[8];
    float Bv[16], Cv[16];
    Bv[0] = b0.x; Bv[1] = b0.y; Bv[2] = b0.z; Bv[3] = b0.w;
    Bv[4] = b1.x; Bv[5] = b1.y; Bv[6] = b1.z; Bv[7] = b1.w;
    Bv[8] = b2.x; Bv[9] = b2.y; Bv[10] = b2.z; Bv[11] = b2.w;
    Bv[12] = b3.x; Bv[13] = b3.y; Bv[14] = b3.z; Bv[15] = b3.w;
    Cv[0] = c0.x; Cv[1] = c0.y; Cv[2] = c0.z; Cv[3] = c0.w;
    Cv[4] = c1.x; Cv[5] = c1.y; Cv[6] = c1.z; Cv[7] = c1.w;
    Cv[8] = c2.x; Cv[9] = c2.y; Cv[10] = c2.z; Cv[11] = c2.w;
    Cv[12] = c3.x; Cv[13] = c3.y; Cv[14] = c3.z; Cv[15] = c3.w;
    float y = 0.f;
#pragma unroll
    for (int n = 0; n < 16; ++n) {
      h[n] = exp2f(An2[n] * dt) * h[n] + dtu * Bv[n];
      y += h[n] * Cv[n];
    }
    yB[(size_t)l << 7] = y;
  }
}

// ycomb[bl][p][d] = sum of 4 direction outputs (mapped) + xxc * sum_k Ds
__global__ __launch_bounds__(256) void combine_kernel(const float* __restrict__ ys,
                                                      const float* __restrict__ xxc,
                                                      const float* __restrict__ Ds,
                                                      float* __restrict__ ycomb) {
  size_t gid = (size_t)blockIdx.x * 256 + threadIdx.x;  // 6*4096*128
  int d = gid & 127;
  size_t pi = gid >> 7;
  int p = (int)(pi & 4095);
  int bl = (int)(pi >> 12);
  int h = p >> 6, w = p & 63;
  int l1 = (w << 6) | h;
  size_t base = ((size_t)bl * 4) << 12;
  float v = ys[((base + p) << 7) + d]
          + ys[((base + 4096 + l1) << 7) + d]
          + ys[((base + 2 * 4096 + (4095 - p)) << 7) + d]
          + ys[((base + 3 * 4096 + (4095 - l1)) << 7) + d];
  float ds = Ds[d] + Ds[128 + d] + Ds[256 + d] + Ds[384 + d];
  v += xxc[(pi << 7) + d] * ds;
  ycomb[(pi << 7) + d] = v;
}

// out_norm LN(128) -> *silu(z) -> out_proj 128->64 -> + x_res
__global__ __launch_bounds__(256) void outproj_kernel(const float* __restrict__ ycomb,
                                                      const float* __restrict__ z,
                                                      const float* __restrict__ ong,
                                                      const float* __restrict__ onb,
                                                      const float* __restrict__ opw,
                                                      const float* __restrict__ xres,
                                                      float* __restrict__ x1) {
  int wv = threadIdx.x >> 6, lane = threadIdx.x & 63;
  size_t pi = (size_t)blockIdx.x * 4 + wv;
  float y0 = ycomb[(pi << 7) + lane], y1 = ycomb[(pi << 7) + 64 + lane];
  float s = wred64(y0 + y1);
  float s2 = wred64(y0 * y0 + y1 * y1);
  float m = s * (1.f / 128), var = s2 * (1.f / 128) - m * m;
  float rstd = rsqrtf(var + 1e-5f);
  float z0 = z[(pi << 7) + lane], z1 = z[(pi << 7) + 64 + lane];
  float g0 = ((y0 - m) * rstd * ong[lane] + onb[lane]) * silu(z0);
  float g1 = ((y1 - m) * rstd * ong[64 + lane] + onb[64 + lane]) * silu(z1);
  __shared__ float gb[4][128];
  gb[wv][lane] = g0;
  gb[wv][64 + lane] = g1;
  __syncthreads();
  float acc = 0.f;
  const float* wrow = opw + (size_t)(lane << 7);
  for (int i4 = 0; i4 < 32; ++i4) {
    float4 w4 = *(const float4*)&wrow[i4 << 2];
    float4 g4 = *(const float4*)&gb[wv][i4 << 2];
    acc += w4.x * g4.x + w4.y * g4.y + w4.z * g4.z + w4.w * g4.w;
  }
  x1[pi * 64 + lane] = xres[pi * 64 + lane] + acc;
}

// ln2 -> fc1 -> gelu(tanh) -> fc2 -> residual; NHWC
__global__ __launch_bounds__(256) void mlp_kernel(const float* __restrict__ x1,
                                                  const float* __restrict__ g2,
                                                  const float* __restrict__ b2,
                                                  const float* __restrict__ w1,
                                                  const float* __restrict__ bb1,
                                                  const float* __restrict__ w2,
                                                  const float* __restrict__ bb2,
                                                  float* __restrict__ x2) {
  int wv = threadIdx.x >> 6, lane = threadIdx.x & 63;
  size_t pi = (size_t)blockIdx.x * 4 + wv;
  float xv = x1[pi * 64 + lane];
  float s = wred64(xv), s2 = wred64(xv * xv);
  float m = s * (1.f / 64), var = s2 * (1.f / 64) - m * m;
  float rstd = rsqrtf(var + 1e-5f);
  float xm = (xv - m) * rstd * g2[lane] + b2[lane];
  __shared__ float xb[4][64], tb[4][64];
  xb[wv][lane] = xm;
  __syncthreads();
  float acc = bb1[lane];
  const float* wr = w1 + (size_t)(lane << 6);
  for (int i4 = 0; i4 < 16; ++i4) {
    float4 w4 = *(const float4*)&wr[i4 << 2];
    float4 x4 = *(const float4*)&xb[wv][i4 << 2];
    acc += w4.x * x4.x + w4.y * x4.y + w4.z * x4.z + w4.w * x4.w;
  }
  float u = acc;
  float tt = tanhf(0.7978845608028654f * (u + 0.044715f * u * u * u));
  float t1 = 0.5f * u * (1.f + tt);
  tb[wv][lane] = t1;
  __syncthreads();
  float acc2 = bb2[lane];
  const float* wr2 = w2 + (size_t)(lane << 6);
  for (int i4 = 0; i4 < 16; ++i4) {
    float4 w4 = *(const float4*)&wr2[i4 << 2];
    float4 t4 = *(const float4*)&tb[wv][i4 << 2];
    acc2 += w4.x * t4.x + w4.y * t4.y + w4.z * t4.z + w4.w * t4.w;
  }
  x2[pi * 64 + lane] = xv + acc2;
}

// NHWC (bl,p,c) -> NCHW (bl,c,p) tiled transpose into d_out
__global__ __launch_bounds__(256) void transpose_out_kernel(const float* __restrict__ x2,
                                                            float* __restrict__ out) {
  int bi = blockIdx.x;  // NBL * 2 * 128
  int pt = bi & 127;
  int ct = (bi >> 7) & 1;
  int bl = bi >> 8;
  __shared__ float lds[32][33];
  int t = threadIdx.x;
  int j = t & 31, i0 = t >> 5;
  int p0 = pt << 5, c0 = ct << 5;
#pragma unroll
  for (int q = 0; q < 4; ++q) {
    int i = i0 + (q << 3);
    lds[i][j] = x2[((size_t)bl * NHW + p0 + i) * 64 + c0 + j];
  }
  __syncthreads();
#pragma unroll
  for (int q = 0; q < 4; ++q) {
    int i = i0 + (q << 3);
    out[((size_t)bl * 64 + c0 + i) * (size_t)NHW + p0 + j] = lds[j][i];
  }
}

extern "C" void kernel_launch(void* const* d_in, const int* in_sizes, int n_in,
                              void* d_out, int out_size, void* d_ws, size_t ws_size,
                              hipStream_t stream) {
  const float* img  = (const float*)d_in[0];
  const float* dz   = (const float*)d_in[1];
  const float* sg   = (const float*)d_in[2];
  const float* gn1g = (const float*)d_in[3];
  const float* gn1b = (const float*)d_in[4];
  const float* c1w  = (const float*)d_in[5];
  const float* c1b  = (const float*)d_in[6];
  const float* gn2g = (const float*)d_in[7];
  const float* gn2b = (const float*)d_in[8];
  const float* c2w  = (const float*)d_in[9];
  const float* c2b  = (const float*)d_in[10];
  const float* skw  = (const float*)d_in[11];
  const float* skb  = (const float*)d_in[12];
  const float* ln1g = (const float*)d_in[13];
  const float* ln1b = (const float*)d_in[14];
  const float* ln2g = (const float*)d_in[15];
  const float* ln2b = (const float*)d_in[16];
  const float* ipw  = (const float*)d_in[17];
  const float* dww  = (const float*)d_in[18];
  const float* dwb  = (const float*)d_in[19];
  const float* xpw  = (const float*)d_in[20];
  const float* dtw  = (const float*)d_in[21];
  const float* dtb  = (const float*)d_in[22];
  const float* Alog = (const float*)d_in[23];
  const float* Dsp  = (const float*)d_in[24];
  const float* ong  = (const float*)d_in[25];
  const float* onb  = (const float*)d_in[26];
  const float* opw  = (const float*)d_in[27];
  const float* f1w  = (const float*)d_in[28];
  const float* f1b  = (const float*)d_in[29];
  const float* f2w  = (const float*)d_in[30];
  const float* f2b  = (const float*)d_in[31];

  float* out = (float*)d_out;
  float* ws = (float*)d_ws;
  if (ws_size < F_TOTAL * sizeof(float)) return;

  float* xcat  = ws + F_XCAT;
  float* h1    = ws + F_H1;
  float* h2    = ws + F_H2;
  float* xres  = ws + F_XRES;
  float* xxin  = ws + F_XXIN;
  float* zbuf  = ws + F_Z;
  float* xxc   = ws + F_XXC;
  float* xdbl  = ws + F_XDBL;
  float* ysb   = ws + F_YS;
  float* ycomb = ws + F_YCOMB;
  float* x1    = ws + F_X1;
  float* x2    = ws + F_X2;
  float* stats = ws + F_STATS;
  // bf16 activation + weight-pack buffers (alias dead f32 regions)
  ushortT* act1b = (ushortT*)(ws + F_ACT1);          // 4.72M ushorts
  ushortT* act2b = (ushortT*)(ws + F_ACT2);          // 1.57M ushorts
  ushortT* wb1   = (ushortT*)(ws + F_YS + 8192);     // 110592 ushorts
  ushortT* wb2   = wb1 + 110592;                     // 36864 ushorts
  // scan chunk arrays alias buffers that are dead during the scan
  float* chunkP  = ws + F_XXIN;
  float* chunkH  = ws + F_YCOMB;
  float* chunkHS = ws + F_X1;
  // stats partials live at the head of the YS region (before wb1)
  double* part = (double*)(ws + F_YS);

  // weight prepacks (no deps — launch first)
  wprep_kernel<<<432, 256, 0, stream>>>(c1w, wb1, NC3, 6);
  wprep_kernel<<<144, 256, 0, stream>>>(c2w, wb2, NC, 2);
  // stage 0: instance-norm stats over image per (b,l)
  stats1_kernel<<<NBL * 32, 256, 0, stream>>>(img, NC * NHW, part);
  stats2_kernel<<<NBL, 64, 0, stream>>>(part, NC * NHW, stats + 0, stats + 8);
  build_xcat_kernel<<<18432, 256, 0, stream>>>(img, dz, sg, stats, xcat);
  // gn1 + silu -> NHWC bf16
  stats1_kernel<<<NBL * 32, 256, 0, stream>>>(xcat, NC3 * NHW, part);
  stats2_kernel<<<NBL, 64, 0, stream>>>(part, NC3 * NHW, stats + 16, stats + 24);
  gnsilu_t_kernel<NC3><<<NBL * 64, 256, 0, stream>>>(xcat, gn1g, gn1b, stats + 16, act1b);
  conv_mfma_kernel<NC3><<<NBL * 64 * 2, 256, 0, stream>>>(act1b, wb1, c1b, h1);
  // gn2 + silu -> NHWC bf16
  stats1_kernel<<<NBL * 32, 256, 0, stream>>>(h1, NC * NHW, part);
  stats2_kernel<<<NBL, 64, 0, stream>>>(part, NC * NHW, stats + 32, stats + 40);
  gnsilu_t_kernel<NC><<<NBL * 64, 256, 0, stream>>>(h1, gn2g, gn2b, stats + 32, act2b);
  conv_mfma_kernel<NC><<<NBL * 64 * 2, 256, 0, stream>>>(act2b, wb2, c2b, h2);
  // skip 1x1 + residual + NHWC transpose
  skip_kernel<<<NBL * 64, 256, 0, stream>>>(xcat, h2, skw, skb, xres);
  // SS2D
  inproj_kernel<<<6144, 256, 0, stream>>>(xres, ln1g, ln1b, ipw, xxin, zbuf);
  dwconv_kernel<<<12288, 256, 0, stream>>>(xxin, dww, dwb, xxc);
  xdbl_kernel<<<NBL * NK * 64, 256, 0, stream>>>(xxc, xpw, xdbl);
  // chunked scan (dt computed inline; no delta buffer)
  scan_pass1_kernel<<<24 * 64, 128, 0, stream>>>(xdbl, xxc, dtw, dtb, Alog, chunkP, chunkH);
  scan_pass2_kernel<<<192, 256, 0, stream>>>(chunkP, chunkH, chunkHS);
  scan_pass3_kernel<<<24 * 64, 128, 0, stream>>>(xdbl, xxc, dtw, dtb, Alog, chunkHS, ysb);
  combine_kernel<<<12288, 256, 0, stream>>>(ysb, xxc, Dsp, ycomb);
  outproj_kernel<<<6144, 256, 0, stream>>>(ycomb, zbuf, ong, onb, opw, xres, x1);
  // MLP + residual
  mlp_kernel<<<6144, 256, 0, stream>>>(x1, ln2g, ln2b, f1w, f1b, f2w, f2b, x2);
  // final transpose to NCHW output
  transpose_out_kernel<<<NBL * 256, 256, 0, stream>>>(x2, out);
}

// Round 6
// 681.885 us; speedup vs baseline: 1.6940x; 1.3307x over previous
//
#include <hip/hip_runtime.h>
#include <hip/hip_bf16.h>

typedef unsigned short ushortT;
typedef short short8v __attribute__((ext_vector_type(8)));
typedef float float4v __attribute__((ext_vector_type(4)));

// Problem constants
#define NBL 6      // B*LEN
#define NC 64
#define NC3 192
#define NHW 4096   // 64*64
#define NDI 128
#define NNS 16
#define NDR 4
#define NK 4
#define NL 4096
#define NCH 64     // scan chunks
#define SCLEN 64   // chunk length
#define NSTATE 49152  // 24 bk * 128 d * 16 n

// workspace offsets in floats
static const size_t F_XCAT  = 0;          // 6*192*4096 = 4,718,592 (wt_ip after skip)
static const size_t F_ACT1  = 4718592;    // act1b bf16 NHWC; wt_sk after conv1
static const size_t F_H1    = 9437184;    // 1,572,864
static const size_t F_ACT2  = 11010048;   // act2b bf16 NHWC (1.57M ushorts)
static const size_t F_H2    = 12582912;   // 1,572,864
static const size_t F_XRES  = 14155776;   // 1,572,864
static const size_t F_XXIN  = 15728640;   // 3,145,728 (chunkP during scan; wt_op/f1/f2 after pass2)
static const size_t F_Z     = 18874368;   // 3,145,728
static const size_t F_XXC   = 22020096;   // 3,145,728
static const size_t F_XDBL  = 25165824;   // 6*4*36*4096 = 3,538,944
static const size_t F_YS    = 28704768;   // 12,582,912 (stats partials + conv wpacks early, ys later)
static const size_t F_YCOMB = 41287680;   // 3,145,728  (chunkH during scan)
static const size_t F_X1    = 44433408;   // 1,572,864  (X1+X2 -> chunkHS during scan)
static const size_t F_X2    = 46006272;   // 1,572,864
static const size_t F_STATS = 47579136;   // 48
static const size_t F_TOTAL = 47579184;   // floats (~190.3 MB)

__device__ __forceinline__ float wred64(float v) {
#pragma unroll
  for (int m = 32; m; m >>= 1) v += __shfl_xor(v, m, 64);
  return v;
}

__device__ __forceinline__ float silu(float v) {
  return v / (1.f + __expf(-v));
}

__device__ __forceinline__ ushortT f2bf(float f) {
  unsigned int u = __builtin_bit_cast(unsigned int, f);
  unsigned int r = (u + 0x7FFFu + ((u >> 16) & 1u)) >> 16;
  return (ushortT)r;
}

__device__ __forceinline__ int map_pos(int k, int l) {
  if (k == 0) return l;
  if (k == 1) return ((l & 63) << 6) | (l >> 6);
  if (k == 2) return 4095 - l;
  int lp = 4095 - l;
  return ((lp & 63) << 6) | (lp >> 6);
}

// generic weight transpose: dst[c*O + o] = src[o*C + c]
__global__ __launch_bounds__(256) void wtrans_kernel(const float* __restrict__ src,
                                                     float* __restrict__ dst, int O, int C) {
  int id = blockIdx.x * 256 + threadIdx.x;
  if (id >= O * C) return;
  int c = id / O, o = id % O;
  dst[id] = src[o * C + c];
}

// ---- two-stage per-sample mean/rstd (f64 accumulate) ----
__global__ __launch_bounds__(256) void stats1_kernel(const float* __restrict__ in, int n,
                                                     double* __restrict__ part) {
  int bi = blockIdx.x;
  int s = bi >> 5, j = bi & 31;
  int slice = n >> 5;
  const float4* p = (const float4*)(in + (size_t)s * n + (size_t)j * slice);
  int n4 = slice >> 2;
  double dsum = 0.0, dsq = 0.0;
  for (int i = threadIdx.x; i < n4; i += 256) {
    float4 v = p[i];
    dsum += (double)((v.x + v.y) + (v.z + v.w));
    dsq += (double)v.x * v.x + (double)v.y * v.y + (double)v.z * v.z + (double)v.w * v.w;
  }
  __shared__ double s1[256], s2[256];
  s1[threadIdx.x] = dsum; s2[threadIdx.x] = dsq;
  __syncthreads();
  for (int off = 128; off; off >>= 1) {
    if (threadIdx.x < off) { s1[threadIdx.x] += s1[threadIdx.x + off]; s2[threadIdx.x] += s2[threadIdx.x + off]; }
    __syncthreads();
  }
  if (threadIdx.x == 0) { part[2 * bi] = s1[0]; part[2 * bi + 1] = s2[0]; }
}

__global__ __launch_bounds__(64) void stats2_kernel(const double* __restrict__ part, int n,
                                                    float* __restrict__ mean_out,
                                                    float* __restrict__ rstd_out) {
  int s = blockIdx.x;
  int lane = threadIdx.x;
  double sum = 0.0, sq = 0.0;
  if (lane < 32) { sum = part[2 * (s * 32 + lane)]; sq = part[2 * (s * 32 + lane) + 1]; }
#pragma unroll
  for (int m = 16; m; m >>= 1) { sum += __shfl_xor(sum, m, 64); sq += __shfl_xor(sq, m, 64); }
  if (lane == 0) {
    double mean = sum / n;
    double var = sq / n - mean * mean;
    mean_out[s] = (float)mean;
    rstd_out[s] = (float)(1.0 / sqrt(var + 1e-5));
  }
}

// x_cat[bl][ch][p]: ch<64 dz, 64..127 instance-normed img, 128..191 sigma
__global__ __launch_bounds__(256) void build_xcat_kernel(const float* __restrict__ img,
                                                         const float* __restrict__ dz,
                                                         const float* __restrict__ sg,
                                                         const float* __restrict__ stats,
                                                         float* __restrict__ xcat) {
  size_t gid = (size_t)blockIdx.x * 256 + threadIdx.x;
  int p = gid & 4095;
  size_t r = gid >> 12;
  int ch = (int)(r % NC3);
  int bl = (int)(r / NC3);
  int b = bl / 3;
  float v;
  if (ch < 64) {
    v = dz[((size_t)b * NC + ch) * NHW + p];
  } else if (ch < 128) {
    float m = stats[bl], rs = stats[8 + bl];
    v = (img[((size_t)bl * NC + (ch - 64)) * NHW + p] - m) * rs;
  } else {
    v = sg[((size_t)b * NC + (ch - 128)) * NHW + p];
  }
  xcat[gid] = v;
}

// GN + SiLU + NCHW->NHWC transpose + f32->bf16. grid NBL*64, block 256.
template <int CCH>
__global__ __launch_bounds__(256) void gnsilu_t_kernel(const float* __restrict__ in,
                                                       const float* __restrict__ g,
                                                       const float* __restrict__ b,
                                                       const float* __restrict__ stats,
                                                       ushortT* __restrict__ outb) {
  int bi = blockIdx.x;
  int bl = bi >> 6, h = bi & 63;
  __shared__ ushortT tile[CCH][66];
  float m = stats[bl], rs = stats[8 + bl];
  int t = threadIdx.x;
  for (int idx = t; idx < CCH * 64; idx += 256) {
    int ch = idx >> 6, w = idx & 63;
    float v = in[(((size_t)bl * CCH + ch) << 12) + (h << 6) + w];
    v = (v - m) * rs * g[ch] + b[ch];
    v = silu(v);
    tile[ch][w] = f2bf(v);
  }
  __syncthreads();
  constexpr int C8 = CCH / 8;
  for (int idx = t; idx < 64 * C8; idx += 256) {
    int w = idx / C8, c8 = idx % C8;
    short8v v;
#pragma unroll
    for (int j = 0; j < 8; ++j) v[j] = (short)tile[c8 * 8 + j][w];
    *(short8v*)&outb[(size_t)(bl * 4096 + h * 64 + w) * CCH + c8 * 8] = v;
  }
}

// Pre-pack conv weights into per-lane MFMA B-fragments (bf16).
__global__ __launch_bounds__(256) void wprep_kernel(const float* __restrict__ w,
                                                    ushortT* __restrict__ out,
                                                    int CIN, int KT) {
  int id = blockIdx.x * 256 + threadIdx.x;
  int j = id & 7;
  int lane = (id >> 3) & 63;
  int nt = (id >> 9) & 3;
  int rest = id >> 11;
  int kt = rest % KT;
  int tap = rest / KT;
  int oc = nt * 16 + (lane & 15);
  int ic = kt * 32 + ((lane >> 4) << 3) + j;
  int r = tap / 3, s = tap % 3;
  out[id] = f2bf(w[(((size_t)oc * CIN + ic) * 3 + r) * 3 + s]);
}

// Implicit-GEMM 3x3 SAME conv via bf16 MFMA, f32 accumulate.
template <int CIN>
__global__ __launch_bounds__(256) void conv_mfma_kernel(const ushortT* __restrict__ actb,
                                                        const ushortT* __restrict__ wb,
                                                        const float* __restrict__ bias,
                                                        float* __restrict__ out) {
  constexpr int KT = CIN / 32;
  constexpr int STRIDE = CIN + 8;
  constexpr int C8 = CIN / 8;
  int bi = blockIdx.x;
  int nh = bi & 1;
  int h = (bi >> 1) & 63;
  int bl = bi >> 7;
  int t = threadIdx.x;
  int wv = t >> 6, lane = t & 63;
  __shared__ ushortT lds[66 * STRIDE];
  float4v acc0 = {0.f, 0.f, 0.f, 0.f};
  float4v acc1 = {0.f, 0.f, 0.f, 0.f};
  int lrow = lane & 15;
  int lk = (lane >> 4) << 3;
  for (int dy = 0; dy < 3; ++dy) {
    int hh = h + dy - 1;
    bool valid = (hh >= 0) && (hh < 64);
    int hc = valid ? hh : 0;
    if (dy) __syncthreads();
    const ushortT* src = actb + (size_t)(bl * 4096 + hc * 64) * CIN;
    for (int idx = t; idx < 64 * C8; idx += 256) {
      int w = idx / C8, c8 = idx % C8;
      short8v v = {0, 0, 0, 0, 0, 0, 0, 0};
      if (valid) v = *(const short8v*)&src[(size_t)w * CIN + c8 * 8];
      *(short8v*)&lds[(w + 1) * STRIDE + c8 * 8] = v;
    }
    if (t < 2 * C8) {
      int which = t / C8, c8 = t % C8;
      short8v z = {0, 0, 0, 0, 0, 0, 0, 0};
      *(short8v*)&lds[(which ? 65 : 0) * STRIDE + c8 * 8] = z;
    }
    __syncthreads();
    for (int dx = 0; dx < 3; ++dx) {
      int tap = dy * 3 + dx;
      int wl = (wv << 4) + lrow + dx;
#pragma unroll
      for (int kt = 0; kt < KT; ++kt) {
        short8v a = *(const short8v*)&lds[wl * STRIDE + kt * 32 + lk];
        const ushortT* wp = wb + ((size_t)(((tap * KT + kt) * 4 + (nh << 1)) * 64 + lane) << 3);
        short8v b0 = *(const short8v*)&wp[0];
        short8v b1 = *(const short8v*)&wp[512];
        acc0 = __builtin_amdgcn_mfma_f32_16x16x32_bf16(a, b0, acc0, 0, 0, 0);
        acc1 = __builtin_amdgcn_mfma_f32_16x16x32_bf16(a, b1, acc1, 0, 0, 0);
      }
    }
  }
  int oc0 = (nh << 5) + lrow;
  int oc1 = oc0 + 16;
  int w0 = (wv << 4) + ((lane >> 4) << 2);
  float bv0 = bias[oc0], bv1 = bias[oc1];
  float4 o0 = make_float4(acc0[0] + bv0, acc0[1] + bv0, acc0[2] + bv0, acc0[3] + bv0);
  float4 o1 = make_float4(acc1[0] + bv1, acc1[1] + bv1, acc1[2] + bv1, acc1[3] + bv1);
  *(float4*)&out[(((size_t)bl * 64 + oc0) << 12) + (h << 6) + w0] = o0;
  *(float4*)&out[(((size_t)bl * 64 + oc1) << 12) + (h << 6) + w0] = o1;
}

// x_res[bl][p][oc] = h2[bl][oc][p] + 1x1skip(xcat)[oc] + skb[oc]   (NHWC out)
// skwt layout: [ch(192)][oc(64)] transposed -> coalesced over oc=lane
__global__ __launch_bounds__(256) void skip_kernel(const float* __restrict__ xcat,
                                                   const float* __restrict__ h2,
                                                   const float* __restrict__ skwt,
                                                   const float* __restrict__ skb,
                                                   float* __restrict__ xres) {
  int bi = blockIdx.x;
  int bl = bi >> 6, h = bi & 63;
  int t = threadIdx.x;
  int oc = t & 63, w0 = (t >> 6) << 4;
  __shared__ float lds[64][64];
  float acc[16];
#pragma unroll
  for (int i = 0; i < 16; ++i) acc[i] = 0.f;
  for (int cc = 0; cc < 3; ++cc) {
    __syncthreads();
    for (int idx = t; idx < 4096; idx += 256) {
      int ch = idx >> 6, w = idx & 63;
      lds[ch][w] = xcat[(((size_t)bl * NC3 + cc * 64 + ch) << 12) + (h << 6) + w];
    }
    __syncthreads();
    for (int ch = 0; ch < 64; ++ch) {
      float wv = skwt[((cc << 6) + ch) * 64 + oc];
#pragma unroll
      for (int i = 0; i < 16; ++i) acc[i] += wv * lds[ch][w0 + i];
    }
  }
  float bv = skb[oc];
  int p0 = (h << 6) + w0;
#pragma unroll
  for (int i = 0; i < 16; ++i) {
    float hv = h2[(((size_t)bl * 64 + oc) << 12) + p0 + i];
    xres[((size_t)bl * NHW + p0 + i) * 64 + oc] = acc[i] + bv + hv;
  }
}

// LN(ln1) + 64->256 proj, transposed weight wt[c(64)][oc(256)].
// Block = 4 positions; wave wv computes oc quarter [wv*64, wv*64+64) for ALL 4 positions.
__global__ __launch_bounds__(256) void inproj_kernel(const float* __restrict__ xres,
                                                     const float* __restrict__ g,
                                                     const float* __restrict__ b,
                                                     const float* __restrict__ wt,
                                                     float* __restrict__ xxin,
                                                     float* __restrict__ z) {
  int wv = threadIdx.x >> 6, lane = threadIdx.x & 63;
  size_t pi0 = (size_t)blockIdx.x * 4;
  size_t pi = pi0 + wv;
  float x = xres[pi * 64 + lane];
  float s = wred64(x);
  float s2 = wred64(x * x);
  float m = s * (1.f / 64), var = s2 * (1.f / 64) - m * m;
  float rstd = rsqrtf(var + 1e-5f);
  float xln = (x - m) * rstd * g[lane] + b[lane];
  __shared__ float xb[64][4];
  xb[lane][wv] = xln;
  __syncthreads();
  float acc[4] = {0.f, 0.f, 0.f, 0.f};
  int oc = (wv << 6) + lane;
  for (int c = 0; c < 64; ++c) {
    float4 xv = *(const float4*)&xb[c][0];       // uniform b128 broadcast
    float w = wt[(c << 8) + oc];                 // coalesced 256B per wave
    acc[0] += w * xv.x; acc[1] += w * xv.y; acc[2] += w * xv.z; acc[3] += w * xv.w;
  }
#pragma unroll
  for (int p = 0; p < 4; ++p) {
    size_t pp = pi0 + p;
    if (oc < 128) xxin[(pp << 7) + oc] = acc[p];
    else z[(pp << 7) + (oc - 128)] = acc[p];
  }
}

// depthwise 3x3 SAME + bias + silu on NHWC [bl][p][128]
__global__ __launch_bounds__(256) void dwconv_kernel(const float* __restrict__ xx,
                                                     const float* __restrict__ w,
                                                     const float* __restrict__ b,
                                                     float* __restrict__ out) {
  size_t gid = (size_t)blockIdx.x * 256 + threadIdx.x;
  int d = gid & 127;
  size_t pi = gid >> 7;
  int p = (int)(pi & 4095);
  int bl = (int)(pi >> 12);
  int h = p >> 6, wq = p & 63;
  float acc = b[d];
  const float* wr = w + d * 9;
#pragma unroll
  for (int dy = -1; dy <= 1; ++dy) {
    int hh = h + dy;
    if (hh < 0 || hh >= 64) continue;
#pragma unroll
    for (int dx = -1; dx <= 1; ++dx) {
      int ww = wq + dx;
      if (ww < 0 || ww >= 64) continue;
      acc += wr[(dy + 1) * 3 + (dx + 1)] * xx[(((size_t)bl << 12) + (hh << 6) + ww) * 128 + d];
    }
  }
  out[pi * 128 + d] = silu(acc);
}

// x_dbl[bk][c][l] = sum_d xpw[k][c][d] * xs[bk][d][l]
__global__ __launch_bounds__(256) void xdbl_kernel(const float* __restrict__ xxc,
                                                   const float* __restrict__ xpw,
                                                   float* __restrict__ xdbl) {
  int bi = blockIdx.x;
  int lt = bi & 63;
  int k = (bi >> 6) & 3;
  int bl = bi >> 8;
  int lbase = lt << 6;
  __shared__ float lds[64][132];
  int t = threadIdx.x;
  for (int idx = t; idx < 64 * 128; idx += 256) {
    int i = idx >> 7, d = idx & 127;
    int pos = map_pos(k, lbase + i);
    lds[i][d] = xxc[((size_t)bl * NHW + pos) * 128 + d];
  }
  __syncthreads();
  for (int oi = t; oi < 36 * 64; oi += 256) {
    int c = oi >> 6, l = oi & 63;
    const float* wrow = xpw + (k * 36 + c) * 128;
    float acc = 0.f;
    for (int d4 = 0; d4 < 32; ++d4) {
      float4 w4 = *(const float4*)&wrow[d4 << 2];
      float4 x4 = *(const float4*)&lds[l][d4 << 2];
      acc += w4.x * x4.x + w4.y * x4.y + w4.z * x4.z + w4.w * x4.w;
    }
    xdbl[(((size_t)(bl * 4 + k)) * 36 + c) * (size_t)NL + lbase + l] = acc;
  }
}

// ---- chunked selective scan, per-thread 16-state version ----
__global__ __launch_bounds__(128) void scan_pass1_kernel(const float* __restrict__ xdbl,
                                                         const float* __restrict__ xxc,
                                                         const float* __restrict__ dtw,
                                                         const float* __restrict__ dtb,
                                                         const float* __restrict__ Alog,
                                                         float* __restrict__ chunkP,
                                                         float* __restrict__ chunkH) {
  int bi = blockIdx.x;
  int chunk = bi & 63;
  int bk = bi >> 6;
  int k = bk & 3, bl = bk >> 2;
  int d = threadIdx.x;
  float4 wv = *(const float4*)(dtw + (size_t)(((k << 7) + d) << 2));
  float bias = dtb[(k << 7) + d];
  float An2[16];
  {
    const float* ar = Alog + (size_t)(((k << 7) + d) << 4);
#pragma unroll
    for (int n = 0; n < 16; ++n) An2[n] = -__expf(ar[n]) * 1.44269504f;
  }
  __shared__ float xd[SCLEN][36];
  int l0 = chunk << 6;
  for (int idx = threadIdx.x; idx < 36 * SCLEN; idx += 128) {
    int c = idx >> 6, li = idx & 63;
    xd[li][c] = xdbl[((size_t)bk * 36 + c) * (size_t)NL + l0 + li];
  }
  __syncthreads();
  const float* uB = xxc + ((size_t)bl << 19) + d;
  float h[16];
#pragma unroll
  for (int n = 0; n < 16; ++n) h[n] = 0.f;
  float sdt = 0.f;
#pragma unroll 2
  for (int li = 0; li < SCLEN; ++li) {
    int l = l0 + li;
    int pos = map_pos(k, l);
    const float4* row = (const float4*)&xd[li][0];
    float4 q0 = row[0];
    float acc = bias + wv.x * q0.x + wv.y * q0.y + wv.z * q0.z + wv.w * q0.w;
    float dt = (acc > 20.f) ? acc : log1pf(__expf(acc));
    float u = uB[(size_t)pos << 7];
    float dtu = dt * u;
    sdt += dt;
    float4 b0 = row[1], b1 = row[2], b2 = row[3], b3 = row[4];
    float Bv[16];
    Bv[0] = b0.x; Bv[1] = b0.y; Bv[2] = b0.z; Bv[3] = b0.w;
    Bv[4] = b1.x; Bv[5] = b1.y; Bv[6] = b1.z; Bv[7] = b1.w;
    Bv[8] = b2.x; Bv[9] = b2.y; Bv[10] = b2.z; Bv[11] = b2.w;
    Bv[12] = b3.x; Bv[13] = b3.y; Bv[14] = b3.z; Bv[15] = b3.w;
#pragma unroll
    for (int n = 0; n < 16; ++n) h[n] = exp2f(An2[n] * dt) * h[n] + dtu * Bv[n];
  }
  size_t base = (size_t)chunk * NSTATE + (((size_t)bk << 7) + (size_t)d) * 16;
#pragma unroll
  for (int n = 0; n < 16; ++n) {
    chunkP[base + n] = exp2f(An2[n] * sdt);
    chunkH[base + n] = h[n];
  }
}

__global__ __launch_bounds__(256) void scan_pass2_kernel(const float* __restrict__ chunkP,
                                                         const float* __restrict__ chunkH,
                                                         float* __restrict__ chunkHS) {
  size_t state = (size_t)blockIdx.x * 256 + threadIdx.x;
  float h = 0.f;
#pragma unroll 4
  for (int j = 0; j < NCH; ++j) {
    size_t idx = (size_t)j * NSTATE + state;
    chunkHS[idx] = h;
    h = chunkP[idx] * h + chunkH[idx];
  }
}

__global__ __launch_bounds__(128) void scan_pass3_kernel(const float* __restrict__ xdbl,
                                                         const float* __restrict__ xxc,
                                                         const float* __restrict__ dtw,
                                                         const float* __restrict__ dtb,
                                                         const float* __restrict__ Alog,
                                                         const float* __restrict__ chunkHS,
                                                         float* __restrict__ ys) {
  int bi = blockIdx.x;
  int chunk = bi & 63;
  int bk = bi >> 6;
  int k = bk & 3, bl = bk >> 2;
  int d = threadIdx.x;
  float4 wv = *(const float4*)(dtw + (size_t)(((k << 7) + d) << 2));
  float bias = dtb[(k << 7) + d];
  float An2[16];
  {
    const float* ar = Alog + (size_t)(((k << 7) + d) << 4);
#pragma unroll
    for (int n = 0; n < 16; ++n) An2[n] = -__expf(ar[n]) * 1.44269504f;
  }
  __shared__ float xd[SCLEN][36];
  int l0 = chunk << 6;
  for (int idx = threadIdx.x; idx < 36 * SCLEN; idx += 128) {
    int c = idx >> 6, li = idx & 63;
    xd[li][c] = xdbl[((size_t)bk * 36 + c) * (size_t)NL + l0 + li];
  }
  __syncthreads();
  const float* uB = xxc + ((size_t)bl << 19) + d;
  float* yB = ys + ((size_t)bk << 19) + d;
  size_t base = (size_t)chunk * NSTATE + (((size_t)bk << 7) + (size_t)d) * 16;
  float h[16];
  {
    const float4* hp = (const float4*)(chunkHS + base);
    float4 h0 = hp[0], h1 = hp[1], h2 = hp[2], h3 = hp[3];
    h[0] = h0.x; h[1] = h0.y; h[2] = h0.z; h[3] = h0.w;
    h[4] = h1.x; h[5] = h1.y; h[6] = h1.z; h[7] = h1.w;
    h[8] = h2.x; h[9] = h2.y; h[10] = h2.z; h[11] = h2.w;
    h[12] = h3.x; h[13] = h3.y; h[14] = h3.z; h[15] = h3.w;
  }
#pragma unroll 2
  for (int li = 0; li < SCLEN; ++li) {
    int l = l0 + li;
    int pos = map_pos(k, l);
    const float4* row = (const float4*)&xd[li][0];
    float4 q0 = row[0];
    float acc = bias + wv.x * q0.x + wv.y * q0.y + wv.z * q0.z + wv.w * q0.w;
    float dt = (acc > 20.f) ? acc : log1pf(__expf(acc));
    float u = uB[(size_t)pos << 7];
    float dtu = dt * u;
    float4 b0 = row[1], b1 = row[2], b2 = row[3], b3 = row[4];
    float4 c0 = row[5], c1 = row[6], c2 = row[7], c3 = row[8];
    float Bv[16], Cv[16];
    Bv[0] = b0.x; Bv[1] = b0.y; Bv[2] = b0.z; Bv[3] = b0.w;
    Bv[4] = b1.x; Bv[5] = b1.y; Bv[6] = b1.z; Bv[7] = b1.w;
    Bv[8] = b2.x; Bv[9] = b2.y; Bv[10] = b2.z; Bv[11] = b2.w;
    Bv[12] = b3.x; Bv[13] = b3.y; Bv[14] = b3.z; Bv[15] = b3.w;
    Cv[0] = c0.x; Cv[1] = c0.y; Cv[2] = c0.z; Cv[3] = c0.w;
    Cv[4] = c1.x; Cv[5] = c1.y; Cv[6] = c1.z; Cv[7] = c1.w;
    Cv[8] = c2.x; Cv[9] = c2.y; Cv[10] = c2.z; Cv[11] = c2.w;
    Cv[12] = c3.x; Cv[13] = c3.y; Cv[14] = c3.z; Cv[15] = c3.w;
    float y = 0.f;
#pragma unroll
    for (int n = 0; n < 16; ++n) {
      h[n] = exp2f(An2[n] * dt) * h[n] + dtu * Bv[n];
      y += h[n] * Cv[n];
    }
    yB[(size_t)l << 7] = y;
  }
}

// ycomb[bl][p][d] = sum of 4 direction outputs (mapped) + xxc * sum_k Ds
__global__ __launch_bounds__(256) void combine_kernel(const float* __restrict__ ys,
                                                      const float* __restrict__ xxc,
                                                      const float* __restrict__ Ds,
                                                      float* __restrict__ ycomb) {
  size_t gid = (size_t)blockIdx.x * 256 + threadIdx.x;
  int d = gid & 127;
  size_t pi = gid >> 7;
  int p = (int)(pi & 4095);
  int bl = (int)(pi >> 12);
  int h = p >> 6, w = p & 63;
  int l1 = (w << 6) | h;
  size_t base = ((size_t)bl * 4) << 12;
  float v = ys[((base + p) << 7) + d]
          + ys[((base + 4096 + l1) << 7) + d]
          + ys[((base + 2 * 4096 + (4095 - p)) << 7) + d]
          + ys[((base + 3 * 4096 + (4095 - l1)) << 7) + d];
  float ds = Ds[d] + Ds[128 + d] + Ds[256 + d] + Ds[384 + d];
  v += xxc[(pi << 7) + d] * ds;
  ycomb[(pi << 7) + d] = v;
}

// out_norm LN(128) -> *silu(z) -> out_proj (transposed wt[c(128)][oc(64)]) -> + x_res
__global__ __launch_bounds__(256) void outproj_kernel(const float* __restrict__ ycomb,
                                                      const float* __restrict__ z,
                                                      const float* __restrict__ ong,
                                                      const float* __restrict__ onb,
                                                      const float* __restrict__ opwt,
                                                      const float* __restrict__ xres,
                                                      float* __restrict__ x1) {
  int wv = threadIdx.x >> 6, lane = threadIdx.x & 63;
  size_t pi = (size_t)blockIdx.x * 4 + wv;
  float y0 = ycomb[(pi << 7) + lane], y1 = ycomb[(pi << 7) + 64 + lane];
  float s = wred64(y0 + y1);
  float s2 = wred64(y0 * y0 + y1 * y1);
  float m = s * (1.f / 128), var = s2 * (1.f / 128) - m * m;
  float rstd = rsqrtf(var + 1e-5f);
  float z0 = z[(pi << 7) + lane], z1 = z[(pi << 7) + 64 + lane];
  float g0 = ((y0 - m) * rstd * ong[lane] + onb[lane]) * silu(z0);
  float g1 = ((y1 - m) * rstd * ong[64 + lane] + onb[64 + lane]) * silu(z1);
  __shared__ float gb[128][4];
  gb[lane][wv] = g0;
  gb[64 + lane][wv] = g1;
  __syncthreads();
  float acc = 0.f;
  for (int c = 0; c < 128; ++c) {
    acc += opwt[(c << 6) + lane] * gb[c][wv];   // coalesced weight, uniform LDS
  }
  x1[pi * 64 + lane] = xres[pi * 64 + lane] + acc;
}

// ln2 -> fc1 -> gelu(tanh) -> fc2 -> residual; transposed weights wt[c][oc]
__global__ __launch_bounds__(256) void mlp_kernel(const float* __restrict__ x1,
                                                  const float* __restrict__ g2,
                                                  const float* __restrict__ b2,
                                                  const float* __restrict__ w1t,
                                                  const float* __restrict__ bb1,
                                                  const float* __restrict__ w2t,
                                                  const float* __restrict__ bb2,
                                                  float* __restrict__ x2) {
  int wv = threadIdx.x >> 6, lane = threadIdx.x & 63;
  size_t pi = (size_t)blockIdx.x * 4 + wv;
  float xv = x1[pi * 64 + lane];
  float s = wred64(xv), s2 = wred64(xv * xv);
  float m = s * (1.f / 64), var = s2 * (1.f / 64) - m * m;
  float rstd = rsqrtf(var + 1e-5f);
  float xm = (xv - m) * rstd * g2[lane] + b2[lane];
  __shared__ float xb[64][4], tb[64][4];
  xb[lane][wv] = xm;
  __syncthreads();
  float acc = bb1[lane];
  for (int c = 0; c < 64; ++c) acc += w1t[(c << 6) + lane] * xb[c][wv];
  float u = acc;
  float tt = tanhf(0.7978845608028654f * (u + 0.044715f * u * u * u));
  float t1 = 0.5f * u * (1.f + tt);
  tb[lane][wv] = t1;
  __syncthreads();
  float acc2 = bb2[lane];
  for (int c = 0; c < 64; ++c) acc2 += w2t[(c << 6) + lane] * tb[c][wv];
  x2[pi * 64 + lane] = xv + acc2;
}

// NHWC (bl,p,c) -> NCHW (bl,c,p) tiled transpose into d_out
__global__ __launch_bounds__(256) void transpose_out_kernel(const float* __restrict__ x2,
                                                            float* __restrict__ out) {
  int bi = blockIdx.x;
  int pt = bi & 127;
  int ct = (bi >> 7) & 1;
  int bl = bi >> 8;
  __shared__ float lds[32][33];
  int t = threadIdx.x;
  int j = t & 31, i0 = t >> 5;
  int p0 = pt << 5, c0 = ct << 5;
#pragma unroll
  for (int q = 0; q < 4; ++q) {
    int i = i0 + (q << 3);
    lds[i][j] = x2[((size_t)bl * NHW + p0 + i) * 64 + c0 + j];
  }
  __syncthreads();
#pragma unroll
  for (int q = 0; q < 4; ++q) {
    int i = i0 + (q << 3);
    out[((size_t)bl * 64 + c0 + i) * (size_t)NHW + p0 + j] = lds[j][i];
  }
}

extern "C" void kernel_launch(void* const* d_in, const int* in_sizes, int n_in,
                              void* d_out, int out_size, void* d_ws, size_t ws_size,
                              hipStream_t stream) {
  const float* img  = (const float*)d_in[0];
  const float* dz   = (const float*)d_in[1];
  const float* sg   = (const float*)d_in[2];
  const float* gn1g = (const float*)d_in[3];
  const float* gn1b = (const float*)d_in[4];
  const float* c1w  = (const float*)d_in[5];
  const float* c1b  = (const float*)d_in[6];
  const float* gn2g = (const float*)d_in[7];
  const float* gn2b = (const float*)d_in[8];
  const float* c2w  = (const float*)d_in[9];
  const float* c2b  = (const float*)d_in[10];
  const float* skw  = (const float*)d_in[11];
  const float* skb  = (const float*)d_in[12];
  const float* ln1g = (const float*)d_in[13];
  const float* ln1b = (const float*)d_in[14];
  const float* ln2g = (const float*)d_in[15];
  const float* ln2b = (const float*)d_in[16];
  const float* ipw  = (const float*)d_in[17];
  const float* dww  = (const float*)d_in[18];
  const float* dwb  = (const float*)d_in[19];
  const float* xpw  = (const float*)d_in[20];
  const float* dtw  = (const float*)d_in[21];
  const float* dtb  = (const float*)d_in[22];
  const float* Alog = (const float*)d_in[23];
  const float* Dsp  = (const float*)d_in[24];
  const float* ong  = (const float*)d_in[25];
  const float* onb  = (const float*)d_in[26];
  const float* opw  = (const float*)d_in[27];
  const float* f1w  = (const float*)d_in[28];
  const float* f1b  = (const float*)d_in[29];
  const float* f2w  = (const float*)d_in[30];
  const float* f2b  = (const float*)d_in[31];

  float* out = (float*)d_out;
  float* ws = (float*)d_ws;
  if (ws_size < F_TOTAL * sizeof(float)) return;

  float* xcat  = ws + F_XCAT;
  float* h1    = ws + F_H1;
  float* h2    = ws + F_H2;
  float* xres  = ws + F_XRES;
  float* xxin  = ws + F_XXIN;
  float* zbuf  = ws + F_Z;
  float* xxc   = ws + F_XXC;
  float* xdbl  = ws + F_XDBL;
  float* ysb   = ws + F_YS;
  float* ycomb = ws + F_YCOMB;
  float* x1    = ws + F_X1;
  float* x2    = ws + F_X2;
  float* stats = ws + F_STATS;
  // bf16 activation + conv weight-pack buffers (alias dead f32 regions)
  ushortT* act1b = (ushortT*)(ws + F_ACT1);
  ushortT* act2b = (ushortT*)(ws + F_ACT2);
  ushortT* wb1   = (ushortT*)(ws + F_YS + 8192);
  ushortT* wb2   = wb1 + 110592;
  // scan chunk arrays alias buffers that are dead during the scan
  float* chunkP  = ws + F_XXIN;
  float* chunkH  = ws + F_YCOMB;
  float* chunkHS = ws + F_X1;
  // stats partials at head of YS region
  double* part = (double*)(ws + F_YS);
  // transposed small-GEMM weights (JIT into just-freed regions)
  float* wt_sk = ws + F_ACT1;          // 12288 floats; after conv1 (act1b dead)
  float* wt_ip = ws + F_XCAT;          // 16384 floats; after skip (xcat dead)
  float* wt_op = ws + F_XXIN;          // 8192 floats;  after pass2 (chunkP dead)
  float* wt_f1 = ws + F_XXIN + 8192;   // 4096
  float* wt_f2 = ws + F_XXIN + 12288;  // 4096

  // conv weight prepacks (no deps)
  wprep_kernel<<<432, 256, 0, stream>>>(c1w, wb1, NC3, 6);
  wprep_kernel<<<144, 256, 0, stream>>>(c2w, wb2, NC, 2);
  // stage 0: instance-norm stats
  stats1_kernel<<<NBL * 32, 256, 0, stream>>>(img, NC * NHW, part);
  stats2_kernel<<<NBL, 64, 0, stream>>>(part, NC * NHW, stats + 0, stats + 8);
  build_xcat_kernel<<<18432, 256, 0, stream>>>(img, dz, sg, stats, xcat);
  // gn1 + silu -> NHWC bf16
  stats1_kernel<<<NBL * 32, 256, 0, stream>>>(xcat, NC3 * NHW, part);
  stats2_kernel<<<NBL, 64, 0, stream>>>(part, NC3 * NHW, stats + 16, stats + 24);
  gnsilu_t_kernel<NC3><<<NBL * 64, 256, 0, stream>>>(xcat, gn1g, gn1b, stats + 16, act1b);
  conv_mfma_kernel<NC3><<<NBL * 64 * 2, 256, 0, stream>>>(act1b, wb1, c1b, h1);
  // act1b now dead -> transpose skip weight into its region
  wtrans_kernel<<<48, 256, 0, stream>>>(skw, wt_sk, 64, 192);
  // gn2 + silu -> NHWC bf16
  stats1_kernel<<<NBL * 32, 256, 0, stream>>>(h1, NC * NHW, part);
  stats2_kernel<<<NBL, 64, 0, stream>>>(part, NC * NHW, stats + 32, stats + 40);
  gnsilu_t_kernel<NC><<<NBL * 64, 256, 0, stream>>>(h1, gn2g, gn2b, stats + 32, act2b);
  conv_mfma_kernel<NC><<<NBL * 64 * 2, 256, 0, stream>>>(act2b, wb2, c2b, h2);
  // skip 1x1 + residual + NHWC transpose
  skip_kernel<<<NBL * 64, 256, 0, stream>>>(xcat, h2, wt_sk, skb, xres);
  // xcat now dead -> transpose in_proj weight
  wtrans_kernel<<<64, 256, 0, stream>>>(ipw, wt_ip, 256, 64);
  // SS2D
  inproj_kernel<<<6144, 256, 0, stream>>>(xres, ln1g, ln1b, wt_ip, xxin, zbuf);
  dwconv_kernel<<<12288, 256, 0, stream>>>(xxin, dww, dwb, xxc);
  xdbl_kernel<<<NBL * NK * 64, 256, 0, stream>>>(xxc, xpw, xdbl);
  // chunked scan
  scan_pass1_kernel<<<24 * 64, 128, 0, stream>>>(xdbl, xxc, dtw, dtb, Alog, chunkP, chunkH);
  scan_pass2_kernel<<<192, 256, 0, stream>>>(chunkP, chunkH, chunkHS);
  // chunkP (XXIN region) now dead -> transpose outproj/mlp weights
  wtrans_kernel<<<32, 256, 0, stream>>>(opw, wt_op, 64, 128);
  wtrans_kernel<<<16, 256, 0, stream>>>(f1w, wt_f1, 64, 64);
  wtrans_kernel<<<16, 256, 0, stream>>>(f2w, wt_f2, 64, 64);
  scan_pass3_kernel<<<24 * 64, 128, 0, stream>>>(xdbl, xxc, dtw, dtb, Alog, chunkHS, ysb);
  combine_kernel<<<12288, 256, 0, stream>>>(ysb, xxc, Dsp, ycomb);
  outproj_kernel<<<6144, 256, 0, stream>>>(ycomb, zbuf, ong, onb, wt_op, xres, x1);
  // MLP + residual
  mlp_kernel<<<6144, 256, 0, stream>>>(x1, ln2g, ln2b, wt_f1, f1b, wt_f2, f2b, x2);
  // final transpose to NCHW output
  transpose_out_kernel<<<NBL * 256, 256, 0, stream>>>(x2, out);
}

// Round 7
// 594.787 us; speedup vs baseline: 1.9420x; 1.1464x over previous
//
#include <hip/hip_runtime.h>
#include <hip/hip_bf16.h>

typedef unsigned short ushortT;
typedef short short8v __attribute__((ext_vector_type(8)));
typedef float float4v __attribute__((ext_vector_type(4)));

// Problem constants
#define NBL 6      // B*LEN
#define NC 64
#define NC3 192
#define NHW 4096   // 64*64
#define NDI 128
#define NNS 16
#define NDR 4
#define NK 4
#define NL 4096
#define NCH 64     // scan chunks
#define SCLEN 64   // chunk length
#define NSTATE 49152  // 24 bk * 128 d * 16 n

// workspace offsets in floats
static const size_t F_XCAT  = 0;          // 6*192*4096 = 4,718,592 (wt_ip after skip)
static const size_t F_ACT1  = 4718592;    // act1b bf16 NHWC; wt_sk after conv1
static const size_t F_H1    = 9437184;    // 1,572,864
static const size_t F_ACT2  = 11010048;   // act2b bf16 NHWC (1.57M ushorts)
static const size_t F_H2    = 12582912;   // 1,572,864
static const size_t F_XRES  = 14155776;   // 1,572,864
static const size_t F_XXIN  = 15728640;   // 3,145,728 (chunkP during scan; wt_op/f1/f2 after pass2)
static const size_t F_Z     = 18874368;   // 3,145,728
static const size_t F_XXC   = 22020096;   // 3,145,728
static const size_t F_XDBL  = 25165824;   // 6*4*36*4096 = 3,538,944
static const size_t F_YS    = 28704768;   // 12,582,912 (stats partials + conv wpacks early, ys later)
static const size_t F_YCOMB = 41287680;   // 3,145,728  (chunkH during scan)
static const size_t F_X1    = 44433408;   // 1,572,864  (X1+X2 -> chunkHS during scan)
static const size_t F_X2    = 46006272;   // 1,572,864
static const size_t F_STATS = 47579136;   // 48
static const size_t F_TOTAL = 47579184;   // floats (~190.3 MB)

__device__ __forceinline__ float wred64(float v) {
#pragma unroll
  for (int m = 32; m; m >>= 1) v += __shfl_xor(v, m, 64);
  return v;
}

__device__ __forceinline__ float silu(float v) {
  return v / (1.f + __expf(-v));
}

__device__ __forceinline__ ushortT f2bf(float f) {
  unsigned int u = __builtin_bit_cast(unsigned int, f);
  unsigned int r = (u + 0x7FFFu + ((u >> 16) & 1u)) >> 16;
  return (ushortT)r;
}

__device__ __forceinline__ int map_pos(int k, int l) {
  if (k == 0) return l;
  if (k == 1) return ((l & 63) << 6) | (l >> 6);
  if (k == 2) return 4095 - l;
  int lp = 4095 - l;
  return ((lp & 63) << 6) | (lp >> 6);
}

// softplus via hw exp2/log2: ln(1+e^a) = ln2 * log2(1 + 2^(a*log2e))
__device__ __forceinline__ float softplus_fast(float a) {
  float t = exp2f(a * 1.44269504f);
  float r = 0.69314718f * __log2f(1.f + t);
  return (a > 20.f) ? a : r;
}

// generic weight transpose: dst[c*O + o] = src[o*C + c]
__global__ __launch_bounds__(256) void wtrans_kernel(const float* __restrict__ src,
                                                     float* __restrict__ dst, int O, int C) {
  int id = blockIdx.x * 256 + threadIdx.x;
  if (id >= O * C) return;
  int c = id / O, o = id % O;
  dst[id] = src[o * C + c];
}

// ---- two-stage per-sample mean/rstd (f64 accumulate) ----
__global__ __launch_bounds__(256) void stats1_kernel(const float* __restrict__ in, int n,
                                                     double* __restrict__ part) {
  int bi = blockIdx.x;
  int s = bi >> 5, j = bi & 31;
  int slice = n >> 5;
  const float4* p = (const float4*)(in + (size_t)s * n + (size_t)j * slice);
  int n4 = slice >> 2;
  double dsum = 0.0, dsq = 0.0;
  for (int i = threadIdx.x; i < n4; i += 256) {
    float4 v = p[i];
    dsum += (double)((v.x + v.y) + (v.z + v.w));
    dsq += (double)v.x * v.x + (double)v.y * v.y + (double)v.z * v.z + (double)v.w * v.w;
  }
  __shared__ double s1[256], s2[256];
  s1[threadIdx.x] = dsum; s2[threadIdx.x] = dsq;
  __syncthreads();
  for (int off = 128; off; off >>= 1) {
    if (threadIdx.x < off) { s1[threadIdx.x] += s1[threadIdx.x + off]; s2[threadIdx.x] += s2[threadIdx.x + off]; }
    __syncthreads();
  }
  if (threadIdx.x == 0) { part[2 * bi] = s1[0]; part[2 * bi + 1] = s2[0]; }
}

__global__ __launch_bounds__(64) void stats2_kernel(const double* __restrict__ part, int n,
                                                    float* __restrict__ mean_out,
                                                    float* __restrict__ rstd_out) {
  int s = blockIdx.x;
  int lane = threadIdx.x;
  double sum = 0.0, sq = 0.0;
  if (lane < 32) { sum = part[2 * (s * 32 + lane)]; sq = part[2 * (s * 32 + lane) + 1]; }
#pragma unroll
  for (int m = 16; m; m >>= 1) { sum += __shfl_xor(sum, m, 64); sq += __shfl_xor(sq, m, 64); }
  if (lane == 0) {
    double mean = sum / n;
    double var = sq / n - mean * mean;
    mean_out[s] = (float)mean;
    rstd_out[s] = (float)(1.0 / sqrt(var + 1e-5));
  }
}

// x_cat[bl][ch][p]: ch<64 dz, 64..127 instance-normed img, 128..191 sigma
__global__ __launch_bounds__(256) void build_xcat_kernel(const float* __restrict__ img,
                                                         const float* __restrict__ dz,
                                                         const float* __restrict__ sg,
                                                         const float* __restrict__ stats,
                                                         float* __restrict__ xcat) {
  size_t gid = (size_t)blockIdx.x * 256 + threadIdx.x;
  int p = gid & 4095;
  size_t r = gid >> 12;
  int ch = (int)(r % NC3);
  int bl = (int)(r / NC3);
  int b = bl / 3;
  float v;
  if (ch < 64) {
    v = dz[((size_t)b * NC + ch) * NHW + p];
  } else if (ch < 128) {
    float m = stats[bl], rs = stats[8 + bl];
    v = (img[((size_t)bl * NC + (ch - 64)) * NHW + p] - m) * rs;
  } else {
    v = sg[((size_t)b * NC + (ch - 128)) * NHW + p];
  }
  xcat[gid] = v;
}

// GN + SiLU + NCHW->NHWC transpose + f32->bf16. grid NBL*64, block 256.
template <int CCH>
__global__ __launch_bounds__(256) void gnsilu_t_kernel(const float* __restrict__ in,
                                                       const float* __restrict__ g,
                                                       const float* __restrict__ b,
                                                       const float* __restrict__ stats,
                                                       ushortT* __restrict__ outb) {
  int bi = blockIdx.x;
  int bl = bi >> 6, h = bi & 63;
  __shared__ ushortT tile[CCH][66];
  float m = stats[bl], rs = stats[8 + bl];
  int t = threadIdx.x;
  for (int idx = t; idx < CCH * 64; idx += 256) {
    int ch = idx >> 6, w = idx & 63;
    float v = in[(((size_t)bl * CCH + ch) << 12) + (h << 6) + w];
    v = (v - m) * rs * g[ch] + b[ch];
    v = silu(v);
    tile[ch][w] = f2bf(v);
  }
  __syncthreads();
  constexpr int C8 = CCH / 8;
  for (int idx = t; idx < 64 * C8; idx += 256) {
    int w = idx / C8, c8 = idx % C8;
    short8v v;
#pragma unroll
    for (int j = 0; j < 8; ++j) v[j] = (short)tile[c8 * 8 + j][w];
    *(short8v*)&outb[(size_t)(bl * 4096 + h * 64 + w) * CCH + c8 * 8] = v;
  }
}

// Pre-pack conv weights into per-lane MFMA B-fragments (bf16).
__global__ __launch_bounds__(256) void wprep_kernel(const float* __restrict__ w,
                                                    ushortT* __restrict__ out,
                                                    int CIN, int KT) {
  int id = blockIdx.x * 256 + threadIdx.x;
  int j = id & 7;
  int lane = (id >> 3) & 63;
  int nt = (id >> 9) & 3;
  int rest = id >> 11;
  int kt = rest % KT;
  int tap = rest / KT;
  int oc = nt * 16 + (lane & 15);
  int ic = kt * 32 + ((lane >> 4) << 3) + j;
  int r = tap / 3, s = tap % 3;
  out[id] = f2bf(w[(((size_t)oc * CIN + ic) * 3 + r) * 3 + s]);
}

// Implicit-GEMM 3x3 SAME conv via bf16 MFMA, f32 accumulate.
template <int CIN>
__global__ __launch_bounds__(256) void conv_mfma_kernel(const ushortT* __restrict__ actb,
                                                        const ushortT* __restrict__ wb,
                                                        const float* __restrict__ bias,
                                                        float* __restrict__ out) {
  constexpr int KT = CIN / 32;
  constexpr int STRIDE = CIN + 8;
  constexpr int C8 = CIN / 8;
  int bi = blockIdx.x;
  int nh = bi & 1;
  int h = (bi >> 1) & 63;
  int bl = bi >> 7;
  int t = threadIdx.x;
  int wv = t >> 6, lane = t & 63;
  __shared__ ushortT lds[66 * STRIDE];
  float4v acc0 = {0.f, 0.f, 0.f, 0.f};
  float4v acc1 = {0.f, 0.f, 0.f, 0.f};
  int lrow = lane & 15;
  int lk = (lane >> 4) << 3;
  for (int dy = 0; dy < 3; ++dy) {
    int hh = h + dy - 1;
    bool valid = (hh >= 0) && (hh < 64);
    int hc = valid ? hh : 0;
    if (dy) __syncthreads();
    const ushortT* src = actb + (size_t)(bl * 4096 + hc * 64) * CIN;
    for (int idx = t; idx < 64 * C8; idx += 256) {
      int w = idx / C8, c8 = idx % C8;
      short8v v = {0, 0, 0, 0, 0, 0, 0, 0};
      if (valid) v = *(const short8v*)&src[(size_t)w * CIN + c8 * 8];
      *(short8v*)&lds[(w + 1) * STRIDE + c8 * 8] = v;
    }
    if (t < 2 * C8) {
      int which = t / C8, c8 = t % C8;
      short8v z = {0, 0, 0, 0, 0, 0, 0, 0};
      *(short8v*)&lds[(which ? 65 : 0) * STRIDE + c8 * 8] = z;
    }
    __syncthreads();
    for (int dx = 0; dx < 3; ++dx) {
      int tap = dy * 3 + dx;
      int wl = (wv << 4) + lrow + dx;
#pragma unroll
      for (int kt = 0; kt < KT; ++kt) {
        short8v a = *(const short8v*)&lds[wl * STRIDE + kt * 32 + lk];
        const ushortT* wp = wb + ((size_t)(((tap * KT + kt) * 4 + (nh << 1)) * 64 + lane) << 3);
        short8v b0 = *(const short8v*)&wp[0];
        short8v b1 = *(const short8v*)&wp[512];
        acc0 = __builtin_amdgcn_mfma_f32_16x16x32_bf16(a, b0, acc0, 0, 0, 0);
        acc1 = __builtin_amdgcn_mfma_f32_16x16x32_bf16(a, b1, acc1, 0, 0, 0);
      }
    }
  }
  int oc0 = (nh << 5) + lrow;
  int oc1 = oc0 + 16;
  int w0 = (wv << 4) + ((lane >> 4) << 2);
  float bv0 = bias[oc0], bv1 = bias[oc1];
  float4 o0 = make_float4(acc0[0] + bv0, acc0[1] + bv0, acc0[2] + bv0, acc0[3] + bv0);
  float4 o1 = make_float4(acc1[0] + bv1, acc1[1] + bv1, acc1[2] + bv1, acc1[3] + bv1);
  *(float4*)&out[(((size_t)bl * 64 + oc0) << 12) + (h << 6) + w0] = o0;
  *(float4*)&out[(((size_t)bl * 64 + oc1) << 12) + (h << 6) + w0] = o1;
}

// x_res[bl][p][oc] = h2[bl][oc][p] + 1x1skip(xcat)[oc] + skb[oc]   (NHWC out)
__global__ __launch_bounds__(256) void skip_kernel(const float* __restrict__ xcat,
                                                   const float* __restrict__ h2,
                                                   const float* __restrict__ skwt,
                                                   const float* __restrict__ skb,
                                                   float* __restrict__ xres) {
  int bi = blockIdx.x;
  int bl = bi >> 6, h = bi & 63;
  int t = threadIdx.x;
  int oc = t & 63, w0 = (t >> 6) << 4;
  __shared__ float lds[64][64];
  float acc[16];
#pragma unroll
  for (int i = 0; i < 16; ++i) acc[i] = 0.f;
  for (int cc = 0; cc < 3; ++cc) {
    __syncthreads();
    for (int idx = t; idx < 4096; idx += 256) {
      int ch = idx >> 6, w = idx & 63;
      lds[ch][w] = xcat[(((size_t)bl * NC3 + cc * 64 + ch) << 12) + (h << 6) + w];
    }
    __syncthreads();
    for (int ch = 0; ch < 64; ++ch) {
      float wv = skwt[((cc << 6) + ch) * 64 + oc];
#pragma unroll
      for (int i = 0; i < 16; ++i) acc[i] += wv * lds[ch][w0 + i];
    }
  }
  float bv = skb[oc];
  int p0 = (h << 6) + w0;
#pragma unroll
  for (int i = 0; i < 16; ++i) {
    float hv = h2[(((size_t)bl * 64 + oc) << 12) + p0 + i];
    xres[((size_t)bl * NHW + p0 + i) * 64 + oc] = acc[i] + bv + hv;
  }
}

// LN(ln1) + 64->256 proj, transposed weight wt[c(64)][oc(256)].
__global__ __launch_bounds__(256) void inproj_kernel(const float* __restrict__ xres,
                                                     const float* __restrict__ g,
                                                     const float* __restrict__ b,
                                                     const float* __restrict__ wt,
                                                     float* __restrict__ xxin,
                                                     float* __restrict__ z) {
  int wv = threadIdx.x >> 6, lane = threadIdx.x & 63;
  size_t pi0 = (size_t)blockIdx.x * 4;
  size_t pi = pi0 + wv;
  float x = xres[pi * 64 + lane];
  float s = wred64(x);
  float s2 = wred64(x * x);
  float m = s * (1.f / 64), var = s2 * (1.f / 64) - m * m;
  float rstd = rsqrtf(var + 1e-5f);
  float xln = (x - m) * rstd * g[lane] + b[lane];
  __shared__ float xb[64][4];
  xb[lane][wv] = xln;
  __syncthreads();
  float acc[4] = {0.f, 0.f, 0.f, 0.f};
  int oc = (wv << 6) + lane;
  for (int c = 0; c < 64; ++c) {
    float4 xv = *(const float4*)&xb[c][0];
    float w = wt[(c << 8) + oc];
    acc[0] += w * xv.x; acc[1] += w * xv.y; acc[2] += w * xv.z; acc[3] += w * xv.w;
  }
#pragma unroll
  for (int p = 0; p < 4; ++p) {
    size_t pp = pi0 + p;
    if (oc < 128) xxin[(pp << 7) + oc] = acc[p];
    else z[(pp << 7) + (oc - 128)] = acc[p];
  }
}

// depthwise 3x3 SAME + bias + silu on NHWC [bl][p][128]
__global__ __launch_bounds__(256) void dwconv_kernel(const float* __restrict__ xx,
                                                     const float* __restrict__ w,
                                                     const float* __restrict__ b,
                                                     float* __restrict__ out) {
  size_t gid = (size_t)blockIdx.x * 256 + threadIdx.x;
  int d = gid & 127;
  size_t pi = gid >> 7;
  int p = (int)(pi & 4095);
  int bl = (int)(pi >> 12);
  int h = p >> 6, wq = p & 63;
  float acc = b[d];
  const float* wr = w + d * 9;
#pragma unroll
  for (int dy = -1; dy <= 1; ++dy) {
    int hh = h + dy;
    if (hh < 0 || hh >= 64) continue;
#pragma unroll
    for (int dx = -1; dx <= 1; ++dx) {
      int ww = wq + dx;
      if (ww < 0 || ww >= 64) continue;
      acc += wr[(dy + 1) * 3 + (dx + 1)] * xx[(((size_t)bl << 12) + (hh << 6) + ww) * 128 + d];
    }
  }
  out[pi * 128 + d] = silu(acc);
}

// x_dbl[bk][c][l] = sum_d xpw[k][c][d] * xs[bk][d][l]
__global__ __launch_bounds__(256) void xdbl_kernel(const float* __restrict__ xxc,
                                                   const float* __restrict__ xpw,
                                                   float* __restrict__ xdbl) {
  int bi = blockIdx.x;
  int lt = bi & 63;
  int k = (bi >> 6) & 3;
  int bl = bi >> 8;
  int lbase = lt << 6;
  __shared__ float lds[64][132];
  int t = threadIdx.x;
  for (int idx = t; idx < 64 * 128; idx += 256) {
    int i = idx >> 7, d = idx & 127;
    int pos = map_pos(k, lbase + i);
    lds[i][d] = xxc[((size_t)bl * NHW + pos) * 128 + d];
  }
  __syncthreads();
  for (int oi = t; oi < 36 * 64; oi += 256) {
    int c = oi >> 6, l = oi & 63;
    const float* wrow = xpw + (k * 36 + c) * 128;
    float acc = 0.f;
    for (int d4 = 0; d4 < 32; ++d4) {
      float4 w4 = *(const float4*)&wrow[d4 << 2];
      float4 x4 = *(const float4*)&lds[l][d4 << 2];
      acc += w4.x * x4.x + w4.y * x4.y + w4.z * x4.z + w4.w * x4.w;
    }
    xdbl[(((size_t)(bl * 4 + k)) * 36 + c) * (size_t)NL + lbase + l] = acc;
  }
}

// ---- chunked selective scan, vector-register 16-state version ----
// grid = 24 bk * 64 chunks; block 128 (one thread per d).
__global__ __launch_bounds__(128) void scan_pass1_kernel(const float* __restrict__ xdbl,
                                                         const float* __restrict__ xxc,
                                                         const float* __restrict__ dtw,
                                                         const float* __restrict__ dtb,
                                                         const float* __restrict__ Alog,
                                                         float* __restrict__ chunkP,
                                                         float* __restrict__ chunkH) {
  int bi = blockIdx.x;
  int chunk = bi & 63;
  int bk = bi >> 6;
  int k = bk & 3, bl = bk >> 2;
  int d = threadIdx.x;
  float4 wv = *(const float4*)(dtw + (size_t)(((k << 7) + d) << 2));
  float bias = dtb[(k << 7) + d];
  float4v a0, a1, a2, a3;
  {
    const float* ar = Alog + (size_t)(((k << 7) + d) << 4);
#pragma unroll
    for (int j = 0; j < 4; ++j) {
      a0[j] = -__expf(ar[j]) * 1.44269504f;
      a1[j] = -__expf(ar[4 + j]) * 1.44269504f;
      a2[j] = -__expf(ar[8 + j]) * 1.44269504f;
      a3[j] = -__expf(ar[12 + j]) * 1.44269504f;
    }
  }
  __shared__ float xd[SCLEN][36];
  int l0 = chunk << 6;
  for (int idx = threadIdx.x; idx < 36 * SCLEN; idx += 128) {
    int c = idx >> 6, li = idx & 63;
    xd[li][c] = xdbl[((size_t)bk * 36 + c) * (size_t)NL + l0 + li];
  }
  __syncthreads();
  const float* uB = xxc + ((size_t)bl << 19) + d;
  float4v h0 = {0.f, 0.f, 0.f, 0.f}, h1 = h0, h2 = h0, h3 = h0;
  float sdt = 0.f;
  float u_nxt = uB[(size_t)map_pos(k, l0) << 7];
  for (int li = 0; li < SCLEN; ++li) {
    float u = u_nxt;
    int nl = (li < SCLEN - 1) ? (li + 1) : (SCLEN - 1);
    u_nxt = uB[(size_t)map_pos(k, l0 + nl) << 7];
    const float4v* row = (const float4v*)&xd[li][0];
    float4v q0 = row[0];
    float accq = bias + wv.x * q0[0] + wv.y * q0[1] + wv.z * q0[2] + wv.w * q0[3];
    float dt = softplus_fast(accq);
    float dtu = dt * u;
    sdt += dt;
    float4v b0 = row[1], b1 = row[2], b2 = row[3], b3 = row[4];
    float4v e0, e1, e2, e3;
#pragma unroll
    for (int j = 0; j < 4; ++j) {
      e0[j] = exp2f(a0[j] * dt);
      e1[j] = exp2f(a1[j] * dt);
      e2[j] = exp2f(a2[j] * dt);
      e3[j] = exp2f(a3[j] * dt);
    }
    h0 = e0 * h0 + dtu * b0;
    h1 = e1 * h1 + dtu * b1;
    h2 = e2 * h2 + dtu * b2;
    h3 = e3 * h3 + dtu * b3;
  }
  size_t base = (size_t)chunk * NSTATE + (((size_t)bk << 7) + (size_t)d) * 16;
  float4v p0, p1, p2, p3;
#pragma unroll
  for (int j = 0; j < 4; ++j) {
    p0[j] = exp2f(a0[j] * sdt);
    p1[j] = exp2f(a1[j] * sdt);
    p2[j] = exp2f(a2[j] * sdt);
    p3[j] = exp2f(a3[j] * sdt);
  }
  *(float4v*)&chunkP[base + 0] = p0;
  *(float4v*)&chunkP[base + 4] = p1;
  *(float4v*)&chunkP[base + 8] = p2;
  *(float4v*)&chunkP[base + 12] = p3;
  *(float4v*)&chunkH[base + 0] = h0;
  *(float4v*)&chunkH[base + 4] = h1;
  *(float4v*)&chunkH[base + 8] = h2;
  *(float4v*)&chunkH[base + 12] = h3;
}

__global__ __launch_bounds__(256) void scan_pass2_kernel(const float* __restrict__ chunkP,
                                                         const float* __restrict__ chunkH,
                                                         float* __restrict__ chunkHS) {
  size_t state = (size_t)blockIdx.x * 256 + threadIdx.x;
  float h = 0.f;
#pragma unroll 4
  for (int j = 0; j < NCH; ++j) {
    size_t idx = (size_t)j * NSTATE + state;
    chunkHS[idx] = h;
    h = chunkP[idx] * h + chunkH[idx];
  }
}

__global__ __launch_bounds__(128) void scan_pass3_kernel(const float* __restrict__ xdbl,
                                                         const float* __restrict__ xxc,
                                                         const float* __restrict__ dtw,
                                                         const float* __restrict__ dtb,
                                                         const float* __restrict__ Alog,
                                                         const float* __restrict__ chunkHS,
                                                         float* __restrict__ ys) {
  int bi = blockIdx.x;
  int chunk = bi & 63;
  int bk = bi >> 6;
  int k = bk & 3, bl = bk >> 2;
  int d = threadIdx.x;
  float4 wv = *(const float4*)(dtw + (size_t)(((k << 7) + d) << 2));
  float bias = dtb[(k << 7) + d];
  float4v a0, a1, a2, a3;
  {
    const float* ar = Alog + (size_t)(((k << 7) + d) << 4);
#pragma unroll
    for (int j = 0; j < 4; ++j) {
      a0[j] = -__expf(ar[j]) * 1.44269504f;
      a1[j] = -__expf(ar[4 + j]) * 1.44269504f;
      a2[j] = -__expf(ar[8 + j]) * 1.44269504f;
      a3[j] = -__expf(ar[12 + j]) * 1.44269504f;
    }
  }
  __shared__ float xd[SCLEN][36];
  int l0 = chunk << 6;
  for (int idx = threadIdx.x; idx < 36 * SCLEN; idx += 128) {
    int c = idx >> 6, li = idx & 63;
    xd[li][c] = xdbl[((size_t)bk * 36 + c) * (size_t)NL + l0 + li];
  }
  __syncthreads();
  const float* uB = xxc + ((size_t)bl << 19) + d;
  float* yB = ys + ((size_t)bk << 19) + d;
  size_t base = (size_t)chunk * NSTATE + (((size_t)bk << 7) + (size_t)d) * 16;
  float4v h0 = *(const float4v*)&chunkHS[base + 0];
  float4v h1 = *(const float4v*)&chunkHS[base + 4];
  float4v h2 = *(const float4v*)&chunkHS[base + 8];
  float4v h3 = *(const float4v*)&chunkHS[base + 12];
  float u_nxt = uB[(size_t)map_pos(k, l0) << 7];
  for (int li = 0; li < SCLEN; ++li) {
    float u = u_nxt;
    int nl = (li < SCLEN - 1) ? (li + 1) : (SCLEN - 1);
    u_nxt = uB[(size_t)map_pos(k, l0 + nl) << 7];
    const float4v* row = (const float4v*)&xd[li][0];
    float4v q0 = row[0];
    float accq = bias + wv.x * q0[0] + wv.y * q0[1] + wv.z * q0[2] + wv.w * q0[3];
    float dt = softplus_fast(accq);
    float dtu = dt * u;
    float4v b0 = row[1], b1 = row[2], b2 = row[3], b3 = row[4];
    float4v c0 = row[5], c1 = row[6], c2 = row[7], c3 = row[8];
    float4v e0, e1, e2, e3;
#pragma unroll
    for (int j = 0; j < 4; ++j) {
      e0[j] = exp2f(a0[j] * dt);
      e1[j] = exp2f(a1[j] * dt);
      e2[j] = exp2f(a2[j] * dt);
      e3[j] = exp2f(a3[j] * dt);
    }
    h0 = e0 * h0 + dtu * b0;
    h1 = e1 * h1 + dtu * b1;
    h2 = e2 * h2 + dtu * b2;
    h3 = e3 * h3 + dtu * b3;
    float4v sy = h0 * c0;
    sy += h1 * c1;
    sy += h2 * c2;
    sy += h3 * c3;
    yB[(size_t)(l0 + li) << 7] = (sy[0] + sy[1]) + (sy[2] + sy[3]);
  }
}

// ycomb[bl][p][d] = sum of 4 direction outputs (mapped) + xxc * sum_k Ds
__global__ __launch_bounds__(256) void combine_kernel(const float* __restrict__ ys,
                                                      const float* __restrict__ xxc,
                                                      const float* __restrict__ Ds,
                                                      float* __restrict__ ycomb) {
  size_t gid = (size_t)blockIdx.x * 256 + threadIdx.x;
  int d = gid & 127;
  size_t pi = gid >> 7;
  int p = (int)(pi & 4095);
  int bl = (int)(pi >> 12);
  int h = p >> 6, w = p & 63;
  int l1 = (w << 6) | h;
  size_t base = ((size_t)bl * 4) << 12;
  float v = ys[((base + p) << 7) + d]
          + ys[((base + 4096 + l1) << 7) + d]
          + ys[((base + 2 * 4096 + (4095 - p)) << 7) + d]
          + ys[((base + 3 * 4096 + (4095 - l1)) << 7) + d];
  float ds = Ds[d] + Ds[128 + d] + Ds[256 + d] + Ds[384 + d];
  v += xxc[(pi << 7) + d] * ds;
  ycomb[(pi << 7) + d] = v;
}

// out_norm LN(128) -> *silu(z) -> out_proj (transposed wt[c(128)][oc(64)]) -> + x_res
__global__ __launch_bounds__(256) void outproj_kernel(const float* __restrict__ ycomb,
                                                      const float* __restrict__ z,
                                                      const float* __restrict__ ong,
                                                      const float* __restrict__ onb,
                                                      const float* __restrict__ opwt,
                                                      const float* __restrict__ xres,
                                                      float* __restrict__ x1) {
  int wv = threadIdx.x >> 6, lane = threadIdx.x & 63;
  size_t pi = (size_t)blockIdx.x * 4 + wv;
  float y0 = ycomb[(pi << 7) + lane], y1 = ycomb[(pi << 7) + 64 + lane];
  float s = wred64(y0 + y1);
  float s2 = wred64(y0 * y0 + y1 * y1);
  float m = s * (1.f / 128), var = s2 * (1.f / 128) - m * m;
  float rstd = rsqrtf(var + 1e-5f);
  float z0 = z[(pi << 7) + lane], z1 = z[(pi << 7) + 64 + lane];
  float g0 = ((y0 - m) * rstd * ong[lane] + onb[lane]) * silu(z0);
  float g1 = ((y1 - m) * rstd * ong[64 + lane] + onb[64 + lane]) * silu(z1);
  __shared__ float gb[128][4];
  gb[lane][wv] = g0;
  gb[64 + lane][wv] = g1;
  __syncthreads();
  float acc = 0.f;
  for (int c = 0; c < 128; ++c) {
    acc += opwt[(c << 6) + lane] * gb[c][wv];
  }
  x1[pi * 64 + lane] = xres[pi * 64 + lane] + acc;
}

// ln2 -> fc1 -> gelu(tanh) -> fc2 -> residual; transposed weights wt[c][oc]
__global__ __launch_bounds__(256) void mlp_kernel(const float* __restrict__ x1,
                                                  const float* __restrict__ g2,
                                                  const float* __restrict__ b2,
                                                  const float* __restrict__ w1t,
                                                  const float* __restrict__ bb1,
                                                  const float* __restrict__ w2t,
                                                  const float* __restrict__ bb2,
                                                  float* __restrict__ x2) {
  int wv = threadIdx.x >> 6, lane = threadIdx.x & 63;
  size_t pi = (size_t)blockIdx.x * 4 + wv;
  float xv = x1[pi * 64 + lane];
  float s = wred64(xv), s2 = wred64(xv * xv);
  float m = s * (1.f / 64), var = s2 * (1.f / 64) - m * m;
  float rstd = rsqrtf(var + 1e-5f);
  float xm = (xv - m) * rstd * g2[lane] + b2[lane];
  __shared__ float xb[64][4], tb[64][4];
  xb[lane][wv] = xm;
  __syncthreads();
  float acc = bb1[lane];
  for (int c = 0; c < 64; ++c) acc += w1t[(c << 6) + lane] * xb[c][wv];
  float u = acc;
  float tt = tanhf(0.7978845608028654f * (u + 0.044715f * u * u * u));
  float t1 = 0.5f * u * (1.f + tt);
  tb[lane][wv] = t1;
  __syncthreads();
  float acc2 = bb2[lane];
  for (int c = 0; c < 64; ++c) acc2 += w2t[(c << 6) + lane] * tb[c][wv];
  x2[pi * 64 + lane] = xv + acc2;
}

// NHWC (bl,p,c) -> NCHW (bl,c,p) tiled transpose into d_out
__global__ __launch_bounds__(256) void transpose_out_kernel(const float* __restrict__ x2,
                                                            float* __restrict__ out) {
  int bi = blockIdx.x;
  int pt = bi & 127;
  int ct = (bi >> 7) & 1;
  int bl = bi >> 8;
  __shared__ float lds[32][33];
  int t = threadIdx.x;
  int j = t & 31, i0 = t >> 5;
  int p0 = pt << 5, c0 = ct << 5;
#pragma unroll
  for (int q = 0; q < 4; ++q) {
    int i = i0 + (q << 3);
    lds[i][j] = x2[((size_t)bl * NHW + p0 + i) * 64 + c0 + j];
  }
  __syncthreads();
#pragma unroll
  for (int q = 0; q < 4; ++q) {
    int i = i0 + (q << 3);
    out[((size_t)bl * 64 + c0 + i) * (size_t)NHW + p0 + j] = lds[j][i];
  }
}

extern "C" void kernel_launch(void* const* d_in, const int* in_sizes, int n_in,
                              void* d_out, int out_size, void* d_ws, size_t ws_size,
                              hipStream_t stream) {
  const float* img  = (const float*)d_in[0];
  const float* dz   = (const float*)d_in[1];
  const float* sg   = (const float*)d_in[2];
  const float* gn1g = (const float*)d_in[3];
  const float* gn1b = (const float*)d_in[4];
  const float* c1w  = (const float*)d_in[5];
  const float* c1b  = (const float*)d_in[6];
  const float* gn2g = (const float*)d_in[7];
  const float* gn2b = (const float*)d_in[8];
  const float* c2w  = (const float*)d_in[9];
  const float* c2b  = (const float*)d_in[10];
  const float* skw  = (const float*)d_in[11];
  const float* skb  = (const float*)d_in[12];
  const float* ln1g = (const float*)d_in[13];
  const float* ln1b = (const float*)d_in[14];
  const float* ln2g = (const float*)d_in[15];
  const float* ln2b = (const float*)d_in[16];
  const float* ipw  = (const float*)d_in[17];
  const float* dww  = (const float*)d_in[18];
  const float* dwb  = (const float*)d_in[19];
  const float* xpw  = (const float*)d_in[20];
  const float* dtw  = (const float*)d_in[21];
  const float* dtb  = (const float*)d_in[22];
  const float* Alog = (const float*)d_in[23];
  const float* Dsp  = (const float*)d_in[24];
  const float* ong  = (const float*)d_in[25];
  const float* onb  = (const float*)d_in[26];
  const float* opw  = (const float*)d_in[27];
  const float* f1w  = (const float*)d_in[28];
  const float* f1b  = (const float*)d_in[29];
  const float* f2w  = (const float*)d_in[30];
  const float* f2b  = (const float*)d_in[31];

  float* out = (float*)d_out;
  float* ws = (float*)d_ws;
  if (ws_size < F_TOTAL * sizeof(float)) return;

  float* xcat  = ws + F_XCAT;
  float* h1    = ws + F_H1;
  float* h2    = ws + F_H2;
  float* xres  = ws + F_XRES;
  float* xxin  = ws + F_XXIN;
  float* zbuf  = ws + F_Z;
  float* xxc   = ws + F_XXC;
  float* xdbl  = ws + F_XDBL;
  float* ysb   = ws + F_YS;
  float* ycomb = ws + F_YCOMB;
  float* x1    = ws + F_X1;
  float* x2    = ws + F_X2;
  float* stats = ws + F_STATS;
  ushortT* act1b = (ushortT*)(ws + F_ACT1);
  ushortT* act2b = (ushortT*)(ws + F_ACT2);
  ushortT* wb1   = (ushortT*)(ws + F_YS + 8192);
  ushortT* wb2   = wb1 + 110592;
  float* chunkP  = ws + F_XXIN;
  float* chunkH  = ws + F_YCOMB;
  float* chunkHS = ws + F_X1;
  double* part = (double*)(ws + F_YS);
  float* wt_sk = ws + F_ACT1;
  float* wt_ip = ws + F_XCAT;
  float* wt_op = ws + F_XXIN;
  float* wt_f1 = ws + F_XXIN + 8192;
  float* wt_f2 = ws + F_XXIN + 12288;

  // conv weight prepacks (no deps)
  wprep_kernel<<<432, 256, 0, stream>>>(c1w, wb1, NC3, 6);
  wprep_kernel<<<144, 256, 0, stream>>>(c2w, wb2, NC, 2);
  // stage 0: instance-norm stats
  stats1_kernel<<<NBL * 32, 256, 0, stream>>>(img, NC * NHW, part);
  stats2_kernel<<<NBL, 64, 0, stream>>>(part, NC * NHW, stats + 0, stats + 8);
  build_xcat_kernel<<<18432, 256, 0, stream>>>(img, dz, sg, stats, xcat);
  // gn1 + silu -> NHWC bf16
  stats1_kernel<<<NBL * 32, 256, 0, stream>>>(xcat, NC3 * NHW, part);
  stats2_kernel<<<NBL, 64, 0, stream>>>(part, NC3 * NHW, stats + 16, stats + 24);
  gnsilu_t_kernel<NC3><<<NBL * 64, 256, 0, stream>>>(xcat, gn1g, gn1b, stats + 16, act1b);
  conv_mfma_kernel<NC3><<<NBL * 64 * 2, 256, 0, stream>>>(act1b, wb1, c1b, h1);
  wtrans_kernel<<<48, 256, 0, stream>>>(skw, wt_sk, 64, 192);
  // gn2 + silu -> NHWC bf16
  stats1_kernel<<<NBL * 32, 256, 0, stream>>>(h1, NC * NHW, part);
  stats2_kernel<<<NBL, 64, 0, stream>>>(part, NC * NHW, stats + 32, stats + 40);
  gnsilu_t_kernel<NC><<<NBL * 64, 256, 0, stream>>>(h1, gn2g, gn2b, stats + 32, act2b);
  conv_mfma_kernel<NC><<<NBL * 64 * 2, 256, 0, stream>>>(act2b, wb2, c2b, h2);
  // skip 1x1 + residual + NHWC transpose
  skip_kernel<<<NBL * 64, 256, 0, stream>>>(xcat, h2, wt_sk, skb, xres);
  wtrans_kernel<<<64, 256, 0, stream>>>(ipw, wt_ip, 256, 64);
  // SS2D
  inproj_kernel<<<6144, 256, 0, stream>>>(xres, ln1g, ln1b, wt_ip, xxin, zbuf);
  dwconv_kernel<<<12288, 256, 0, stream>>>(xxin, dww, dwb, xxc);
  xdbl_kernel<<<NBL * NK * 64, 256, 0, stream>>>(xxc, xpw, xdbl);
  // chunked scan
  scan_pass1_kernel<<<24 * 64, 128, 0, stream>>>(xdbl, xxc, dtw, dtb, Alog, chunkP, chunkH);
  scan_pass2_kernel<<<192, 256, 0, stream>>>(chunkP, chunkH, chunkHS);
  wtrans_kernel<<<32, 256, 0, stream>>>(opw, wt_op, 64, 128);
  wtrans_kernel<<<16, 256, 0, stream>>>(f1w, wt_f1, 64, 64);
  wtrans_kernel<<<16, 256, 0, stream>>>(f2w, wt_f2, 64, 64);
  scan_pass3_kernel<<<24 * 64, 128, 0, stream>>>(xdbl, xxc, dtw, dtb, Alog, chunkHS, ysb);
  combine_kernel<<<12288, 256, 0, stream>>>(ysb, xxc, Dsp, ycomb);
  outproj_kernel<<<6144, 256, 0, stream>>>(ycomb, zbuf, ong, onb, wt_op, xres, x1);
  // MLP + residual
  mlp_kernel<<<6144, 256, 0, stream>>>(x1, ln2g, ln2b, wt_f1, f1b, wt_f2, f2b, x2);
  // final transpose to NCHW output
  transpose_out_kernel<<<NBL * 256, 256, 0, stream>>>(x2, out);
}

// Round 8
// 502.013 us; speedup vs baseline: 2.3009x; 1.1848x over previous
//
#include <hip/hip_runtime.h>
#include <hip/hip_bf16.h>

typedef unsigned short ushortT;
typedef short short8v __attribute__((ext_vector_type(8)));
typedef float float4v __attribute__((ext_vector_type(4)));

// Problem constants
#define NBL 6      // B*LEN
#define NC 64
#define NC3 192
#define NHW 4096   // 64*64
#define NDI 128
#define NNS 16
#define NDR 4
#define NK 4
#define NL 4096
#define NCH 128    // scan chunks
#define SCLEN 32   // chunk length
#define NSTATE 49152  // 24 bk * 128 d * 16 n

// workspace offsets in floats
static const size_t F_XCAT  = 0;          // 4,718,592 (wt_ip after skip; chunkHS span during scan)
static const size_t F_ACT1  = 4718592;    // act1b bf16 NHWC; wt_sk after conv1; chunkHS tail
static const size_t F_H1    = 9437184;    // 1,572,864
static const size_t F_ACT2  = 11010048;   // act2b bf16 NHWC
static const size_t F_H2    = 12582912;   // 1,572,864
static const size_t F_XRES  = 14155776;   // 1,572,864
static const size_t F_XXIN  = 15728640;   // 3,145,728 (wt_op/f1/f2 after dwconv)
static const size_t F_Z     = 18874368;   // 3,145,728
static const size_t F_XXC   = 22020096;   // 3,145,728
static const size_t F_XDBL  = 25165824;   // 3,538,944
static const size_t F_YS    = 28704768;   // 12,582,912 (chunkP+chunkH during scan; ys after)
static const size_t F_YCOMB = 41287680;   // 3,145,728
static const size_t F_X1    = 44433408;   // 1,572,864
static const size_t F_X2    = 46006272;   // 1,572,864 (stats partials + conv wpacks early)
static const size_t F_STATS = 47579136;   // 48
static const size_t F_TOTAL = 47579184;   // floats (~190.3 MB)

__device__ __forceinline__ float wred64(float v) {
#pragma unroll
  for (int m = 32; m; m >>= 1) v += __shfl_xor(v, m, 64);
  return v;
}

__device__ __forceinline__ float silu(float v) {
  return v / (1.f + __expf(-v));
}

__device__ __forceinline__ ushortT f2bf(float f) {
  unsigned int u = __builtin_bit_cast(unsigned int, f);
  unsigned int r = (u + 0x7FFFu + ((u >> 16) & 1u)) >> 16;
  return (ushortT)r;
}

__device__ __forceinline__ int map_pos(int k, int l) {
  if (k == 0) return l;
  if (k == 1) return ((l & 63) << 6) | (l >> 6);
  if (k == 2) return 4095 - l;
  int lp = 4095 - l;
  return ((lp & 63) << 6) | (lp >> 6);
}

// softplus via hw exp2/log2: ln(1+e^a) = ln2 * log2(1 + 2^(a*log2e))
__device__ __forceinline__ float softplus_fast(float a) {
  float t = exp2f(a * 1.44269504f);
  float r = 0.69314718f * __log2f(1.f + t);
  return (a > 20.f) ? a : r;
}

// powers E^1..E^16 via mul tree (for geometric A: a_n = (n+1)*a_1)
__device__ __forceinline__ void pow_tree(float E1, float4v& e0, float4v& e1,
                                         float4v& e2, float4v& e3) {
  float E2 = E1 * E1, E3 = E2 * E1, E4 = E2 * E2;
  float E5 = E4 * E1, E6 = E4 * E2, E7 = E4 * E3, E8 = E4 * E4;
  e0[0] = E1; e0[1] = E2; e0[2] = E3; e0[3] = E4;
  e1[0] = E5; e1[1] = E6; e1[2] = E7; e1[3] = E8;
  e2[0] = E8 * E1; e2[1] = E8 * E2; e2[2] = E8 * E3; e2[3] = E8 * E4;
  e3[0] = E8 * E5; e3[1] = E8 * E6; e3[2] = E8 * E7; e3[3] = E8 * E8;
}

// generic weight transpose: dst[c*O + o] = src[o*C + c]
__global__ __launch_bounds__(256) void wtrans_kernel(const float* __restrict__ src,
                                                     float* __restrict__ dst, int O, int C) {
  int id = blockIdx.x * 256 + threadIdx.x;
  if (id >= O * C) return;
  int c = id / O, o = id % O;
  dst[id] = src[o * C + c];
}

// ---- two-stage per-sample mean/rstd (f64 accumulate) ----
__global__ __launch_bounds__(256) void stats1_kernel(const float* __restrict__ in, int n,
                                                     double* __restrict__ part) {
  int bi = blockIdx.x;
  int s = bi >> 5, j = bi & 31;
  int slice = n >> 5;
  const float4* p = (const float4*)(in + (size_t)s * n + (size_t)j * slice);
  int n4 = slice >> 2;
  double dsum = 0.0, dsq = 0.0;
  for (int i = threadIdx.x; i < n4; i += 256) {
    float4 v = p[i];
    dsum += (double)((v.x + v.y) + (v.z + v.w));
    dsq += (double)v.x * v.x + (double)v.y * v.y + (double)v.z * v.z + (double)v.w * v.w;
  }
  __shared__ double s1[256], s2[256];
  s1[threadIdx.x] = dsum; s2[threadIdx.x] = dsq;
  __syncthreads();
  for (int off = 128; off; off >>= 1) {
    if (threadIdx.x < off) { s1[threadIdx.x] += s1[threadIdx.x + off]; s2[threadIdx.x] += s2[threadIdx.x + off]; }
    __syncthreads();
  }
  if (threadIdx.x == 0) { part[2 * bi] = s1[0]; part[2 * bi + 1] = s2[0]; }
}

__global__ __launch_bounds__(64) void stats2_kernel(const double* __restrict__ part, int n,
                                                    float* __restrict__ mean_out,
                                                    float* __restrict__ rstd_out) {
  int s = blockIdx.x;
  int lane = threadIdx.x;
  double sum = 0.0, sq = 0.0;
  if (lane < 32) { sum = part[2 * (s * 32 + lane)]; sq = part[2 * (s * 32 + lane) + 1]; }
#pragma unroll
  for (int m = 16; m; m >>= 1) { sum += __shfl_xor(sum, m, 64); sq += __shfl_xor(sq, m, 64); }
  if (lane == 0) {
    double mean = sum / n;
    double var = sq / n - mean * mean;
    mean_out[s] = (float)mean;
    rstd_out[s] = (float)(1.0 / sqrt(var + 1e-5));
  }
}

// x_cat[bl][ch][p]: ch<64 dz, 64..127 instance-normed img, 128..191 sigma
__global__ __launch_bounds__(256) void build_xcat_kernel(const float* __restrict__ img,
                                                         const float* __restrict__ dz,
                                                         const float* __restrict__ sg,
                                                         const float* __restrict__ stats,
                                                         float* __restrict__ xcat) {
  size_t gid = (size_t)blockIdx.x * 256 + threadIdx.x;
  int p = gid & 4095;
  size_t r = gid >> 12;
  int ch = (int)(r % NC3);
  int bl = (int)(r / NC3);
  int b = bl / 3;
  float v;
  if (ch < 64) {
    v = dz[((size_t)b * NC + ch) * NHW + p];
  } else if (ch < 128) {
    float m = stats[bl], rs = stats[8 + bl];
    v = (img[((size_t)bl * NC + (ch - 64)) * NHW + p] - m) * rs;
  } else {
    v = sg[((size_t)b * NC + (ch - 128)) * NHW + p];
  }
  xcat[gid] = v;
}

// GN + SiLU + NCHW->NHWC transpose + f32->bf16. grid NBL*64, block 256.
template <int CCH>
__global__ __launch_bounds__(256) void gnsilu_t_kernel(const float* __restrict__ in,
                                                       const float* __restrict__ g,
                                                       const float* __restrict__ b,
                                                       const float* __restrict__ stats,
                                                       ushortT* __restrict__ outb) {
  int bi = blockIdx.x;
  int bl = bi >> 6, h = bi & 63;
  __shared__ ushortT tile[CCH][66];
  float m = stats[bl], rs = stats[8 + bl];
  int t = threadIdx.x;
  for (int idx = t; idx < CCH * 64; idx += 256) {
    int ch = idx >> 6, w = idx & 63;
    float v = in[(((size_t)bl * CCH + ch) << 12) + (h << 6) + w];
    v = (v - m) * rs * g[ch] + b[ch];
    v = silu(v);
    tile[ch][w] = f2bf(v);
  }
  __syncthreads();
  constexpr int C8 = CCH / 8;
  for (int idx = t; idx < 64 * C8; idx += 256) {
    int w = idx / C8, c8 = idx % C8;
    short8v v;
#pragma unroll
    for (int j = 0; j < 8; ++j) v[j] = (short)tile[c8 * 8 + j][w];
    *(short8v*)&outb[(size_t)(bl * 4096 + h * 64 + w) * CCH + c8 * 8] = v;
  }
}

// Pre-pack conv weights into per-lane MFMA B-fragments (bf16).
__global__ __launch_bounds__(256) void wprep_kernel(const float* __restrict__ w,
                                                    ushortT* __restrict__ out,
                                                    int CIN, int KT) {
  int id = blockIdx.x * 256 + threadIdx.x;
  int j = id & 7;
  int lane = (id >> 3) & 63;
  int nt = (id >> 9) & 3;
  int rest = id >> 11;
  int kt = rest % KT;
  int tap = rest / KT;
  int oc = nt * 16 + (lane & 15);
  int ic = kt * 32 + ((lane >> 4) << 3) + j;
  int r = tap / 3, s = tap % 3;
  out[id] = f2bf(w[(((size_t)oc * CIN + ic) * 3 + r) * 3 + s]);
}

// Implicit-GEMM 3x3 SAME conv via bf16 MFMA, f32 accumulate.
template <int CIN>
__global__ __launch_bounds__(256) void conv_mfma_kernel(const ushortT* __restrict__ actb,
                                                        const ushortT* __restrict__ wb,
                                                        const float* __restrict__ bias,
                                                        float* __restrict__ out) {
  constexpr int KT = CIN / 32;
  constexpr int STRIDE = CIN + 8;
  constexpr int C8 = CIN / 8;
  int bi = blockIdx.x;
  int nh = bi & 1;
  int h = (bi >> 1) & 63;
  int bl = bi >> 7;
  int t = threadIdx.x;
  int wv = t >> 6, lane = t & 63;
  __shared__ ushortT lds[66 * STRIDE];
  float4v acc0 = {0.f, 0.f, 0.f, 0.f};
  float4v acc1 = {0.f, 0.f, 0.f, 0.f};
  int lrow = lane & 15;
  int lk = (lane >> 4) << 3;
  for (int dy = 0; dy < 3; ++dy) {
    int hh = h + dy - 1;
    bool valid = (hh >= 0) && (hh < 64);
    int hc = valid ? hh : 0;
    if (dy) __syncthreads();
    const ushortT* src = actb + (size_t)(bl * 4096 + hc * 64) * CIN;
    for (int idx = t; idx < 64 * C8; idx += 256) {
      int w = idx / C8, c8 = idx % C8;
      short8v v = {0, 0, 0, 0, 0, 0, 0, 0};
      if (valid) v = *(const short8v*)&src[(size_t)w * CIN + c8 * 8];
      *(short8v*)&lds[(w + 1) * STRIDE + c8 * 8] = v;
    }
    if (t < 2 * C8) {
      int which = t / C8, c8 = t % C8;
      short8v z = {0, 0, 0, 0, 0, 0, 0, 0};
      *(short8v*)&lds[(which ? 65 : 0) * STRIDE + c8 * 8] = z;
    }
    __syncthreads();
    for (int dx = 0; dx < 3; ++dx) {
      int tap = dy * 3 + dx;
      int wl = (wv << 4) + lrow + dx;
#pragma unroll
      for (int kt = 0; kt < KT; ++kt) {
        short8v a = *(const short8v*)&lds[wl * STRIDE + kt * 32 + lk];
        const ushortT* wp = wb + ((size_t)(((tap * KT + kt) * 4 + (nh << 1)) * 64 + lane) << 3);
        short8v b0 = *(const short8v*)&wp[0];
        short8v b1 = *(const short8v*)&wp[512];
        acc0 = __builtin_amdgcn_mfma_f32_16x16x32_bf16(a, b0, acc0, 0, 0, 0);
        acc1 = __builtin_amdgcn_mfma_f32_16x16x32_bf16(a, b1, acc1, 0, 0, 0);
      }
    }
  }
  int oc0 = (nh << 5) + lrow;
  int oc1 = oc0 + 16;
  int w0 = (wv << 4) + ((lane >> 4) << 2);
  float bv0 = bias[oc0], bv1 = bias[oc1];
  float4 o0 = make_float4(acc0[0] + bv0, acc0[1] + bv0, acc0[2] + bv0, acc0[3] + bv0);
  float4 o1 = make_float4(acc1[0] + bv1, acc1[1] + bv1, acc1[2] + bv1, acc1[3] + bv1);
  *(float4*)&out[(((size_t)bl * 64 + oc0) << 12) + (h << 6) + w0] = o0;
  *(float4*)&out[(((size_t)bl * 64 + oc1) << 12) + (h << 6) + w0] = o1;
}

// x_res[bl][p][oc] = h2[bl][oc][p] + 1x1skip(xcat)[oc] + skb[oc]   (NHWC out)
__global__ __launch_bounds__(256) void skip_kernel(const float* __restrict__ xcat,
                                                   const float* __restrict__ h2,
                                                   const float* __restrict__ skwt,
                                                   const float* __restrict__ skb,
                                                   float* __restrict__ xres) {
  int bi = blockIdx.x;
  int bl = bi >> 6, h = bi & 63;
  int t = threadIdx.x;
  int oc = t & 63, w0 = (t >> 6) << 4;
  __shared__ float lds[64][64];
  float acc[16];
#pragma unroll
  for (int i = 0; i < 16; ++i) acc[i] = 0.f;
  for (int cc = 0; cc < 3; ++cc) {
    __syncthreads();
    for (int idx = t; idx < 4096; idx += 256) {
      int ch = idx >> 6, w = idx & 63;
      lds[ch][w] = xcat[(((size_t)bl * NC3 + cc * 64 + ch) << 12) + (h << 6) + w];
    }
    __syncthreads();
    for (int ch = 0; ch < 64; ++ch) {
      float wv = skwt[((cc << 6) + ch) * 64 + oc];
#pragma unroll
      for (int i = 0; i < 16; ++i) acc[i] += wv * lds[ch][w0 + i];
    }
  }
  float bv = skb[oc];
  int p0 = (h << 6) + w0;
#pragma unroll
  for (int i = 0; i < 16; ++i) {
    float hv = h2[(((size_t)bl * 64 + oc) << 12) + p0 + i];
    xres[((size_t)bl * NHW + p0 + i) * 64 + oc] = acc[i] + bv + hv;
  }
}

// LN(ln1) + 64->256 proj, transposed weight wt[c(64)][oc(256)].
__global__ __launch_bounds__(256) void inproj_kernel(const float* __restrict__ xres,
                                                     const float* __restrict__ g,
                                                     const float* __restrict__ b,
                                                     const float* __restrict__ wt,
                                                     float* __restrict__ xxin,
                                                     float* __restrict__ z) {
  int wv = threadIdx.x >> 6, lane = threadIdx.x & 63;
  size_t pi0 = (size_t)blockIdx.x * 4;
  size_t pi = pi0 + wv;
  float x = xres[pi * 64 + lane];
  float s = wred64(x);
  float s2 = wred64(x * x);
  float m = s * (1.f / 64), var = s2 * (1.f / 64) - m * m;
  float rstd = rsqrtf(var + 1e-5f);
  float xln = (x - m) * rstd * g[lane] + b[lane];
  __shared__ float xb[64][4];
  xb[lane][wv] = xln;
  __syncthreads();
  float acc[4] = {0.f, 0.f, 0.f, 0.f};
  int oc = (wv << 6) + lane;
  for (int c = 0; c < 64; ++c) {
    float4 xv = *(const float4*)&xb[c][0];
    float w = wt[(c << 8) + oc];
    acc[0] += w * xv.x; acc[1] += w * xv.y; acc[2] += w * xv.z; acc[3] += w * xv.w;
  }
#pragma unroll
  for (int p = 0; p < 4; ++p) {
    size_t pp = pi0 + p;
    if (oc < 128) xxin[(pp << 7) + oc] = acc[p];
    else z[(pp << 7) + (oc - 128)] = acc[p];
  }
}

// depthwise 3x3 SAME + bias + silu on NHWC [bl][p][128]
__global__ __launch_bounds__(256) void dwconv_kernel(const float* __restrict__ xx,
                                                     const float* __restrict__ w,
                                                     const float* __restrict__ b,
                                                     float* __restrict__ out) {
  size_t gid = (size_t)blockIdx.x * 256 + threadIdx.x;
  int d = gid & 127;
  size_t pi = gid >> 7;
  int p = (int)(pi & 4095);
  int bl = (int)(pi >> 12);
  int h = p >> 6, wq = p & 63;
  float acc = b[d];
  const float* wr = w + d * 9;
#pragma unroll
  for (int dy = -1; dy <= 1; ++dy) {
    int hh = h + dy;
    if (hh < 0 || hh >= 64) continue;
#pragma unroll
    for (int dx = -1; dx <= 1; ++dx) {
      int ww = wq + dx;
      if (ww < 0 || ww >= 64) continue;
      acc += wr[(dy + 1) * 3 + (dx + 1)] * xx[(((size_t)bl << 12) + (hh << 6) + ww) * 128 + d];
    }
  }
  out[pi * 128 + d] = silu(acc);
}

// x_dbl[bk][c][l] = sum_d xpw[k][c][d] * xs[bk][d][l]
__global__ __launch_bounds__(256) void xdbl_kernel(const float* __restrict__ xxc,
                                                   const float* __restrict__ xpw,
                                                   float* __restrict__ xdbl) {
  int bi = blockIdx.x;
  int lt = bi & 63;
  int k = (bi >> 6) & 3;
  int bl = bi >> 8;
  int lbase = lt << 6;
  __shared__ float lds[64][132];
  int t = threadIdx.x;
  for (int idx = t; idx < 64 * 128; idx += 256) {
    int i = idx >> 7, d = idx & 127;
    int pos = map_pos(k, lbase + i);
    lds[i][d] = xxc[((size_t)bl * NHW + pos) * 128 + d];
  }
  __syncthreads();
  for (int oi = t; oi < 36 * 64; oi += 256) {
    int c = oi >> 6, l = oi & 63;
    const float* wrow = xpw + (k * 36 + c) * 128;
    float acc = 0.f;
    for (int d4 = 0; d4 < 32; ++d4) {
      float4 w4 = *(const float4*)&wrow[d4 << 2];
      float4 x4 = *(const float4*)&lds[l][d4 << 2];
      acc += w4.x * x4.x + w4.y * x4.y + w4.z * x4.z + w4.w * x4.w;
    }
    xdbl[(((size_t)(bl * 4 + k)) * 36 + c) * (size_t)NL + lbase + l] = acc;
  }
}

// ---- chunked selective scan ----
// grid = 24 bk * 128 chunks; block 128 (one thread per d).
__global__ __launch_bounds__(128) void scan_pass1_kernel(const float* __restrict__ xdbl,
                                                         const float* __restrict__ xxc,
                                                         const float* __restrict__ dtw,
                                                         const float* __restrict__ dtb,
                                                         const float* __restrict__ Alog,
                                                         float* __restrict__ chunkP,
                                                         float* __restrict__ chunkH) {
  int bi = blockIdx.x;
  int chunk = bi & (NCH - 1);
  int bk = bi >> 7;
  int k = bk & 3, bl = bk >> 2;
  int d = threadIdx.x;
  float4 wv = *(const float4*)(dtw + (size_t)(((k << 7) + d) << 2));
  float bias = dtb[(k << 7) + d];
  const float* ar = Alog + (size_t)(((k << 7) + d) << 4);
  float a1v = -__expf(ar[0]) * 1.44269504f;
  bool geom = true;
#pragma unroll
  for (int n = 1; n < 16; ++n) {
    float an = -__expf(ar[n]) * 1.44269504f;
    geom = geom && (fabsf(an - (float)(n + 1) * a1v) <= 1e-3f * fabsf((float)(n + 1) * a1v) + 1e-6f);
  }
  __shared__ float xd[SCLEN][20];
  int l0 = chunk << 5;
  for (int idx = threadIdx.x; idx < 20 * SCLEN; idx += 128) {
    int c = idx >> 5, li = idx & 31;
    xd[li][c] = xdbl[((size_t)bk * 36 + c) * (size_t)NL + l0 + li];
  }
  __syncthreads();
  const float* uB = xxc + ((size_t)bl << 19) + d;
  float4v h0 = {0.f, 0.f, 0.f, 0.f}, h1 = h0, h2 = h0, h3 = h0;
  float sdt = 0.f;
  float u_nxt = uB[(size_t)map_pos(k, l0) << 7];
  if (geom) {
    for (int li = 0; li < SCLEN; ++li) {
      float u = u_nxt;
      int nl = (li < SCLEN - 1) ? (li + 1) : (SCLEN - 1);
      u_nxt = uB[(size_t)map_pos(k, l0 + nl) << 7];
      const float4v* row = (const float4v*)&xd[li][0];
      float4v q0 = row[0];
      float accq = bias + wv.x * q0[0] + wv.y * q0[1] + wv.z * q0[2] + wv.w * q0[3];
      float dt = softplus_fast(accq);
      float dtu = dt * u;
      sdt += dt;
      float4v b0 = row[1], b1 = row[2], b2 = row[3], b3 = row[4];
      float4v e0, e1, e2, e3;
      pow_tree(exp2f(a1v * dt), e0, e1, e2, e3);
      h0 = e0 * h0 + dtu * b0;
      h1 = e1 * h1 + dtu * b1;
      h2 = e2 * h2 + dtu * b2;
      h3 = e3 * h3 + dtu * b3;
    }
  } else {
    float4v a0v, a1q, a2q, a3q;
#pragma unroll
    for (int j = 0; j < 4; ++j) {
      a0v[j] = -__expf(ar[j]) * 1.44269504f;
      a1q[j] = -__expf(ar[4 + j]) * 1.44269504f;
      a2q[j] = -__expf(ar[8 + j]) * 1.44269504f;
      a3q[j] = -__expf(ar[12 + j]) * 1.44269504f;
    }
    for (int li = 0; li < SCLEN; ++li) {
      float u = u_nxt;
      int nl = (li < SCLEN - 1) ? (li + 1) : (SCLEN - 1);
      u_nxt = uB[(size_t)map_pos(k, l0 + nl) << 7];
      const float4v* row = (const float4v*)&xd[li][0];
      float4v q0 = row[0];
      float accq = bias + wv.x * q0[0] + wv.y * q0[1] + wv.z * q0[2] + wv.w * q0[3];
      float dt = softplus_fast(accq);
      float dtu = dt * u;
      sdt += dt;
      float4v b0 = row[1], b1 = row[2], b2 = row[3], b3 = row[4];
      float4v e0, e1, e2, e3;
#pragma unroll
      for (int j = 0; j < 4; ++j) {
        e0[j] = exp2f(a0v[j] * dt);
        e1[j] = exp2f(a1q[j] * dt);
        e2[j] = exp2f(a2q[j] * dt);
        e3[j] = exp2f(a3q[j] * dt);
      }
      h0 = e0 * h0 + dtu * b0;
      h1 = e1 * h1 + dtu * b1;
      h2 = e2 * h2 + dtu * b2;
      h3 = e3 * h3 + dtu * b3;
    }
  }
  size_t base = (size_t)chunk * NSTATE + (((size_t)bk << 7) + (size_t)d) * 16;
  float4v p0, p1, p2, p3;
  if (geom) {
    pow_tree(exp2f(a1v * sdt), p0, p1, p2, p3);
  } else {
#pragma unroll
    for (int j = 0; j < 4; ++j) {
      p0[j] = exp2f(-__expf(ar[j]) * 1.44269504f * sdt);
      p1[j] = exp2f(-__expf(ar[4 + j]) * 1.44269504f * sdt);
      p2[j] = exp2f(-__expf(ar[8 + j]) * 1.44269504f * sdt);
      p3[j] = exp2f(-__expf(ar[12 + j]) * 1.44269504f * sdt);
    }
  }
  *(float4v*)&chunkP[base + 0] = p0;
  *(float4v*)&chunkP[base + 4] = p1;
  *(float4v*)&chunkP[base + 8] = p2;
  *(float4v*)&chunkP[base + 12] = p3;
  *(float4v*)&chunkH[base + 0] = h0;
  *(float4v*)&chunkH[base + 4] = h1;
  *(float4v*)&chunkH[base + 8] = h2;
  *(float4v*)&chunkH[base + 12] = h3;
}

__global__ __launch_bounds__(256) void scan_pass2_kernel(const float* __restrict__ chunkP,
                                                         const float* __restrict__ chunkH,
                                                         float* __restrict__ chunkHS) {
  size_t state = (size_t)blockIdx.x * 256 + threadIdx.x;
  float h = 0.f;
#pragma unroll 4
  for (int j = 0; j < NCH; ++j) {
    size_t idx = (size_t)j * NSTATE + state;
    chunkHS[idx] = h;
    h = chunkP[idx] * h + chunkH[idx];
  }
}

__global__ __launch_bounds__(128) void scan_pass3_kernel(const float* __restrict__ xdbl,
                                                         const float* __restrict__ xxc,
                                                         const float* __restrict__ dtw,
                                                         const float* __restrict__ dtb,
                                                         const float* __restrict__ Alog,
                                                         const float* __restrict__ chunkHS,
                                                         float* __restrict__ ys) {
  int bi = blockIdx.x;
  int chunk = bi & (NCH - 1);
  int bk = bi >> 7;
  int k = bk & 3, bl = bk >> 2;
  int d = threadIdx.x;
  float4 wv = *(const float4*)(dtw + (size_t)(((k << 7) + d) << 2));
  float bias = dtb[(k << 7) + d];
  const float* ar = Alog + (size_t)(((k << 7) + d) << 4);
  float a1v = -__expf(ar[0]) * 1.44269504f;
  bool geom = true;
#pragma unroll
  for (int n = 1; n < 16; ++n) {
    float an = -__expf(ar[n]) * 1.44269504f;
    geom = geom && (fabsf(an - (float)(n + 1) * a1v) <= 1e-3f * fabsf((float)(n + 1) * a1v) + 1e-6f);
  }
  __shared__ float xd[SCLEN][36];
  int l0 = chunk << 5;
  for (int idx = threadIdx.x; idx < 36 * SCLEN; idx += 128) {
    int c = idx >> 5, li = idx & 31;
    xd[li][c] = xdbl[((size_t)bk * 36 + c) * (size_t)NL + l0 + li];
  }
  __syncthreads();
  const float* uB = xxc + ((size_t)bl << 19) + d;
  float* yB = ys + ((size_t)bk << 19) + d;
  size_t base = (size_t)chunk * NSTATE + (((size_t)bk << 7) + (size_t)d) * 16;
  float4v h0 = *(const float4v*)&chunkHS[base + 0];
  float4v h1 = *(const float4v*)&chunkHS[base + 4];
  float4v h2 = *(const float4v*)&chunkHS[base + 8];
  float4v h3 = *(const float4v*)&chunkHS[base + 12];
  float u_nxt = uB[(size_t)map_pos(k, l0) << 7];
  if (geom) {
    for (int li = 0; li < SCLEN; ++li) {
      float u = u_nxt;
      int nl = (li < SCLEN - 1) ? (li + 1) : (SCLEN - 1);
      u_nxt = uB[(size_t)map_pos(k, l0 + nl) << 7];
      const float4v* row = (const float4v*)&xd[li][0];
      float4v q0 = row[0];
      float accq = bias + wv.x * q0[0] + wv.y * q0[1] + wv.z * q0[2] + wv.w * q0[3];
      float dt = softplus_fast(accq);
      float dtu = dt * u;
      float4v b0 = row[1], b1 = row[2], b2 = row[3], b3 = row[4];
      float4v c0 = row[5], c1 = row[6], c2 = row[7], c3 = row[8];
      float4v e0, e1, e2, e3;
      pow_tree(exp2f(a1v * dt), e0, e1, e2, e3);
      h0 = e0 * h0 + dtu * b0;
      h1 = e1 * h1 + dtu * b1;
      h2 = e2 * h2 + dtu * b2;
      h3 = e3 * h3 + dtu * b3;
      float4v sy = h0 * c0;
      sy += h1 * c1;
      sy += h2 * c2;
      sy += h3 * c3;
      yB[(size_t)(l0 + li) << 7] = (sy[0] + sy[1]) + (sy[2] + sy[3]);
    }
  } else {
    float4v a0v, a1q, a2q, a3q;
#pragma unroll
    for (int j = 0; j < 4; ++j) {
      a0v[j] = -__expf(ar[j]) * 1.44269504f;
      a1q[j] = -__expf(ar[4 + j]) * 1.44269504f;
      a2q[j] = -__expf(ar[8 + j]) * 1.44269504f;
      a3q[j] = -__expf(ar[12 + j]) * 1.44269504f;
    }
    for (int li = 0; li < SCLEN; ++li) {
      float u = u_nxt;
      int nl = (li < SCLEN - 1) ? (li + 1) : (SCLEN - 1);
      u_nxt = uB[(size_t)map_pos(k, l0 + nl) << 7];
      const float4v* row = (const float4v*)&xd[li][0];
      float4v q0 = row[0];
      float accq = bias + wv.x * q0[0] + wv.y * q0[1] + wv.z * q0[2] + wv.w * q0[3];
      float dt = softplus_fast(accq);
      float dtu = dt * u;
      float4v b0 = row[1], b1 = row[2], b2 = row[3], b3 = row[4];
      float4v c0 = row[5], c1 = row[6], c2 = row[7], c3 = row[8];
      float4v e0, e1, e2, e3;
#pragma unroll
      for (int j = 0; j < 4; ++j) {
        e0[j] = exp2f(a0v[j] * dt);
        e1[j] = exp2f(a1q[j] * dt);
        e2[j] = exp2f(a2q[j] * dt);
        e3[j] = exp2f(a3q[j] * dt);
      }
      h0 = e0 * h0 + dtu * b0;
      h1 = e1 * h1 + dtu * b1;
      h2 = e2 * h2 + dtu * b2;
      h3 = e3 * h3 + dtu * b3;
      float4v sy = h0 * c0;
      sy += h1 * c1;
      sy += h2 * c2;
      sy += h3 * c3;
      yB[(size_t)(l0 + li) << 7] = (sy[0] + sy[1]) + (sy[2] + sy[3]);
    }
  }
}

// ycomb[bl][p][d] = sum of 4 direction outputs (mapped) + xxc * sum_k Ds
__global__ __launch_bounds__(256) void combine_kernel(const float* __restrict__ ys,
                                                      const float* __restrict__ xxc,
                                                      const float* __restrict__ Ds,
                                                      float* __restrict__ ycomb) {
  size_t gid = (size_t)blockIdx.x * 256 + threadIdx.x;
  int d = gid & 127;
  size_t pi = gid >> 7;
  int p = (int)(pi & 4095);
  int bl = (int)(pi >> 12);
  int h = p >> 6, w = p & 63;
  int l1 = (w << 6) | h;
  size_t base = ((size_t)bl * 4) << 12;
  float v = ys[((base + p) << 7) + d]
          + ys[((base + 4096 + l1) << 7) + d]
          + ys[((base + 2 * 4096 + (4095 - p)) << 7) + d]
          + ys[((base + 3 * 4096 + (4095 - l1)) << 7) + d];
  float ds = Ds[d] + Ds[128 + d] + Ds[256 + d] + Ds[384 + d];
  v += xxc[(pi << 7) + d] * ds;
  ycomb[(pi << 7) + d] = v;
}

// out_norm LN(128) -> *silu(z) -> out_proj (transposed wt[c(128)][oc(64)]) -> + x_res
__global__ __launch_bounds__(256) void outproj_kernel(const float* __restrict__ ycomb,
                                                      const float* __restrict__ z,
                                                      const float* __restrict__ ong,
                                                      const float* __restrict__ onb,
                                                      const float* __restrict__ opwt,
                                                      const float* __restrict__ xres,
                                                      float* __restrict__ x1) {
  int wv = threadIdx.x >> 6, lane = threadIdx.x & 63;
  size_t pi = (size_t)blockIdx.x * 4 + wv;
  float y0 = ycomb[(pi << 7) + lane], y1 = ycomb[(pi << 7) + 64 + lane];
  float s = wred64(y0 + y1);
  float s2 = wred64(y0 * y0 + y1 * y1);
  float m = s * (1.f / 128), var = s2 * (1.f / 128) - m * m;
  float rstd = rsqrtf(var + 1e-5f);
  float z0 = z[(pi << 7) + lane], z1 = z[(pi << 7) + 64 + lane];
  float g0 = ((y0 - m) * rstd * ong[lane] + onb[lane]) * silu(z0);
  float g1 = ((y1 - m) * rstd * ong[64 + lane] + onb[64 + lane]) * silu(z1);
  __shared__ float gb[128][4];
  gb[lane][wv] = g0;
  gb[64 + lane][wv] = g1;
  __syncthreads();
  float acc = 0.f;
  for (int c = 0; c < 128; ++c) {
    acc += opwt[(c << 6) + lane] * gb[c][wv];
  }
  x1[pi * 64 + lane] = xres[pi * 64 + lane] + acc;
}

// ln2 -> fc1 -> gelu(tanh) -> fc2 -> residual; transposed weights wt[c][oc]
__global__ __launch_bounds__(256) void mlp_kernel(const float* __restrict__ x1,
                                                  const float* __restrict__ g2,
                                                  const float* __restrict__ b2,
                                                  const float* __restrict__ w1t,
                                                  const float* __restrict__ bb1,
                                                  const float* __restrict__ w2t,
                                                  const float* __restrict__ bb2,
                                                  float* __restrict__ x2) {
  int wv = threadIdx.x >> 6, lane = threadIdx.x & 63;
  size_t pi = (size_t)blockIdx.x * 4 + wv;
  float xv = x1[pi * 64 + lane];
  float s = wred64(xv), s2 = wred64(xv * xv);
  float m = s * (1.f / 64), var = s2 * (1.f / 64) - m * m;
  float rstd = rsqrtf(var + 1e-5f);
  float xm = (xv - m) * rstd * g2[lane] + b2[lane];
  __shared__ float xb[64][4], tb[64][4];
  xb[lane][wv] = xm;
  __syncthreads();
  float acc = bb1[lane];
  for (int c = 0; c < 64; ++c) acc += w1t[(c << 6) + lane] * xb[c][wv];
  float u = acc;
  float tt = tanhf(0.7978845608028654f * (u + 0.044715f * u * u * u));
  float t1 = 0.5f * u * (1.f + tt);
  tb[lane][wv] = t1;
  __syncthreads();
  float acc2 = bb2[lane];
  for (int c = 0; c < 64; ++c) acc2 += w2t[(c << 6) + lane] * tb[c][wv];
  x2[pi * 64 + lane] = xv + acc2;
}

// NHWC (bl,p,c) -> NCHW (bl,c,p) tiled transpose into d_out
__global__ __launch_bounds__(256) void transpose_out_kernel(const float* __restrict__ x2,
                                                            float* __restrict__ out) {
  int bi = blockIdx.x;
  int pt = bi & 127;
  int ct = (bi >> 7) & 1;
  int bl = bi >> 8;
  __shared__ float lds[32][33];
  int t = threadIdx.x;
  int j = t & 31, i0 = t >> 5;
  int p0 = pt << 5, c0 = ct << 5;
#pragma unroll
  for (int q = 0; q < 4; ++q) {
    int i = i0 + (q << 3);
    lds[i][j] = x2[((size_t)bl * NHW + p0 + i) * 64 + c0 + j];
  }
  __syncthreads();
#pragma unroll
  for (int q = 0; q < 4; ++q) {
    int i = i0 + (q << 3);
    out[((size_t)bl * 64 + c0 + i) * (size_t)NHW + p0 + j] = lds[j][i];
  }
}

extern "C" void kernel_launch(void* const* d_in, const int* in_sizes, int n_in,
                              void* d_out, int out_size, void* d_ws, size_t ws_size,
                              hipStream_t stream) {
  const float* img  = (const float*)d_in[0];
  const float* dz   = (const float*)d_in[1];
  const float* sg   = (const float*)d_in[2];
  const float* gn1g = (const float*)d_in[3];
  const float* gn1b = (const float*)d_in[4];
  const float* c1w  = (const float*)d_in[5];
  const float* c1b  = (const float*)d_in[6];
  const float* gn2g = (const float*)d_in[7];
  const float* gn2b = (const float*)d_in[8];
  const float* c2w  = (const float*)d_in[9];
  const float* c2b  = (const float*)d_in[10];
  const float* skw  = (const float*)d_in[11];
  const float* skb  = (const float*)d_in[12];
  const float* ln1g = (const float*)d_in[13];
  const float* ln1b = (const float*)d_in[14];
  const float* ln2g = (const float*)d_in[15];
  const float* ln2b = (const float*)d_in[16];
  const float* ipw  = (const float*)d_in[17];
  const float* dww  = (const float*)d_in[18];
  const float* dwb  = (const float*)d_in[19];
  const float* xpw  = (const float*)d_in[20];
  const float* dtw  = (const float*)d_in[21];
  const float* dtb  = (const float*)d_in[22];
  const float* Alog = (const float*)d_in[23];
  const float* Dsp  = (const float*)d_in[24];
  const float* ong  = (const float*)d_in[25];
  const float* onb  = (const float*)d_in[26];
  const float* opw  = (const float*)d_in[27];
  const float* f1w  = (const float*)d_in[28];
  const float* f1b  = (const float*)d_in[29];
  const float* f2w  = (const float*)d_in[30];
  const float* f2b  = (const float*)d_in[31];

  float* out = (float*)d_out;
  float* ws = (float*)d_ws;
  if (ws_size < F_TOTAL * sizeof(float)) return;

  float* xcat  = ws + F_XCAT;
  float* h1    = ws + F_H1;
  float* h2    = ws + F_H2;
  float* xres  = ws + F_XRES;
  float* xxin  = ws + F_XXIN;
  float* zbuf  = ws + F_Z;
  float* xxc   = ws + F_XXC;
  float* xdbl  = ws + F_XDBL;
  float* ysb   = ws + F_YS;
  float* ycomb = ws + F_YCOMB;
  float* x1    = ws + F_X1;
  float* x2    = ws + F_X2;
  float* stats = ws + F_STATS;
  ushortT* act1b = (ushortT*)(ws + F_ACT1);
  ushortT* act2b = (ushortT*)(ws + F_ACT2);
  // stats partials + conv weight packs live in X2 region (dead until mlp)
  double* part  = (double*)(ws + F_X2);              // 768 floats
  ushortT* wb1  = (ushortT*)(ws + F_X2 + 1024);      // 110592 ushorts
  ushortT* wb2  = wb1 + 110592;                      // 36864 ushorts
  // scan chunk arrays: P+H fill YS exactly (ys overwrites in pass3); HS in XCAT span
  float* chunkP  = ws + F_YS;                        // 6,291,456
  float* chunkH  = ws + F_YS + 6291456;              // 6,291,456
  float* chunkHS = ws + F_XCAT;                      // 6,291,456 (XCAT+ACT1, dead after inproj)
  // transposed small-GEMM weights
  float* wt_sk = ws + F_ACT1;                        // dead after skip
  float* wt_ip = ws + F_XCAT;                        // dead after inproj
  float* wt_op = ws + F_XXIN;                        // XXIN dead after dwconv
  float* wt_f1 = ws + F_XXIN + 8192;
  float* wt_f2 = ws + F_XXIN + 12288;

  // conv weight prepacks (no deps)
  wprep_kernel<<<432, 256, 0, stream>>>(c1w, wb1, NC3, 6);
  wprep_kernel<<<144, 256, 0, stream>>>(c2w, wb2, NC, 2);
  // stage 0: instance-norm stats
  stats1_kernel<<<NBL * 32, 256, 0, stream>>>(img, NC * NHW, part);
  stats2_kernel<<<NBL, 64, 0, stream>>>(part, NC * NHW, stats + 0, stats + 8);
  build_xcat_kernel<<<18432, 256, 0, stream>>>(img, dz, sg, stats, xcat);
  // gn1 + silu -> NHWC bf16
  stats1_kernel<<<NBL * 32, 256, 0, stream>>>(xcat, NC3 * NHW, part);
  stats2_kernel<<<NBL, 64, 0, stream>>>(part, NC3 * NHW, stats + 16, stats + 24);
  gnsilu_t_kernel<NC3><<<NBL * 64, 256, 0, stream>>>(xcat, gn1g, gn1b, stats + 16, act1b);
  conv_mfma_kernel<NC3><<<NBL * 64 * 2, 256, 0, stream>>>(act1b, wb1, c1b, h1);
  wtrans_kernel<<<48, 256, 0, stream>>>(skw, wt_sk, 64, 192);
  // gn2 + silu -> NHWC bf16
  stats1_kernel<<<NBL * 32, 256, 0, stream>>>(h1, NC * NHW, part);
  stats2_kernel<<<NBL, 64, 0, stream>>>(part, NC * NHW, stats + 32, stats + 40);
  gnsilu_t_kernel<NC><<<NBL * 64, 256, 0, stream>>>(h1, gn2g, gn2b, stats + 32, act2b);
  conv_mfma_kernel<NC><<<NBL * 64 * 2, 256, 0, stream>>>(act2b, wb2, c2b, h2);
  // skip 1x1 + residual + NHWC transpose
  skip_kernel<<<NBL * 64, 256, 0, stream>>>(xcat, h2, wt_sk, skb, xres);
  wtrans_kernel<<<64, 256, 0, stream>>>(ipw, wt_ip, 256, 64);
  // SS2D
  inproj_kernel<<<6144, 256, 0, stream>>>(xres, ln1g, ln1b, wt_ip, xxin, zbuf);
  dwconv_kernel<<<12288, 256, 0, stream>>>(xxin, dww, dwb, xxc);
  wtrans_kernel<<<32, 256, 0, stream>>>(opw, wt_op, 64, 128);
  wtrans_kernel<<<16, 256, 0, stream>>>(f1w, wt_f1, 64, 64);
  wtrans_kernel<<<16, 256, 0, stream>>>(f2w, wt_f2, 64, 64);
  xdbl_kernel<<<NBL * NK * 64, 256, 0, stream>>>(xxc, xpw, xdbl);
  // chunked scan (128 chunks of 32)
  scan_pass1_kernel<<<24 * NCH, 128, 0, stream>>>(xdbl, xxc, dtw, dtb, Alog, chunkP, chunkH);
  scan_pass2_kernel<<<192, 256, 0, stream>>>(chunkP, chunkH, chunkHS);
  scan_pass3_kernel<<<24 * NCH, 128, 0, stream>>>(xdbl, xxc, dtw, dtb, Alog, chunkHS, ysb);
  combine_kernel<<<12288, 256, 0, stream>>>(ysb, xxc, Dsp, ycomb);
  outproj_kernel<<<6144, 256, 0, stream>>>(ycomb, zbuf, ong, onb, wt_op, xres, x1);
  // MLP + residual
  mlp_kernel<<<6144, 256, 0, stream>>>(x1, ln2g, ln2b, wt_f1, f1b, wt_f2, f2b, x2);
  // final transpose to NCHW output
  transpose_out_kernel<<<NBL * 256, 256, 0, stream>>>(x2, out);
}

// Round 9
// 404.013 us; speedup vs baseline: 2.8591x; 1.2426x over previous
//
#include <hip/hip_runtime.h>
#include <hip/hip_bf16.h>

typedef unsigned short ushortT;
typedef short short8v __attribute__((ext_vector_type(8)));
typedef float float4v __attribute__((ext_vector_type(4)));

// Problem constants
#define NBL 6      // B*LEN
#define NC 64
#define NC3 192
#define NHW 4096   // 64*64
#define NDI 128
#define NNS 16
#define NDR 4
#define NK 4
#define NL 4096
#define NCH 128    // scan chunks
#define SCLEN 32   // chunk length
#define NSTATE 49152  // 24 bk * 128 d * 16 n

// workspace offsets in floats
static const size_t F_XCAT  = 0;          // 4,718,592 (wt_ip after skip; chunkHS span during scan)
static const size_t F_ACT1  = 4718592;    // act1b bf16 NHWC; wt_sk after conv1; chunkHS tail
static const size_t F_H1    = 9437184;    // 1,572,864
static const size_t F_ACT2  = 11010048;   // act2b bf16 NHWC
static const size_t F_H2    = 12582912;   // 1,572,864
static const size_t F_XRES  = 14155776;   // 1,572,864
static const size_t F_XXIN  = 15728640;   // 3,145,728 (wt_op/f1/f2 after dwconv)
static const size_t F_Z     = 18874368;   // 3,145,728
static const size_t F_XXC   = 22020096;   // 3,145,728
static const size_t F_XDBL  = 25165824;   // 3,538,944
static const size_t F_YS    = 28704768;   // 12,582,912 (chunkP+chunkH during scan; ys after)
static const size_t F_YCOMB = 41287680;   // 3,145,728
static const size_t F_X1    = 44433408;   // 1,572,864
static const size_t F_X2    = 46006272;   // 1,572,864 (stats partials + conv wpacks early)
static const size_t F_STATS = 47579136;   // 48
static const size_t F_TOTAL = 47579184;   // floats (~190.3 MB)

__device__ __forceinline__ float wred64(float v) {
#pragma unroll
  for (int m = 32; m; m >>= 1) v += __shfl_xor(v, m, 64);
  return v;
}

__device__ __forceinline__ float silu(float v) {
  return v / (1.f + __expf(-v));
}

__device__ __forceinline__ ushortT f2bf(float f) {
  unsigned int u = __builtin_bit_cast(unsigned int, f);
  unsigned int r = (u + 0x7FFFu + ((u >> 16) & 1u)) >> 16;
  return (ushortT)r;
}

__device__ __forceinline__ int map_pos(int k, int l) {
  if (k == 0) return l;
  if (k == 1) return ((l & 63) << 6) | (l >> 6);
  if (k == 2) return 4095 - l;
  int lp = 4095 - l;
  return ((lp & 63) << 6) | (lp >> 6);
}

// softplus via hw exp2/log2: ln(1+e^a) = ln2 * log2(1 + 2^(a*log2e))
__device__ __forceinline__ float softplus_fast(float a) {
  float t = exp2f(a * 1.44269504f);
  float r = 0.69314718f * __log2f(1.f + t);
  return (a > 20.f) ? a : r;
}

// powers E^1..E^16 via mul tree (for geometric A: a_n = (n+1)*a_1)
__device__ __forceinline__ void pow_tree(float E1, float4v& e0, float4v& e1,
                                         float4v& e2, float4v& e3) {
  float E2 = E1 * E1, E3 = E2 * E1, E4 = E2 * E2;
  float E5 = E4 * E1, E6 = E4 * E2, E7 = E4 * E3, E8 = E4 * E4;
  e0[0] = E1; e0[1] = E2; e0[2] = E3; e0[3] = E4;
  e1[0] = E5; e1[1] = E6; e1[2] = E7; e1[3] = E8;
  e2[0] = E8 * E1; e2[1] = E8 * E2; e2[2] = E8 * E3; e2[3] = E8 * E4;
  e3[0] = E8 * E5; e3[1] = E8 * E6; e3[2] = E8 * E7; e3[3] = E8 * E8;
}

// generic weight transpose: dst[c*O + o] = src[o*C + c]
__global__ __launch_bounds__(256) void wtrans_kernel(const float* __restrict__ src,
                                                     float* __restrict__ dst, int O, int C) {
  int id = blockIdx.x * 256 + threadIdx.x;
  if (id >= O * C) return;
  int c = id / O, o = id % O;
  dst[id] = src[o * C + c];
}

// ---- two-stage per-sample mean/rstd (f64 accumulate) ----
__global__ __launch_bounds__(256) void stats1_kernel(const float* __restrict__ in, int n,
                                                     double* __restrict__ part) {
  int bi = blockIdx.x;
  int s = bi >> 5, j = bi & 31;
  int slice = n >> 5;
  const float4* p = (const float4*)(in + (size_t)s * n + (size_t)j * slice);
  int n4 = slice >> 2;
  double dsum = 0.0, dsq = 0.0;
  for (int i = threadIdx.x; i < n4; i += 256) {
    float4 v = p[i];
    dsum += (double)((v.x + v.y) + (v.z + v.w));
    dsq += (double)v.x * v.x + (double)v.y * v.y + (double)v.z * v.z + (double)v.w * v.w;
  }
  __shared__ double s1[256], s2[256];
  s1[threadIdx.x] = dsum; s2[threadIdx.x] = dsq;
  __syncthreads();
  for (int off = 128; off; off >>= 1) {
    if (threadIdx.x < off) { s1[threadIdx.x] += s1[threadIdx.x + off]; s2[threadIdx.x] += s2[threadIdx.x + off]; }
    __syncthreads();
  }
  if (threadIdx.x == 0) { part[2 * bi] = s1[0]; part[2 * bi + 1] = s2[0]; }
}

__global__ __launch_bounds__(64) void stats2_kernel(const double* __restrict__ part, int n,
                                                    float* __restrict__ mean_out,
                                                    float* __restrict__ rstd_out) {
  int s = blockIdx.x;
  int lane = threadIdx.x;
  double sum = 0.0, sq = 0.0;
  if (lane < 32) { sum = part[2 * (s * 32 + lane)]; sq = part[2 * (s * 32 + lane) + 1]; }
#pragma unroll
  for (int m = 16; m; m >>= 1) { sum += __shfl_xor(sum, m, 64); sq += __shfl_xor(sq, m, 64); }
  if (lane == 0) {
    double mean = sum / n;
    double var = sq / n - mean * mean;
    mean_out[s] = (float)mean;
    rstd_out[s] = (float)(1.0 / sqrt(var + 1e-5));
  }
}

// x_cat[bl][ch][p]: ch<64 dz, 64..127 instance-normed img, 128..191 sigma
__global__ __launch_bounds__(256) void build_xcat_kernel(const float* __restrict__ img,
                                                         const float* __restrict__ dz,
                                                         const float* __restrict__ sg,
                                                         const float* __restrict__ stats,
                                                         float* __restrict__ xcat) {
  size_t gid = (size_t)blockIdx.x * 256 + threadIdx.x;
  int p = gid & 4095;
  size_t r = gid >> 12;
  int ch = (int)(r % NC3);
  int bl = (int)(r / NC3);
  int b = bl / 3;
  float v;
  if (ch < 64) {
    v = dz[((size_t)b * NC + ch) * NHW + p];
  } else if (ch < 128) {
    float m = stats[bl], rs = stats[8 + bl];
    v = (img[((size_t)bl * NC + (ch - 64)) * NHW + p] - m) * rs;
  } else {
    v = sg[((size_t)b * NC + (ch - 128)) * NHW + p];
  }
  xcat[gid] = v;
}

// GN + SiLU + NCHW->NHWC transpose + f32->bf16. grid NBL*64, block 256.
template <int CCH>
__global__ __launch_bounds__(256) void gnsilu_t_kernel(const float* __restrict__ in,
                                                       const float* __restrict__ g,
                                                       const float* __restrict__ b,
                                                       const float* __restrict__ stats,
                                                       ushortT* __restrict__ outb) {
  int bi = blockIdx.x;
  int bl = bi >> 6, h = bi & 63;
  __shared__ ushortT tile[CCH][66];
  float m = stats[bl], rs = stats[8 + bl];
  int t = threadIdx.x;
  for (int idx = t; idx < CCH * 64; idx += 256) {
    int ch = idx >> 6, w = idx & 63;
    float v = in[(((size_t)bl * CCH + ch) << 12) + (h << 6) + w];
    v = (v - m) * rs * g[ch] + b[ch];
    v = silu(v);
    tile[ch][w] = f2bf(v);
  }
  __syncthreads();
  constexpr int C8 = CCH / 8;
  for (int idx = t; idx < 64 * C8; idx += 256) {
    int w = idx / C8, c8 = idx % C8;
    short8v v;
#pragma unroll
    for (int j = 0; j < 8; ++j) v[j] = (short)tile[c8 * 8 + j][w];
    *(short8v*)&outb[(size_t)(bl * 4096 + h * 64 + w) * CCH + c8 * 8] = v;
  }
}

// Pre-pack conv weights into per-lane MFMA B-fragments (bf16).
__global__ __launch_bounds__(256) void wprep_kernel(const float* __restrict__ w,
                                                    ushortT* __restrict__ out,
                                                    int CIN, int KT) {
  int id = blockIdx.x * 256 + threadIdx.x;
  int j = id & 7;
  int lane = (id >> 3) & 63;
  int nt = (id >> 9) & 3;
  int rest = id >> 11;
  int kt = rest % KT;
  int tap = rest / KT;
  int oc = nt * 16 + (lane & 15);
  int ic = kt * 32 + ((lane >> 4) << 3) + j;
  int r = tap / 3, s = tap % 3;
  out[id] = f2bf(w[(((size_t)oc * CIN + ic) * 3 + r) * 3 + s]);
}

// Implicit-GEMM 3x3 SAME conv via bf16 MFMA, f32 accumulate.
template <int CIN>
__global__ __launch_bounds__(256) void conv_mfma_kernel(const ushortT* __restrict__ actb,
                                                        const ushortT* __restrict__ wb,
                                                        const float* __restrict__ bias,
                                                        float* __restrict__ out) {
  constexpr int KT = CIN / 32;
  constexpr int STRIDE = CIN + 8;
  constexpr int C8 = CIN / 8;
  int bi = blockIdx.x;
  int nh = bi & 1;
  int h = (bi >> 1) & 63;
  int bl = bi >> 7;
  int t = threadIdx.x;
  int wv = t >> 6, lane = t & 63;
  __shared__ ushortT lds[66 * STRIDE];
  float4v acc0 = {0.f, 0.f, 0.f, 0.f};
  float4v acc1 = {0.f, 0.f, 0.f, 0.f};
  int lrow = lane & 15;
  int lk = (lane >> 4) << 3;
  for (int dy = 0; dy < 3; ++dy) {
    int hh = h + dy - 1;
    bool valid = (hh >= 0) && (hh < 64);
    int hc = valid ? hh : 0;
    if (dy) __syncthreads();
    const ushortT* src = actb + (size_t)(bl * 4096 + hc * 64) * CIN;
    for (int idx = t; idx < 64 * C8; idx += 256) {
      int w = idx / C8, c8 = idx % C8;
      short8v v = {0, 0, 0, 0, 0, 0, 0, 0};
      if (valid) v = *(const short8v*)&src[(size_t)w * CIN + c8 * 8];
      *(short8v*)&lds[(w + 1) * STRIDE + c8 * 8] = v;
    }
    if (t < 2 * C8) {
      int which = t / C8, c8 = t % C8;
      short8v z = {0, 0, 0, 0, 0, 0, 0, 0};
      *(short8v*)&lds[(which ? 65 : 0) * STRIDE + c8 * 8] = z;
    }
    __syncthreads();
    for (int dx = 0; dx < 3; ++dx) {
      int tap = dy * 3 + dx;
      int wl = (wv << 4) + lrow + dx;
#pragma unroll
      for (int kt = 0; kt < KT; ++kt) {
        short8v a = *(const short8v*)&lds[wl * STRIDE + kt * 32 + lk];
        const ushortT* wp = wb + ((size_t)(((tap * KT + kt) * 4 + (nh << 1)) * 64 + lane) << 3);
        short8v b0 = *(const short8v*)&wp[0];
        short8v b1 = *(const short8v*)&wp[512];
        acc0 = __builtin_amdgcn_mfma_f32_16x16x32_bf16(a, b0, acc0, 0, 0, 0);
        acc1 = __builtin_amdgcn_mfma_f32_16x16x32_bf16(a, b1, acc1, 0, 0, 0);
      }
    }
  }
  int oc0 = (nh << 5) + lrow;
  int oc1 = oc0 + 16;
  int w0 = (wv << 4) + ((lane >> 4) << 2);
  float bv0 = bias[oc0], bv1 = bias[oc1];
  float4 o0 = make_float4(acc0[0] + bv0, acc0[1] + bv0, acc0[2] + bv0, acc0[3] + bv0);
  float4 o1 = make_float4(acc1[0] + bv1, acc1[1] + bv1, acc1[2] + bv1, acc1[3] + bv1);
  *(float4*)&out[(((size_t)bl * 64 + oc0) << 12) + (h << 6) + w0] = o0;
  *(float4*)&out[(((size_t)bl * 64 + oc1) << 12) + (h << 6) + w0] = o1;
}

// x_res[bl][p][oc] = h2[bl][oc][p] + 1x1skip(xcat)[oc] + skb[oc]   (NHWC out)
__global__ __launch_bounds__(256) void skip_kernel(const float* __restrict__ xcat,
                                                   const float* __restrict__ h2,
                                                   const float* __restrict__ skwt,
                                                   const float* __restrict__ skb,
                                                   float* __restrict__ xres) {
  int bi = blockIdx.x;
  int bl = bi >> 6, h = bi & 63;
  int t = threadIdx.x;
  int oc = t & 63, w0 = (t >> 6) << 4;
  __shared__ float lds[64][64];
  float acc[16];
#pragma unroll
  for (int i = 0; i < 16; ++i) acc[i] = 0.f;
  for (int cc = 0; cc < 3; ++cc) {
    __syncthreads();
    for (int idx = t; idx < 4096; idx += 256) {
      int ch = idx >> 6, w = idx & 63;
      lds[ch][w] = xcat[(((size_t)bl * NC3 + cc * 64 + ch) << 12) + (h << 6) + w];
    }
    __syncthreads();
    for (int ch = 0; ch < 64; ++ch) {
      float wv = skwt[((cc << 6) + ch) * 64 + oc];
#pragma unroll
      for (int i = 0; i < 16; ++i) acc[i] += wv * lds[ch][w0 + i];
    }
  }
  float bv = skb[oc];
  int p0 = (h << 6) + w0;
#pragma unroll
  for (int i = 0; i < 16; ++i) {
    float hv = h2[(((size_t)bl * 64 + oc) << 12) + p0 + i];
    xres[((size_t)bl * NHW + p0 + i) * 64 + oc] = acc[i] + bv + hv;
  }
}

// LN(ln1) + 64->256 proj; 16 positions per block; wt[c(64)][oc(256)]. grid 1536.
__global__ __launch_bounds__(256) void inproj_kernel(const float* __restrict__ xres,
                                                     const float* __restrict__ g,
                                                     const float* __restrict__ b,
                                                     const float* __restrict__ wt,
                                                     float* __restrict__ xxin,
                                                     float* __restrict__ z) {
  int wv = threadIdx.x >> 6, lane = threadIdx.x & 63;
  size_t pi0 = (size_t)blockIdx.x << 4;
  __shared__ float xb[64][16];
  float gv = g[lane], bv = b[lane];
#pragma unroll
  for (int j = 0; j < 4; ++j) {
    int p = (wv << 2) + j;
    float x = xres[(pi0 + p) * 64 + lane];
    float s = wred64(x);
    float s2 = wred64(x * x);
    float m = s * (1.f / 64), var = s2 * (1.f / 64) - m * m;
    float rstd = rsqrtf(var + 1e-5f);
    xb[lane][p] = (x - m) * rstd * gv + bv;
  }
  __syncthreads();
  int oc = (wv << 6) + lane;
  float4v a0 = {0.f, 0.f, 0.f, 0.f}, a1 = a0, a2 = a0, a3 = a0;
  for (int c = 0; c < 64; ++c) {
    float w = wt[(c << 8) + oc];
    const float4v* xr = (const float4v*)&xb[c][0];
    a0 += w * xr[0];
    a1 += w * xr[1];
    a2 += w * xr[2];
    a3 += w * xr[3];
  }
  float acc[16];
  *(float4v*)&acc[0] = a0;
  *(float4v*)&acc[4] = a1;
  *(float4v*)&acc[8] = a2;
  *(float4v*)&acc[12] = a3;
  float* dst = (oc < 128) ? xxin : z;
  int oco = (oc < 128) ? oc : (oc - 128);
#pragma unroll
  for (int p = 0; p < 16; ++p) dst[((pi0 + p) << 7) + oco] = acc[p];
}

// depthwise 3x3 SAME + bias + silu on NHWC [bl][p][128]
__global__ __launch_bounds__(256) void dwconv_kernel(const float* __restrict__ xx,
                                                     const float* __restrict__ w,
                                                     const float* __restrict__ b,
                                                     float* __restrict__ out) {
  size_t gid = (size_t)blockIdx.x * 256 + threadIdx.x;
  int d = gid & 127;
  size_t pi = gid >> 7;
  int p = (int)(pi & 4095);
  int bl = (int)(pi >> 12);
  int h = p >> 6, wq = p & 63;
  float acc = b[d];
  const float* wr = w + d * 9;
#pragma unroll
  for (int dy = -1; dy <= 1; ++dy) {
    int hh = h + dy;
    if (hh < 0 || hh >= 64) continue;
#pragma unroll
    for (int dx = -1; dx <= 1; ++dx) {
      int ww = wq + dx;
      if (ww < 0 || ww >= 64) continue;
      acc += wr[(dy + 1) * 3 + (dx + 1)] * xx[(((size_t)bl << 12) + (hh << 6) + ww) * 128 + d];
    }
  }
  out[pi * 128 + d] = silu(acc);
}

// x_dbl[bk][c][l] = sum_d xpw[k][c][d] * xs[bk][d][l]
__global__ __launch_bounds__(256) void xdbl_kernel(const float* __restrict__ xxc,
                                                   const float* __restrict__ xpw,
                                                   float* __restrict__ xdbl) {
  int bi = blockIdx.x;
  int lt = bi & 63;
  int k = (bi >> 6) & 3;
  int bl = bi >> 8;
  int lbase = lt << 6;
  __shared__ float lds[64][132];
  int t = threadIdx.x;
  for (int idx = t; idx < 64 * 128; idx += 256) {
    int i = idx >> 7, d = idx & 127;
    int pos = map_pos(k, lbase + i);
    lds[i][d] = xxc[((size_t)bl * NHW + pos) * 128 + d];
  }
  __syncthreads();
  for (int oi = t; oi < 36 * 64; oi += 256) {
    int c = oi >> 6, l = oi & 63;
    const float* wrow = xpw + (k * 36 + c) * 128;
    float acc = 0.f;
    for (int d4 = 0; d4 < 32; ++d4) {
      float4 w4 = *(const float4*)&wrow[d4 << 2];
      float4 x4 = *(const float4*)&lds[l][d4 << 2];
      acc += w4.x * x4.x + w4.y * x4.y + w4.z * x4.z + w4.w * x4.w;
    }
    xdbl[(((size_t)(bl * 4 + k)) * 36 + c) * (size_t)NL + lbase + l] = acc;
  }
}

// ---- chunked selective scan ----
// grid = 24 bk * 128 chunks; block 128 (one thread per d).
__global__ __launch_bounds__(128) void scan_pass1_kernel(const float* __restrict__ xdbl,
                                                         const float* __restrict__ xxc,
                                                         const float* __restrict__ dtw,
                                                         const float* __restrict__ dtb,
                                                         const float* __restrict__ Alog,
                                                         float* __restrict__ chunkP,
                                                         float* __restrict__ chunkH) {
  int bi = blockIdx.x;
  int chunk = bi & (NCH - 1);
  int bk = bi >> 7;
  int k = bk & 3, bl = bk >> 2;
  int d = threadIdx.x;
  float4 wv = *(const float4*)(dtw + (size_t)(((k << 7) + d) << 2));
  float bias = dtb[(k << 7) + d];
  const float* ar = Alog + (size_t)(((k << 7) + d) << 4);
  float a1v = -__expf(ar[0]) * 1.44269504f;
  bool geom = true;
#pragma unroll
  for (int n = 1; n < 16; ++n) {
    float an = -__expf(ar[n]) * 1.44269504f;
    geom = geom && (fabsf(an - (float)(n + 1) * a1v) <= 1e-3f * fabsf((float)(n + 1) * a1v) + 1e-6f);
  }
  __shared__ float xd[SCLEN][20];
  int l0 = chunk << 5;
  for (int idx = threadIdx.x; idx < 20 * SCLEN; idx += 128) {
    int c = idx >> 5, li = idx & 31;
    xd[li][c] = xdbl[((size_t)bk * 36 + c) * (size_t)NL + l0 + li];
  }
  __syncthreads();
  const float* uB = xxc + ((size_t)bl << 19) + d;
  float4v h0 = {0.f, 0.f, 0.f, 0.f}, h1 = h0, h2 = h0, h3 = h0;
  float sdt = 0.f;
  float u_nxt = uB[(size_t)map_pos(k, l0) << 7];
  if (geom) {
    for (int li = 0; li < SCLEN; ++li) {
      float u = u_nxt;
      int nl = (li < SCLEN - 1) ? (li + 1) : (SCLEN - 1);
      u_nxt = uB[(size_t)map_pos(k, l0 + nl) << 7];
      const float4v* row = (const float4v*)&xd[li][0];
      float4v q0 = row[0];
      float accq = bias + wv.x * q0[0] + wv.y * q0[1] + wv.z * q0[2] + wv.w * q0[3];
      float dt = softplus_fast(accq);
      float dtu = dt * u;
      sdt += dt;
      float4v b0 = row[1], b1 = row[2], b2 = row[3], b3 = row[4];
      float4v e0, e1, e2, e3;
      pow_tree(exp2f(a1v * dt), e0, e1, e2, e3);
      h0 = e0 * h0 + dtu * b0;
      h1 = e1 * h1 + dtu * b1;
      h2 = e2 * h2 + dtu * b2;
      h3 = e3 * h3 + dtu * b3;
    }
  } else {
    float4v a0v, a1q, a2q, a3q;
#pragma unroll
    for (int j = 0; j < 4; ++j) {
      a0v[j] = -__expf(ar[j]) * 1.44269504f;
      a1q[j] = -__expf(ar[4 + j]) * 1.44269504f;
      a2q[j] = -__expf(ar[8 + j]) * 1.44269504f;
      a3q[j] = -__expf(ar[12 + j]) * 1.44269504f;
    }
    for (int li = 0; li < SCLEN; ++li) {
      float u = u_nxt;
      int nl = (li < SCLEN - 1) ? (li + 1) : (SCLEN - 1);
      u_nxt = uB[(size_t)map_pos(k, l0 + nl) << 7];
      const float4v* row = (const float4v*)&xd[li][0];
      float4v q0 = row[0];
      float accq = bias + wv.x * q0[0] + wv.y * q0[1] + wv.z * q0[2] + wv.w * q0[3];
      float dt = softplus_fast(accq);
      float dtu = dt * u;
      sdt += dt;
      float4v b0 = row[1], b1 = row[2], b2 = row[3], b3 = row[4];
      float4v e0, e1, e2, e3;
#pragma unroll
      for (int j = 0; j < 4; ++j) {
        e0[j] = exp2f(a0v[j] * dt);
        e1[j] = exp2f(a1q[j] * dt);
        e2[j] = exp2f(a2q[j] * dt);
        e3[j] = exp2f(a3q[j] * dt);
      }
      h0 = e0 * h0 + dtu * b0;
      h1 = e1 * h1 + dtu * b1;
      h2 = e2 * h2 + dtu * b2;
      h3 = e3 * h3 + dtu * b3;
    }
  }
  size_t base = (size_t)chunk * NSTATE + (((size_t)bk << 7) + (size_t)d) * 16;
  float4v p0, p1, p2, p3;
  if (geom) {
    pow_tree(exp2f(a1v * sdt), p0, p1, p2, p3);
  } else {
#pragma unroll
    for (int j = 0; j < 4; ++j) {
      p0[j] = exp2f(-__expf(ar[j]) * 1.44269504f * sdt);
      p1[j] = exp2f(-__expf(ar[4 + j]) * 1.44269504f * sdt);
      p2[j] = exp2f(-__expf(ar[8 + j]) * 1.44269504f * sdt);
      p3[j] = exp2f(-__expf(ar[12 + j]) * 1.44269504f * sdt);
    }
  }
  *(float4v*)&chunkP[base + 0] = p0;
  *(float4v*)&chunkP[base + 4] = p1;
  *(float4v*)&chunkP[base + 8] = p2;
  *(float4v*)&chunkP[base + 12] = p3;
  *(float4v*)&chunkH[base + 0] = h0;
  *(float4v*)&chunkH[base + 4] = h1;
  *(float4v*)&chunkH[base + 8] = h2;
  *(float4v*)&chunkH[base + 12] = h3;
}

__global__ __launch_bounds__(256) void scan_pass2_kernel(const float* __restrict__ chunkP,
                                                         const float* __restrict__ chunkH,
                                                         float* __restrict__ chunkHS) {
  size_t state = (size_t)blockIdx.x * 256 + threadIdx.x;
  float h = 0.f;
#pragma unroll 4
  for (int j = 0; j < NCH; ++j) {
    size_t idx = (size_t)j * NSTATE + state;
    chunkHS[idx] = h;
    h = chunkP[idx] * h + chunkH[idx];
  }
}

__global__ __launch_bounds__(128) void scan_pass3_kernel(const float* __restrict__ xdbl,
                                                         const float* __restrict__ xxc,
                                                         const float* __restrict__ dtw,
                                                         const float* __restrict__ dtb,
                                                         const float* __restrict__ Alog,
                                                         const float* __restrict__ chunkHS,
                                                         float* __restrict__ ys) {
  int bi = blockIdx.x;
  int chunk = bi & (NCH - 1);
  int bk = bi >> 7;
  int k = bk & 3, bl = bk >> 2;
  int d = threadIdx.x;
  float4 wv = *(const float4*)(dtw + (size_t)(((k << 7) + d) << 2));
  float bias = dtb[(k << 7) + d];
  const float* ar = Alog + (size_t)(((k << 7) + d) << 4);
  float a1v = -__expf(ar[0]) * 1.44269504f;
  bool geom = true;
#pragma unroll
  for (int n = 1; n < 16; ++n) {
    float an = -__expf(ar[n]) * 1.44269504f;
    geom = geom && (fabsf(an - (float)(n + 1) * a1v) <= 1e-3f * fabsf((float)(n + 1) * a1v) + 1e-6f);
  }
  __shared__ float xd[SCLEN][36];
  int l0 = chunk << 5;
  for (int idx = threadIdx.x; idx < 36 * SCLEN; idx += 128) {
    int c = idx >> 5, li = idx & 31;
    xd[li][c] = xdbl[((size_t)bk * 36 + c) * (size_t)NL + l0 + li];
  }
  __syncthreads();
  const float* uB = xxc + ((size_t)bl << 19) + d;
  float* yB = ys + ((size_t)bk << 19) + d;
  size_t base = (size_t)chunk * NSTATE + (((size_t)bk << 7) + (size_t)d) * 16;
  float4v h0 = *(const float4v*)&chunkHS[base + 0];
  float4v h1 = *(const float4v*)&chunkHS[base + 4];
  float4v h2 = *(const float4v*)&chunkHS[base + 8];
  float4v h3 = *(const float4v*)&chunkHS[base + 12];
  float u_nxt = uB[(size_t)map_pos(k, l0) << 7];
  if (geom) {
    for (int li = 0; li < SCLEN; ++li) {
      float u = u_nxt;
      int nl = (li < SCLEN - 1) ? (li + 1) : (SCLEN - 1);
      u_nxt = uB[(size_t)map_pos(k, l0 + nl) << 7];
      const float4v* row = (const float4v*)&xd[li][0];
      float4v q0 = row[0];
      float accq = bias + wv.x * q0[0] + wv.y * q0[1] + wv.z * q0[2] + wv.w * q0[3];
      float dt = softplus_fast(accq);
      float dtu = dt * u;
      float4v b0 = row[1], b1 = row[2], b2 = row[3], b3 = row[4];
      float4v c0 = row[5], c1 = row[6], c2 = row[7], c3 = row[8];
      float4v e0, e1, e2, e3;
      pow_tree(exp2f(a1v * dt), e0, e1, e2, e3);
      h0 = e0 * h0 + dtu * b0;
      h1 = e1 * h1 + dtu * b1;
      h2 = e2 * h2 + dtu * b2;
      h3 = e3 * h3 + dtu * b3;
      float4v sy = h0 * c0;
      sy += h1 * c1;
      sy += h2 * c2;
      sy += h3 * c3;
      yB[(size_t)(l0 + li) << 7] = (sy[0] + sy[1]) + (sy[2] + sy[3]);
    }
  } else {
    float4v a0v, a1q, a2q, a3q;
#pragma unroll
    for (int j = 0; j < 4; ++j) {
      a0v[j] = -__expf(ar[j]) * 1.44269504f;
      a1q[j] = -__expf(ar[4 + j]) * 1.44269504f;
      a2q[j] = -__expf(ar[8 + j]) * 1.44269504f;
      a3q[j] = -__expf(ar[12 + j]) * 1.44269504f;
    }
    for (int li = 0; li < SCLEN; ++li) {
      float u = u_nxt;
      int nl = (li < SCLEN - 1) ? (li + 1) : (SCLEN - 1);
      u_nxt = uB[(size_t)map_pos(k, l0 + nl) << 7];
      const float4v* row = (const float4v*)&xd[li][0];
      float4v q0 = row[0];
      float accq = bias + wv.x * q0[0] + wv.y * q0[1] + wv.z * q0[2] + wv.w * q0[3];
      float dt = softplus_fast(accq);
      float dtu = dt * u;
      float4v b0 = row[1], b1 = row[2], b2 = row[3], b3 = row[4];
      float4v c0 = row[5], c1 = row[6], c2 = row[7], c3 = row[8];
      float4v e0, e1, e2, e3;
#pragma unroll
      for (int j = 0; j < 4; ++j) {
        e0[j] = exp2f(a0v[j] * dt);
        e1[j] = exp2f(a1q[j] * dt);
        e2[j] = exp2f(a2q[j] * dt);
        e3[j] = exp2f(a3q[j] * dt);
      }
      h0 = e0 * h0 + dtu * b0;
      h1 = e1 * h1 + dtu * b1;
      h2 = e2 * h2 + dtu * b2;
      h3 = e3 * h3 + dtu * b3;
      float4v sy = h0 * c0;
      sy += h1 * c1;
      sy += h2 * c2;
      sy += h3 * c3;
      yB[(size_t)(l0 + li) << 7] = (sy[0] + sy[1]) + (sy[2] + sy[3]);
    }
  }
}

// ycomb[bl][p][d] = sum of 4 direction outputs (mapped) + xxc * sum_k Ds
__global__ __launch_bounds__(256) void combine_kernel(const float* __restrict__ ys,
                                                      const float* __restrict__ xxc,
                                                      const float* __restrict__ Ds,
                                                      float* __restrict__ ycomb) {
  size_t gid = (size_t)blockIdx.x * 256 + threadIdx.x;
  int d = gid & 127;
  size_t pi = gid >> 7;
  int p = (int)(pi & 4095);
  int bl = (int)(pi >> 12);
  int h = p >> 6, w = p & 63;
  int l1 = (w << 6) | h;
  size_t base = ((size_t)bl * 4) << 12;
  float v = ys[((base + p) << 7) + d]
          + ys[((base + 4096 + l1) << 7) + d]
          + ys[((base + 2 * 4096 + (4095 - p)) << 7) + d]
          + ys[((base + 3 * 4096 + (4095 - l1)) << 7) + d];
  float ds = Ds[d] + Ds[128 + d] + Ds[256 + d] + Ds[384 + d];
  v += xxc[(pi << 7) + d] * ds;
  ycomb[(pi << 7) + d] = v;
}

// out_norm LN(128) -> *silu(z) -> out_proj wt[c(128)][oc(64)] -> + x_res; 16 pos/block
__global__ __launch_bounds__(256) void outproj_kernel(const float* __restrict__ ycomb,
                                                      const float* __restrict__ z,
                                                      const float* __restrict__ ong,
                                                      const float* __restrict__ onb,
                                                      const float* __restrict__ opwt,
                                                      const float* __restrict__ xres,
                                                      float* __restrict__ x1) {
  int wv = threadIdx.x >> 6, lane = threadIdx.x & 63;
  size_t pi0 = (size_t)blockIdx.x << 4;
  __shared__ float gb[128][16];
  float og0 = ong[lane], ob0 = onb[lane];
  float og1 = ong[64 + lane], ob1 = onb[64 + lane];
#pragma unroll
  for (int j = 0; j < 4; ++j) {
    int p = (wv << 2) + j;
    size_t pp = pi0 + p;
    float y0 = ycomb[(pp << 7) + lane], y1 = ycomb[(pp << 7) + 64 + lane];
    float s = wred64(y0 + y1);
    float s2 = wred64(y0 * y0 + y1 * y1);
    float m = s * (1.f / 128), var = s2 * (1.f / 128) - m * m;
    float rstd = rsqrtf(var + 1e-5f);
    float z0 = z[(pp << 7) + lane], z1 = z[(pp << 7) + 64 + lane];
    gb[lane][p] = ((y0 - m) * rstd * og0 + ob0) * silu(z0);
    gb[64 + lane][p] = ((y1 - m) * rstd * og1 + ob1) * silu(z1);
  }
  __syncthreads();
  int p0 = wv << 2;
  float4v acc = {0.f, 0.f, 0.f, 0.f};
  for (int c = 0; c < 128; ++c) {
    float w = opwt[(c << 6) + lane];
    acc += w * (*(const float4v*)&gb[c][p0]);
  }
  float accs[4];
  *(float4v*)&accs[0] = acc;
#pragma unroll
  for (int j = 0; j < 4; ++j) {
    size_t pp = pi0 + p0 + j;
    x1[pp * 64 + lane] = xres[pp * 64 + lane] + accs[j];
  }
}

// ln2 -> fc1 -> gelu(tanh) -> fc2 -> residual; 16 pos/block; wt[c][oc]
__global__ __launch_bounds__(256) void mlp_kernel(const float* __restrict__ x1,
                                                  const float* __restrict__ g2,
                                                  const float* __restrict__ b2,
                                                  const float* __restrict__ w1t,
                                                  const float* __restrict__ bb1,
                                                  const float* __restrict__ w2t,
                                                  const float* __restrict__ bb2,
                                                  float* __restrict__ x2) {
  int wv = threadIdx.x >> 6, lane = threadIdx.x & 63;
  size_t pi0 = (size_t)blockIdx.x << 4;
  __shared__ float xb[64][16], tb[64][16];
  float gv = g2[lane], bv = b2[lane];
  float xsave[4];
#pragma unroll
  for (int j = 0; j < 4; ++j) {
    int p = (wv << 2) + j;
    float xv = x1[(pi0 + p) * 64 + lane];
    xsave[j] = xv;
    float s = wred64(xv), s2 = wred64(xv * xv);
    float m = s * (1.f / 64), var = s2 * (1.f / 64) - m * m;
    float rstd = rsqrtf(var + 1e-5f);
    xb[lane][p] = (xv - m) * rstd * gv + bv;
  }
  __syncthreads();
  int p0 = wv << 2;
  float bb1v = bb1[lane];
  float4v acc = {bb1v, bb1v, bb1v, bb1v};
  for (int c = 0; c < 64; ++c) {
    float w = w1t[(c << 6) + lane];
    acc += w * (*(const float4v*)&xb[c][p0]);
  }
  float us[4];
  *(float4v*)&us[0] = acc;
#pragma unroll
  for (int j = 0; j < 4; ++j) {
    float u = us[j];
    float tt = tanhf(0.7978845608028654f * (u + 0.044715f * u * u * u));
    tb[lane][p0 + j] = 0.5f * u * (1.f + tt);
  }
  __syncthreads();
  float bb2v = bb2[lane];
  float4v acc2 = {bb2v, bb2v, bb2v, bb2v};
  for (int c = 0; c < 64; ++c) {
    float w = w2t[(c << 6) + lane];
    acc2 += w * (*(const float4v*)&tb[c][p0]);
  }
  float o2[4];
  *(float4v*)&o2[0] = acc2;
#pragma unroll
  for (int j = 0; j < 4; ++j)
    x2[(pi0 + p0 + j) * 64 + lane] = xsave[j] + o2[j];
}

// NHWC (bl,p,c) -> NCHW (bl,c,p) tiled transpose into d_out
__global__ __launch_bounds__(256) void transpose_out_kernel(const float* __restrict__ x2,
                                                            float* __restrict__ out) {
  int bi = blockIdx.x;
  int pt = bi & 127;
  int ct = (bi >> 7) & 1;
  int bl = bi >> 8;
  __shared__ float lds[32][33];
  int t = threadIdx.x;
  int j = t & 31, i0 = t >> 5;
  int p0 = pt << 5, c0 = ct << 5;
#pragma unroll
  for (int q = 0; q < 4; ++q) {
    int i = i0 + (q << 3);
    lds[i][j] = x2[((size_t)bl * NHW + p0 + i) * 64 + c0 + j];
  }
  __syncthreads();
#pragma unroll
  for (int q = 0; q < 4; ++q) {
    int i = i0 + (q << 3);
    out[((size_t)bl * 64 + c0 + i) * (size_t)NHW + p0 + j] = lds[j][i];
  }
}

extern "C" void kernel_launch(void* const* d_in, const int* in_sizes, int n_in,
                              void* d_out, int out_size, void* d_ws, size_t ws_size,
                              hipStream_t stream) {
  const float* img  = (const float*)d_in[0];
  const float* dz   = (const float*)d_in[1];
  const float* sg   = (const float*)d_in[2];
  const float* gn1g = (const float*)d_in[3];
  const float* gn1b = (const float*)d_in[4];
  const float* c1w  = (const float*)d_in[5];
  const float* c1b  = (const float*)d_in[6];
  const float* gn2g = (const float*)d_in[7];
  const float* gn2b = (const float*)d_in[8];
  const float* c2w  = (const float*)d_in[9];
  const float* c2b  = (const float*)d_in[10];
  const float* skw  = (const float*)d_in[11];
  const float* skb  = (const float*)d_in[12];
  const float* ln1g = (const float*)d_in[13];
  const float* ln1b = (const float*)d_in[14];
  const float* ln2g = (const float*)d_in[15];
  const float* ln2b = (const float*)d_in[16];
  const float* ipw  = (const float*)d_in[17];
  const float* dww  = (const float*)d_in[18];
  const float* dwb  = (const float*)d_in[19];
  const float* xpw  = (const float*)d_in[20];
  const float* dtw  = (const float*)d_in[21];
  const float* dtb  = (const float*)d_in[22];
  const float* Alog = (const float*)d_in[23];
  const float* Dsp  = (const float*)d_in[24];
  const float* ong  = (const float*)d_in[25];
  const float* onb  = (const float*)d_in[26];
  const float* opw  = (const float*)d_in[27];
  const float* f1w  = (const float*)d_in[28];
  const float* f1b  = (const float*)d_in[29];
  const float* f2w  = (const float*)d_in[30];
  const float* f2b  = (const float*)d_in[31];

  float* out = (float*)d_out;
  float* ws = (float*)d_ws;
  if (ws_size < F_TOTAL * sizeof(float)) return;

  float* xcat  = ws + F_XCAT;
  float* h1    = ws + F_H1;
  float* h2    = ws + F_H2;
  float* xres  = ws + F_XRES;
  float* xxin  = ws + F_XXIN;
  float* zbuf  = ws + F_Z;
  float* xxc   = ws + F_XXC;
  float* xdbl  = ws + F_XDBL;
  float* ysb   = ws + F_YS;
  float* ycomb = ws + F_YCOMB;
  float* x1    = ws + F_X1;
  float* x2    = ws + F_X2;
  float* stats = ws + F_STATS;
  ushortT* act1b = (ushortT*)(ws + F_ACT1);
  ushortT* act2b = (ushortT*)(ws + F_ACT2);
  // stats partials + conv weight packs live in X2 region (dead until mlp)
  double* part  = (double*)(ws + F_X2);              // 768 floats
  ushortT* wb1  = (ushortT*)(ws + F_X2 + 1024);      // 110592 ushorts
  ushortT* wb2  = wb1 + 110592;                      // 36864 ushorts
  // scan chunk arrays: P+H fill YS exactly (ys overwrites in pass3); HS in XCAT span
  float* chunkP  = ws + F_YS;                        // 6,291,456
  float* chunkH  = ws + F_YS + 6291456;              // 6,291,456
  float* chunkHS = ws + F_XCAT;                      // 6,291,456 (XCAT+ACT1, dead after inproj)
  // transposed small-GEMM weights
  float* wt_sk = ws + F_ACT1;                        // dead after skip
  float* wt_ip = ws + F_XCAT;                        // dead after inproj
  float* wt_op = ws + F_XXIN;                        // XXIN dead after dwconv
  float* wt_f1 = ws + F_XXIN + 8192;
  float* wt_f2 = ws + F_XXIN + 12288;

  // conv weight prepacks (no deps)
  wprep_kernel<<<432, 256, 0, stream>>>(c1w, wb1, NC3, 6);
  wprep_kernel<<<144, 256, 0, stream>>>(c2w, wb2, NC, 2);
  // stage 0: instance-norm stats
  stats1_kernel<<<NBL * 32, 256, 0, stream>>>(img, NC * NHW, part);
  stats2_kernel<<<NBL, 64, 0, stream>>>(part, NC * NHW, stats + 0, stats + 8);
  build_xcat_kernel<<<18432, 256, 0, stream>>>(img, dz, sg, stats, xcat);
  // gn1 + silu -> NHWC bf16
  stats1_kernel<<<NBL * 32, 256, 0, stream>>>(xcat, NC3 * NHW, part);
  stats2_kernel<<<NBL, 64, 0, stream>>>(part, NC3 * NHW, stats + 16, stats + 24);
  gnsilu_t_kernel<NC3><<<NBL * 64, 256, 0, stream>>>(xcat, gn1g, gn1b, stats + 16, act1b);
  conv_mfma_kernel<NC3><<<NBL * 64 * 2, 256, 0, stream>>>(act1b, wb1, c1b, h1);
  wtrans_kernel<<<48, 256, 0, stream>>>(skw, wt_sk, 64, 192);
  // gn2 + silu -> NHWC bf16
  stats1_kernel<<<NBL * 32, 256, 0, stream>>>(h1, NC * NHW, part);
  stats2_kernel<<<NBL, 64, 0, stream>>>(part, NC * NHW, stats + 32, stats + 40);
  gnsilu_t_kernel<NC><<<NBL * 64, 256, 0, stream>>>(h1, gn2g, gn2b, stats + 32, act2b);
  conv_mfma_kernel<NC><<<NBL * 64 * 2, 256, 0, stream>>>(act2b, wb2, c2b, h2);
  // skip 1x1 + residual + NHWC transpose
  skip_kernel<<<NBL * 64, 256, 0, stream>>>(xcat, h2, wt_sk, skb, xres);
  wtrans_kernel<<<64, 256, 0, stream>>>(ipw, wt_ip, 256, 64);
  // SS2D
  inproj_kernel<<<1536, 256, 0, stream>>>(xres, ln1g, ln1b, wt_ip, xxin, zbuf);
  dwconv_kernel<<<12288, 256, 0, stream>>>(xxin, dww, dwb, xxc);
  wtrans_kernel<<<32, 256, 0, stream>>>(opw, wt_op, 64, 128);
  wtrans_kernel<<<16, 256, 0, stream>>>(f1w, wt_f1, 64, 64);
  wtrans_kernel<<<16, 256, 0, stream>>>(f2w, wt_f2, 64, 64);
  xdbl_kernel<<<NBL * NK * 64, 256, 0, stream>>>(xxc, xpw, xdbl);
  // chunked scan (128 chunks of 32)
  scan_pass1_kernel<<<24 * NCH, 128, 0, stream>>>(xdbl, xxc, dtw, dtb, Alog, chunkP, chunkH);
  scan_pass2_kernel<<<192, 256, 0, stream>>>(chunkP, chunkH, chunkHS);
  scan_pass3_kernel<<<24 * NCH, 128, 0, stream>>>(xdbl, xxc, dtw, dtb, Alog, chunkHS, ysb);
  combine_kernel<<<12288, 256, 0, stream>>>(ysb, xxc, Dsp, ycomb);
  outproj_kernel<<<1536, 256, 0, stream>>>(ycomb, zbuf, ong, onb, wt_op, xres, x1);
  // MLP + residual
  mlp_kernel<<<1536, 256, 0, stream>>>(x1, ln2g, ln2b, wt_f1, f1b, wt_f2, f2b, x2);
  // final transpose to NCHW output
  transpose_out_kernel<<<NBL * 256, 256, 0, stream>>>(x2, out);
}

// Round 10
// 355.054 us; speedup vs baseline: 3.2533x; 1.1379x over previous
//
#include <hip/hip_runtime.h>
#include <hip/hip_bf16.h>

typedef unsigned short ushortT;
typedef short short8v __attribute__((ext_vector_type(8)));
typedef float float4v __attribute__((ext_vector_type(4)));

// Problem constants
#define NBL 6      // B*LEN
#define NC 64
#define NC3 192
#define NHW 4096   // 64*64
#define NDI 128
#define NNS 16
#define NDR 4
#define NK 4
#define NL 4096
#define NCH 128    // scan chunks
#define SCLEN 32   // chunk length
#define NSTATE 49152  // 24 bk * 128 d * 16 n

// workspace offsets in floats
static const size_t F_XCAT  = 0;          // 4,718,592 (wt_ip after skip; chunkHS span during scan)
static const size_t F_ACT1  = 4718592;    // act1b bf16 NHWC; wt_sk after conv1; chunkHS tail
static const size_t F_H1    = 9437184;    // 1,572,864
static const size_t F_ACT2  = 11010048;   // act2b bf16 NHWC
static const size_t F_H2    = 12582912;   // 1,572,864
static const size_t F_XRES  = 14155776;   // 1,572,864
static const size_t F_XXIN  = 15728640;   // 3,145,728 (wt_op/f1/f2 after dwconv)
static const size_t F_Z     = 18874368;   // 3,145,728
static const size_t F_XXC   = 22020096;   // 3,145,728
static const size_t F_XDBL  = 25165824;   // 3,538,944
static const size_t F_YS    = 28704768;   // 12,582,912 (chunkP+chunkH during scan; ys after)
static const size_t F_YCOMB = 41287680;   // 3,145,728
static const size_t F_X1    = 44433408;   // 1,572,864
static const size_t F_X2    = 46006272;   // 1,572,864 (stats partials + conv wpacks early)
static const size_t F_STATS = 47579136;   // 48
static const size_t F_TOTAL = 47579184;   // floats (~190.3 MB)

__device__ __forceinline__ float wred64(float v) {
#pragma unroll
  for (int m = 32; m; m >>= 1) v += __shfl_xor(v, m, 64);
  return v;
}

__device__ __forceinline__ float silu(float v) {
  return v / (1.f + __expf(-v));
}

__device__ __forceinline__ ushortT f2bf(float f) {
  unsigned int u = __builtin_bit_cast(unsigned int, f);
  unsigned int r = (u + 0x7FFFu + ((u >> 16) & 1u)) >> 16;
  return (ushortT)r;
}

__device__ __forceinline__ int map_pos(int k, int l) {
  if (k == 0) return l;
  if (k == 1) return ((l & 63) << 6) | (l >> 6);
  if (k == 2) return 4095 - l;
  int lp = 4095 - l;
  return ((lp & 63) << 6) | (lp >> 6);
}

// softplus via hw exp2/log2: ln(1+e^a) = ln2 * log2(1 + 2^(a*log2e))
__device__ __forceinline__ float softplus_fast(float a) {
  float t = exp2f(a * 1.44269504f);
  float r = 0.69314718f * __log2f(1.f + t);
  return (a > 20.f) ? a : r;
}

// powers E^1..E^16 via mul tree (for geometric A: a_n = (n+1)*a_1)
__device__ __forceinline__ void pow_tree(float E1, float4v& e0, float4v& e1,
                                         float4v& e2, float4v& e3) {
  float E2 = E1 * E1, E3 = E2 * E1, E4 = E2 * E2;
  float E5 = E4 * E1, E6 = E4 * E2, E7 = E4 * E3, E8 = E4 * E4;
  e0[0] = E1; e0[1] = E2; e0[2] = E3; e0[3] = E4;
  e1[0] = E5; e1[1] = E6; e1[2] = E7; e1[3] = E8;
  e2[0] = E8 * E1; e2[1] = E8 * E2; e2[2] = E8 * E3; e2[3] = E8 * E4;
  e3[0] = E8 * E5; e3[1] = E8 * E6; e3[2] = E8 * E7; e3[3] = E8 * E8;
}

// generic weight transpose: dst[c*O + o] = src[o*C + c]
__global__ __launch_bounds__(256) void wtrans_kernel(const float* __restrict__ src,
                                                     float* __restrict__ dst, int O, int C) {
  int id = blockIdx.x * 256 + threadIdx.x;
  if (id >= O * C) return;
  int c = id / O, o = id % O;
  dst[id] = src[o * C + c];
}

// ---- two-stage per-sample mean/rstd (f64 accumulate) ----
__global__ __launch_bounds__(256) void stats1_kernel(const float* __restrict__ in, int n,
                                                     double* __restrict__ part) {
  int bi = blockIdx.x;
  int s = bi >> 5, j = bi & 31;
  int slice = n >> 5;
  const float4* p = (const float4*)(in + (size_t)s * n + (size_t)j * slice);
  int n4 = slice >> 2;
  double dsum = 0.0, dsq = 0.0;
  for (int i = threadIdx.x; i < n4; i += 256) {
    float4 v = p[i];
    dsum += (double)((v.x + v.y) + (v.z + v.w));
    dsq += (double)v.x * v.x + (double)v.y * v.y + (double)v.z * v.z + (double)v.w * v.w;
  }
  __shared__ double s1[256], s2[256];
  s1[threadIdx.x] = dsum; s2[threadIdx.x] = dsq;
  __syncthreads();
  for (int off = 128; off; off >>= 1) {
    if (threadIdx.x < off) { s1[threadIdx.x] += s1[threadIdx.x + off]; s2[threadIdx.x] += s2[threadIdx.x + off]; }
    __syncthreads();
  }
  if (threadIdx.x == 0) { part[2 * bi] = s1[0]; part[2 * bi + 1] = s2[0]; }
}

__global__ __launch_bounds__(64) void stats2_kernel(const double* __restrict__ part, int n,
                                                    float* __restrict__ mean_out,
                                                    float* __restrict__ rstd_out) {
  int s = blockIdx.x;
  int lane = threadIdx.x;
  double sum = 0.0, sq = 0.0;
  if (lane < 32) { sum = part[2 * (s * 32 + lane)]; sq = part[2 * (s * 32 + lane) + 1]; }
#pragma unroll
  for (int m = 16; m; m >>= 1) { sum += __shfl_xor(sum, m, 64); sq += __shfl_xor(sq, m, 64); }
  if (lane == 0) {
    double mean = sum / n;
    double var = sq / n - mean * mean;
    mean_out[s] = (float)mean;
    rstd_out[s] = (float)(1.0 / sqrt(var + 1e-5));
  }
}

// x_cat[bl][ch][p]: ch<64 dz, 64..127 instance-normed img, 128..191 sigma
__global__ __launch_bounds__(256) void build_xcat_kernel(const float* __restrict__ img,
                                                         const float* __restrict__ dz,
                                                         const float* __restrict__ sg,
                                                         const float* __restrict__ stats,
                                                         float* __restrict__ xcat) {
  size_t gid = (size_t)blockIdx.x * 256 + threadIdx.x;
  int p = gid & 4095;
  size_t r = gid >> 12;
  int ch = (int)(r % NC3);
  int bl = (int)(r / NC3);
  int b = bl / 3;
  float v;
  if (ch < 64) {
    v = dz[((size_t)b * NC + ch) * NHW + p];
  } else if (ch < 128) {
    float m = stats[bl], rs = stats[8 + bl];
    v = (img[((size_t)bl * NC + (ch - 64)) * NHW + p] - m) * rs;
  } else {
    v = sg[((size_t)b * NC + (ch - 128)) * NHW + p];
  }
  xcat[gid] = v;
}

// GN + SiLU + NCHW->NHWC transpose + f32->bf16. grid NBL*64, block 256.
template <int CCH>
__global__ __launch_bounds__(256) void gnsilu_t_kernel(const float* __restrict__ in,
                                                       const float* __restrict__ g,
                                                       const float* __restrict__ b,
                                                       const float* __restrict__ stats,
                                                       ushortT* __restrict__ outb) {
  int bi = blockIdx.x;
  int bl = bi >> 6, h = bi & 63;
  __shared__ ushortT tile[CCH][66];
  float m = stats[bl], rs = stats[8 + bl];
  int t = threadIdx.x;
  for (int idx = t; idx < CCH * 64; idx += 256) {
    int ch = idx >> 6, w = idx & 63;
    float v = in[(((size_t)bl * CCH + ch) << 12) + (h << 6) + w];
    v = (v - m) * rs * g[ch] + b[ch];
    v = silu(v);
    tile[ch][w] = f2bf(v);
  }
  __syncthreads();
  constexpr int C8 = CCH / 8;
  for (int idx = t; idx < 64 * C8; idx += 256) {
    int w = idx / C8, c8 = idx % C8;
    short8v v;
#pragma unroll
    for (int j = 0; j < 8; ++j) v[j] = (short)tile[c8 * 8 + j][w];
    *(short8v*)&outb[(size_t)(bl * 4096 + h * 64 + w) * CCH + c8 * 8] = v;
  }
}

// Pre-pack conv weights into per-lane MFMA B-fragments (bf16).
__global__ __launch_bounds__(256) void wprep_kernel(const float* __restrict__ w,
                                                    ushortT* __restrict__ out,
                                                    int CIN, int KT) {
  int id = blockIdx.x * 256 + threadIdx.x;
  int j = id & 7;
  int lane = (id >> 3) & 63;
  int nt = (id >> 9) & 3;
  int rest = id >> 11;
  int kt = rest % KT;
  int tap = rest / KT;
  int oc = nt * 16 + (lane & 15);
  int ic = kt * 32 + ((lane >> 4) << 3) + j;
  int r = tap / 3, s = tap % 3;
  out[id] = f2bf(w[(((size_t)oc * CIN + ic) * 3 + r) * 3 + s]);
}

// Implicit-GEMM 3x3 SAME conv via bf16 MFMA, f32 accumulate.
template <int CIN>
__global__ __launch_bounds__(256) void conv_mfma_kernel(const ushortT* __restrict__ actb,
                                                        const ushortT* __restrict__ wb,
                                                        const float* __restrict__ bias,
                                                        float* __restrict__ out) {
  constexpr int KT = CIN / 32;
  constexpr int STRIDE = CIN + 8;
  constexpr int C8 = CIN / 8;
  int bi = blockIdx.x;
  int nh = bi & 1;
  int h = (bi >> 1) & 63;
  int bl = bi >> 7;
  int t = threadIdx.x;
  int wv = t >> 6, lane = t & 63;
  __shared__ ushortT lds[66 * STRIDE];
  float4v acc0 = {0.f, 0.f, 0.f, 0.f};
  float4v acc1 = {0.f, 0.f, 0.f, 0.f};
  int lrow = lane & 15;
  int lk = (lane >> 4) << 3;
  for (int dy = 0; dy < 3; ++dy) {
    int hh = h + dy - 1;
    bool valid = (hh >= 0) && (hh < 64);
    int hc = valid ? hh : 0;
    if (dy) __syncthreads();
    const ushortT* src = actb + (size_t)(bl * 4096 + hc * 64) * CIN;
    for (int idx = t; idx < 64 * C8; idx += 256) {
      int w = idx / C8, c8 = idx % C8;
      short8v v = {0, 0, 0, 0, 0, 0, 0, 0};
      if (valid) v = *(const short8v*)&src[(size_t)w * CIN + c8 * 8];
      *(short8v*)&lds[(w + 1) * STRIDE + c8 * 8] = v;
    }
    if (t < 2 * C8) {
      int which = t / C8, c8 = t % C8;
      short8v z = {0, 0, 0, 0, 0, 0, 0, 0};
      *(short8v*)&lds[(which ? 65 : 0) * STRIDE + c8 * 8] = z;
    }
    __syncthreads();
    for (int dx = 0; dx < 3; ++dx) {
      int tap = dy * 3 + dx;
      int wl = (wv << 4) + lrow + dx;
#pragma unroll
      for (int kt = 0; kt < KT; ++kt) {
        short8v a = *(const short8v*)&lds[wl * STRIDE + kt * 32 + lk];
        const ushortT* wp = wb + ((size_t)(((tap * KT + kt) * 4 + (nh << 1)) * 64 + lane) << 3);
        short8v b0 = *(const short8v*)&wp[0];
        short8v b1 = *(const short8v*)&wp[512];
        acc0 = __builtin_amdgcn_mfma_f32_16x16x32_bf16(a, b0, acc0, 0, 0, 0);
        acc1 = __builtin_amdgcn_mfma_f32_16x16x32_bf16(a, b1, acc1, 0, 0, 0);
      }
    }
  }
  int oc0 = (nh << 5) + lrow;
  int oc1 = oc0 + 16;
  int w0 = (wv << 4) + ((lane >> 4) << 2);
  float bv0 = bias[oc0], bv1 = bias[oc1];
  float4 o0 = make_float4(acc0[0] + bv0, acc0[1] + bv0, acc0[2] + bv0, acc0[3] + bv0);
  float4 o1 = make_float4(acc1[0] + bv1, acc1[1] + bv1, acc1[2] + bv1, acc1[3] + bv1);
  *(float4*)&out[(((size_t)bl * 64 + oc0) << 12) + (h << 6) + w0] = o0;
  *(float4*)&out[(((size_t)bl * 64 + oc1) << 12) + (h << 6) + w0] = o1;
}

// x_res[bl][p][oc] = h2[bl][oc][p] + 1x1skip(xcat)[oc] + skb[oc]   (NHWC out)
__global__ __launch_bounds__(256) void skip_kernel(const float* __restrict__ xcat,
                                                   const float* __restrict__ h2,
                                                   const float* __restrict__ skwt,
                                                   const float* __restrict__ skb,
                                                   float* __restrict__ xres) {
  int bi = blockIdx.x;
  int bl = bi >> 6, h = bi & 63;
  int t = threadIdx.x;
  int oc = t & 63, w0 = (t >> 6) << 4;
  __shared__ float lds[64][64];
  float acc[16];
#pragma unroll
  for (int i = 0; i < 16; ++i) acc[i] = 0.f;
  for (int cc = 0; cc < 3; ++cc) {
    __syncthreads();
    for (int idx = t; idx < 4096; idx += 256) {
      int ch = idx >> 6, w = idx & 63;
      lds[ch][w] = xcat[(((size_t)bl * NC3 + cc * 64 + ch) << 12) + (h << 6) + w];
    }
    __syncthreads();
    for (int ch = 0; ch < 64; ++ch) {
      float wv = skwt[((cc << 6) + ch) * 64 + oc];
#pragma unroll
      for (int i = 0; i < 16; ++i) acc[i] += wv * lds[ch][w0 + i];
    }
  }
  float bv = skb[oc];
  int p0 = (h << 6) + w0;
#pragma unroll
  for (int i = 0; i < 16; ++i) {
    float hv = h2[(((size_t)bl * 64 + oc) << 12) + p0 + i];
    xres[((size_t)bl * NHW + p0 + i) * 64 + oc] = acc[i] + bv + hv;
  }
}

// LN(ln1) + 64->256 proj; 16 positions per block; wt[c(64)][oc(256)]. grid 1536.
__global__ __launch_bounds__(256) void inproj_kernel(const float* __restrict__ xres,
                                                     const float* __restrict__ g,
                                                     const float* __restrict__ b,
                                                     const float* __restrict__ wt,
                                                     float* __restrict__ xxin,
                                                     float* __restrict__ z) {
  int wv = threadIdx.x >> 6, lane = threadIdx.x & 63;
  size_t pi0 = (size_t)blockIdx.x << 4;
  __shared__ float xb[64][16];
  float gv = g[lane], bv = b[lane];
#pragma unroll
  for (int j = 0; j < 4; ++j) {
    int p = (wv << 2) + j;
    float x = xres[(pi0 + p) * 64 + lane];
    float s = wred64(x);
    float s2 = wred64(x * x);
    float m = s * (1.f / 64), var = s2 * (1.f / 64) - m * m;
    float rstd = rsqrtf(var + 1e-5f);
    xb[lane][p] = (x - m) * rstd * gv + bv;
  }
  __syncthreads();
  int oc = (wv << 6) + lane;
  float4v a0 = {0.f, 0.f, 0.f, 0.f}, a1 = a0, a2 = a0, a3 = a0;
  for (int c = 0; c < 64; ++c) {
    float w = wt[(c << 8) + oc];
    const float4v* xr = (const float4v*)&xb[c][0];
    a0 += w * xr[0];
    a1 += w * xr[1];
    a2 += w * xr[2];
    a3 += w * xr[3];
  }
  float acc[16];
  *(float4v*)&acc[0] = a0;
  *(float4v*)&acc[4] = a1;
  *(float4v*)&acc[8] = a2;
  *(float4v*)&acc[12] = a3;
  float* dst = (oc < 128) ? xxin : z;
  int oco = (oc < 128) ? oc : (oc - 128);
#pragma unroll
  for (int p = 0; p < 16; ++p) dst[((pi0 + p) << 7) + oco] = acc[p];
}

// depthwise 3x3 SAME + bias + silu on NHWC [bl][p][128]
__global__ __launch_bounds__(256) void dwconv_kernel(const float* __restrict__ xx,
                                                     const float* __restrict__ w,
                                                     const float* __restrict__ b,
                                                     float* __restrict__ out) {
  size_t gid = (size_t)blockIdx.x * 256 + threadIdx.x;
  int d = gid & 127;
  size_t pi = gid >> 7;
  int p = (int)(pi & 4095);
  int bl = (int)(pi >> 12);
  int h = p >> 6, wq = p & 63;
  float acc = b[d];
  const float* wr = w + d * 9;
#pragma unroll
  for (int dy = -1; dy <= 1; ++dy) {
    int hh = h + dy;
    if (hh < 0 || hh >= 64) continue;
#pragma unroll
    for (int dx = -1; dx <= 1; ++dx) {
      int ww = wq + dx;
      if (ww < 0 || ww >= 64) continue;
      acc += wr[(dy + 1) * 3 + (dx + 1)] * xx[(((size_t)bl << 12) + (hh << 6) + ww) * 128 + d];
    }
  }
  out[pi * 128 + d] = silu(acc);
}

// x_dbl via shared hw/wh tile; computes forward k and reversed k+2 per block.
// grid = NBL*2*64 (bl, korder, ltile); block 256 = 4 waves; lanes = 64 positions.
// Wave wv: k_w = korder + (wv>=2 ? 2 : 0), c range [ (wv&1)*18, +18 ).
__global__ __launch_bounds__(256) void xdbl_kernel(const float* __restrict__ xxc,
                                                   const float* __restrict__ xpw,
                                                   float* __restrict__ xdbl) {
  int bi = blockIdx.x;
  int lt = bi & 63;
  int korder = (bi >> 6) & 1;
  int bl = bi >> 7;
  int lbase = lt << 6;
  __shared__ float xs[64 * 128];  // row l (stride 128), slot-swizzled float4s
  int t = threadIdx.x;
#pragma unroll
  for (int it = 0; it < 8; ++it) {
    int idx = it * 256 + t;            // 2048 float4 = 64 rows x 32 slots
    int i = idx >> 5, d4 = idx & 31;
    int l = lbase + i;
    int pos = korder ? (((l & 63) << 6) | (l >> 6)) : l;
    float4 v = *(const float4*)&xxc[((size_t)bl * NHW + pos) * 128 + (d4 << 2)];
    int slot = d4 ^ (i & 7);
    *(float4*)&xs[i * 128 + (slot << 2)] = v;
  }
  __syncthreads();
  int wv = __builtin_amdgcn_readfirstlane(t >> 6);  // wave-uniform in SGPR
  int lane = t & 63;
  int k_w = korder + ((wv >= 2) ? 2 : 0);
  int c0 = (wv & 1) * 18;
  float acc[18];
#pragma unroll
  for (int j = 0; j < 18; ++j) acc[j] = 0.f;
  const float* wbase = xpw + (size_t)(k_w * 36 + c0) * 128;
  for (int d4 = 0; d4 < 32; ++d4) {
    int slot = d4 ^ (lane & 7);
    float4 x4 = *(const float4*)&xs[lane * 128 + (slot << 2)];
#pragma unroll
    for (int j = 0; j < 18; ++j) {
      float4 w4 = *(const float4*)&wbase[j * 128 + (d4 << 2)];
      acc[j] += w4.x * x4.x + w4.y * x4.y + w4.z * x4.z + w4.w * x4.w;
    }
  }
  int lout = (k_w < 2) ? (lbase + lane) : (4095 - lbase - lane);
  size_t obase = ((size_t)(bl * 4 + k_w) * 36 + c0) * (size_t)NL + lout;
#pragma unroll
  for (int j = 0; j < 18; ++j)
    xdbl[obase + (size_t)j * NL] = acc[j];
}

// ---- chunked selective scan ----
// grid = 24 bk * 128 chunks; block 128 (one thread per d).
__global__ __launch_bounds__(128) void scan_pass1_kernel(const float* __restrict__ xdbl,
                                                         const float* __restrict__ xxc,
                                                         const float* __restrict__ dtw,
                                                         const float* __restrict__ dtb,
                                                         const float* __restrict__ Alog,
                                                         float* __restrict__ chunkP,
                                                         float* __restrict__ chunkH) {
  int bi = blockIdx.x;
  int chunk = bi & (NCH - 1);
  int bk = bi >> 7;
  int k = bk & 3, bl = bk >> 2;
  int d = threadIdx.x;
  float4 wv = *(const float4*)(dtw + (size_t)(((k << 7) + d) << 2));
  float bias = dtb[(k << 7) + d];
  const float* ar = Alog + (size_t)(((k << 7) + d) << 4);
  float a1v = -__expf(ar[0]) * 1.44269504f;
  bool geom = true;
#pragma unroll
  for (int n = 1; n < 16; ++n) {
    float an = -__expf(ar[n]) * 1.44269504f;
    geom = geom && (fabsf(an - (float)(n + 1) * a1v) <= 1e-3f * fabsf((float)(n + 1) * a1v) + 1e-6f);
  }
  __shared__ float xd[SCLEN][20];
  int l0 = chunk << 5;
  for (int idx = threadIdx.x; idx < 20 * SCLEN; idx += 128) {
    int c = idx >> 5, li = idx & 31;
    xd[li][c] = xdbl[((size_t)bk * 36 + c) * (size_t)NL + l0 + li];
  }
  __syncthreads();
  const float* uB = xxc + ((size_t)bl << 19) + d;
  float4v h0 = {0.f, 0.f, 0.f, 0.f}, h1 = h0, h2 = h0, h3 = h0;
  float sdt = 0.f;
  float u_nxt = uB[(size_t)map_pos(k, l0) << 7];
  if (geom) {
    for (int li = 0; li < SCLEN; ++li) {
      float u = u_nxt;
      int nl = (li < SCLEN - 1) ? (li + 1) : (SCLEN - 1);
      u_nxt = uB[(size_t)map_pos(k, l0 + nl) << 7];
      const float4v* row = (const float4v*)&xd[li][0];
      float4v q0 = row[0];
      float accq = bias + wv.x * q0[0] + wv.y * q0[1] + wv.z * q0[2] + wv.w * q0[3];
      float dt = softplus_fast(accq);
      float dtu = dt * u;
      sdt += dt;
      float4v b0 = row[1], b1 = row[2], b2 = row[3], b3 = row[4];
      float4v e0, e1, e2, e3;
      pow_tree(exp2f(a1v * dt), e0, e1, e2, e3);
      h0 = e0 * h0 + dtu * b0;
      h1 = e1 * h1 + dtu * b1;
      h2 = e2 * h2 + dtu * b2;
      h3 = e3 * h3 + dtu * b3;
    }
  } else {
    float4v a0v, a1q, a2q, a3q;
#pragma unroll
    for (int j = 0; j < 4; ++j) {
      a0v[j] = -__expf(ar[j]) * 1.44269504f;
      a1q[j] = -__expf(ar[4 + j]) * 1.44269504f;
      a2q[j] = -__expf(ar[8 + j]) * 1.44269504f;
      a3q[j] = -__expf(ar[12 + j]) * 1.44269504f;
    }
    for (int li = 0; li < SCLEN; ++li) {
      float u = u_nxt;
      int nl = (li < SCLEN - 1) ? (li + 1) : (SCLEN - 1);
      u_nxt = uB[(size_t)map_pos(k, l0 + nl) << 7];
      const float4v* row = (const float4v*)&xd[li][0];
      float4v q0 = row[0];
      float accq = bias + wv.x * q0[0] + wv.y * q0[1] + wv.z * q0[2] + wv.w * q0[3];
      float dt = softplus_fast(accq);
      float dtu = dt * u;
      sdt += dt;
      float4v b0 = row[1], b1 = row[2], b2 = row[3], b3 = row[4];
      float4v e0, e1, e2, e3;
#pragma unroll
      for (int j = 0; j < 4; ++j) {
        e0[j] = exp2f(a0v[j] * dt);
        e1[j] = exp2f(a1q[j] * dt);
        e2[j] = exp2f(a2q[j] * dt);
        e3[j] = exp2f(a3q[j] * dt);
      }
      h0 = e0 * h0 + dtu * b0;
      h1 = e1 * h1 + dtu * b1;
      h2 = e2 * h2 + dtu * b2;
      h3 = e3 * h3 + dtu * b3;
    }
  }
  size_t base = (size_t)chunk * NSTATE + (((size_t)bk << 7) + (size_t)d) * 16;
  float4v p0, p1, p2, p3;
  if (geom) {
    pow_tree(exp2f(a1v * sdt), p0, p1, p2, p3);
  } else {
#pragma unroll
    for (int j = 0; j < 4; ++j) {
      p0[j] = exp2f(-__expf(ar[j]) * 1.44269504f * sdt);
      p1[j] = exp2f(-__expf(ar[4 + j]) * 1.44269504f * sdt);
      p2[j] = exp2f(-__expf(ar[8 + j]) * 1.44269504f * sdt);
      p3[j] = exp2f(-__expf(ar[12 + j]) * 1.44269504f * sdt);
    }
  }
  *(float4v*)&chunkP[base + 0] = p0;
  *(float4v*)&chunkP[base + 4] = p1;
  *(float4v*)&chunkP[base + 8] = p2;
  *(float4v*)&chunkP[base + 12] = p3;
  *(float4v*)&chunkH[base + 0] = h0;
  *(float4v*)&chunkH[base + 4] = h1;
  *(float4v*)&chunkH[base + 8] = h2;
  *(float4v*)&chunkH[base + 12] = h3;
}

__global__ __launch_bounds__(256) void scan_pass2_kernel(const float* __restrict__ chunkP,
                                                         const float* __restrict__ chunkH,
                                                         float* __restrict__ chunkHS) {
  size_t state = (size_t)blockIdx.x * 256 + threadIdx.x;
  float h = 0.f;
#pragma unroll 4
  for (int j = 0; j < NCH; ++j) {
    size_t idx = (size_t)j * NSTATE + state;
    chunkHS[idx] = h;
    h = chunkP[idx] * h + chunkH[idx];
  }
}

__global__ __launch_bounds__(128) void scan_pass3_kernel(const float* __restrict__ xdbl,
                                                         const float* __restrict__ xxc,
                                                         const float* __restrict__ dtw,
                                                         const float* __restrict__ dtb,
                                                         const float* __restrict__ Alog,
                                                         const float* __restrict__ chunkHS,
                                                         float* __restrict__ ys) {
  int bi = blockIdx.x;
  int chunk = bi & (NCH - 1);
  int bk = bi >> 7;
  int k = bk & 3, bl = bk >> 2;
  int d = threadIdx.x;
  float4 wv = *(const float4*)(dtw + (size_t)(((k << 7) + d) << 2));
  float bias = dtb[(k << 7) + d];
  const float* ar = Alog + (size_t)(((k << 7) + d) << 4);
  float a1v = -__expf(ar[0]) * 1.44269504f;
  bool geom = true;
#pragma unroll
  for (int n = 1; n < 16; ++n) {
    float an = -__expf(ar[n]) * 1.44269504f;
    geom = geom && (fabsf(an - (float)(n + 1) * a1v) <= 1e-3f * fabsf((float)(n + 1) * a1v) + 1e-6f);
  }
  __shared__ float xd[SCLEN][36];
  int l0 = chunk << 5;
  for (int idx = threadIdx.x; idx < 36 * SCLEN; idx += 128) {
    int c = idx >> 5, li = idx & 31;
    xd[li][c] = xdbl[((size_t)bk * 36 + c) * (size_t)NL + l0 + li];
  }
  __syncthreads();
  const float* uB = xxc + ((size_t)bl << 19) + d;
  float* yB = ys + ((size_t)bk << 19) + d;
  size_t base = (size_t)chunk * NSTATE + (((size_t)bk << 7) + (size_t)d) * 16;
  float4v h0 = *(const float4v*)&chunkHS[base + 0];
  float4v h1 = *(const float4v*)&chunkHS[base + 4];
  float4v h2 = *(const float4v*)&chunkHS[base + 8];
  float4v h3 = *(const float4v*)&chunkHS[base + 12];
  float u_nxt = uB[(size_t)map_pos(k, l0) << 7];
  if (geom) {
    for (int li = 0; li < SCLEN; ++li) {
      float u = u_nxt;
      int nl = (li < SCLEN - 1) ? (li + 1) : (SCLEN - 1);
      u_nxt = uB[(size_t)map_pos(k, l0 + nl) << 7];
      const float4v* row = (const float4v*)&xd[li][0];
      float4v q0 = row[0];
      float accq = bias + wv.x * q0[0] + wv.y * q0[1] + wv.z * q0[2] + wv.w * q0[3];
      float dt = softplus_fast(accq);
      float dtu = dt * u;
      float4v b0 = row[1], b1 = row[2], b2 = row[3], b3 = row[4];
      float4v c0 = row[5], c1 = row[6], c2 = row[7], c3 = row[8];
      float4v e0, e1, e2, e3;
      pow_tree(exp2f(a1v * dt), e0, e1, e2, e3);
      h0 = e0 * h0 + dtu * b0;
      h1 = e1 * h1 + dtu * b1;
      h2 = e2 * h2 + dtu * b2;
      h3 = e3 * h3 + dtu * b3;
      float4v sy = h0 * c0;
      sy += h1 * c1;
      sy += h2 * c2;
      sy += h3 * c3;
      yB[(size_t)(l0 + li) << 7] = (sy[0] + sy[1]) + (sy[2] + sy[3]);
    }
  } else {
    float4v a0v, a1q, a2q, a3q;
#pragma unroll
    for (int j = 0; j < 4; ++j) {
      a0v[j] = -__expf(ar[j]) * 1.44269504f;
      a1q[j] = -__expf(ar[4 + j]) * 1.44269504f;
      a2q[j] = -__expf(ar[8 + j]) * 1.44269504f;
      a3q[j] = -__expf(ar[12 + j]) * 1.44269504f;
    }
    for (int li = 0; li < SCLEN; ++li) {
      float u = u_nxt;
      int nl = (li < SCLEN - 1) ? (li + 1) : (SCLEN - 1);
      u_nxt = uB[(size_t)map_pos(k, l0 + nl) << 7];
      const float4v* row = (const float4v*)&xd[li][0];
      float4v q0 = row[0];
      float accq = bias + wv.x * q0[0] + wv.y * q0[1] + wv.z * q0[2] + wv.w * q0[3];
      float dt = softplus_fast(accq);
      float dtu = dt * u;
      float4v b0 = row[1], b1 = row[2], b2 = row[3], b3 = row[4];
      float4v c0 = row[5], c1 = row[6], c2 = row[7], c3 = row[8];
      float4v e0, e1, e2, e3;
#pragma unroll
      for (int j = 0; j < 4; ++j) {
        e0[j] = exp2f(a0v[j] * dt);
        e1[j] = exp2f(a1q[j] * dt);
        e2[j] = exp2f(a2q[j] * dt);
        e3[j] = exp2f(a3q[j] * dt);
      }
      h0 = e0 * h0 + dtu * b0;
      h1 = e1 * h1 + dtu * b1;
      h2 = e2 * h2 + dtu * b2;
      h3 = e3 * h3 + dtu * b3;
      float4v sy = h0 * c0;
      sy += h1 * c1;
      sy += h2 * c2;
      sy += h3 * c3;
      yB[(size_t)(l0 + li) << 7] = (sy[0] + sy[1]) + (sy[2] + sy[3]);
    }
  }
}

// ycomb[bl][p][d] = sum of 4 direction outputs (mapped) + xxc * sum_k Ds
__global__ __launch_bounds__(256) void combine_kernel(const float* __restrict__ ys,
                                                      const float* __restrict__ xxc,
                                                      const float* __restrict__ Ds,
                                                      float* __restrict__ ycomb) {
  size_t gid = (size_t)blockIdx.x * 256 + threadIdx.x;
  int d = gid & 127;
  size_t pi = gid >> 7;
  int p = (int)(pi & 4095);
  int bl = (int)(pi >> 12);
  int h = p >> 6, w = p & 63;
  int l1 = (w << 6) | h;
  size_t base = ((size_t)bl * 4) << 12;
  float v = ys[((base + p) << 7) + d]
          + ys[((base + 4096 + l1) << 7) + d]
          + ys[((base + 2 * 4096 + (4095 - p)) << 7) + d]
          + ys[((base + 3 * 4096 + (4095 - l1)) << 7) + d];
  float ds = Ds[d] + Ds[128 + d] + Ds[256 + d] + Ds[384 + d];
  v += xxc[(pi << 7) + d] * ds;
  ycomb[(pi << 7) + d] = v;
}

// out_norm LN(128) -> *silu(z) -> out_proj wt[c(128)][oc(64)] -> + x_res; 16 pos/block
__global__ __launch_bounds__(256) void outproj_kernel(const float* __restrict__ ycomb,
                                                      const float* __restrict__ z,
                                                      const float* __restrict__ ong,
                                                      const float* __restrict__ onb,
                                                      const float* __restrict__ opwt,
                                                      const float* __restrict__ xres,
                                                      float* __restrict__ x1) {
  int wv = threadIdx.x >> 6, lane = threadIdx.x & 63;
  size_t pi0 = (size_t)blockIdx.x << 4;
  __shared__ float gb[128][16];
  float og0 = ong[lane], ob0 = onb[lane];
  float og1 = ong[64 + lane], ob1 = onb[64 + lane];
#pragma unroll
  for (int j = 0; j < 4; ++j) {
    int p = (wv << 2) + j;
    size_t pp = pi0 + p;
    float y0 = ycomb[(pp << 7) + lane], y1 = ycomb[(pp << 7) + 64 + lane];
    float s = wred64(y0 + y1);
    float s2 = wred64(y0 * y0 + y1 * y1);
    float m = s * (1.f / 128), var = s2 * (1.f / 128) - m * m;
    float rstd = rsqrtf(var + 1e-5f);
    float z0 = z[(pp << 7) + lane], z1 = z[(pp << 7) + 64 + lane];
    gb[lane][p] = ((y0 - m) * rstd * og0 + ob0) * silu(z0);
    gb[64 + lane][p] = ((y1 - m) * rstd * og1 + ob1) * silu(z1);
  }
  __syncthreads();
  int p0 = wv << 2;
  float4v acc = {0.f, 0.f, 0.f, 0.f};
  for (int c = 0; c < 128; ++c) {
    float w = opwt[(c << 6) + lane];
    acc += w * (*(const float4v*)&gb[c][p0]);
  }
  float accs[4];
  *(float4v*)&accs[0] = acc;
#pragma unroll
  for (int j = 0; j < 4; ++j) {
    size_t pp = pi0 + p0 + j;
    x1[pp * 64 + lane] = xres[pp * 64 + lane] + accs[j];
  }
}

// ln2 -> fc1 -> gelu(tanh) -> fc2 -> residual; 16 pos/block; wt[c][oc]
__global__ __launch_bounds__(256) void mlp_kernel(const float* __restrict__ x1,
                                                  const float* __restrict__ g2,
                                                  const float* __restrict__ b2,
                                                  const float* __restrict__ w1t,
                                                  const float* __restrict__ bb1,
                                                  const float* __restrict__ w2t,
                                                  const float* __restrict__ bb2,
                                                  float* __restrict__ x2) {
  int wv = threadIdx.x >> 6, lane = threadIdx.x & 63;
  size_t pi0 = (size_t)blockIdx.x << 4;
  __shared__ float xb[64][16], tb[64][16];
  float gv = g2[lane], bv = b2[lane];
  float xsave[4];
#pragma unroll
  for (int j = 0; j < 4; ++j) {
    int p = (wv << 2) + j;
    float xv = x1[(pi0 + p) * 64 + lane];
    xsave[j] = xv;
    float s = wred64(xv), s2 = wred64(xv * xv);
    float m = s * (1.f / 64), var = s2 * (1.f / 64) - m * m;
    float rstd = rsqrtf(var + 1e-5f);
    xb[lane][p] = (xv - m) * rstd * gv + bv;
  }
  __syncthreads();
  int p0 = wv << 2;
  float bb1v = bb1[lane];
  float4v acc = {bb1v, bb1v, bb1v, bb1v};
  for (int c = 0; c < 64; ++c) {
    float w = w1t[(c << 6) + lane];
    acc += w * (*(const float4v*)&xb[c][p0]);
  }
  float us[4];
  *(float4v*)&us[0] = acc;
#pragma unroll
  for (int j = 0; j < 4; ++j) {
    float u = us[j];
    float tt = tanhf(0.7978845608028654f * (u + 0.044715f * u * u * u));
    tb[lane][p0 + j] = 0.5f * u * (1.f + tt);
  }
  __syncthreads();
  float bb2v = bb2[lane];
  float4v acc2 = {bb2v, bb2v, bb2v, bb2v};
  for (int c = 0; c < 64; ++c) {
    float w = w2t[(c << 6) + lane];
    acc2 += w * (*(const float4v*)&tb[c][p0]);
  }
  float o2[4];
  *(float4v*)&o2[0] = acc2;
#pragma unroll
  for (int j = 0; j < 4; ++j)
    x2[(pi0 + p0 + j) * 64 + lane] = xsave[j] + o2[j];
}

// NHWC (bl,p,c) -> NCHW (bl,c,p) tiled transpose into d_out
__global__ __launch_bounds__(256) void transpose_out_kernel(const float* __restrict__ x2,
                                                            float* __restrict__ out) {
  int bi = blockIdx.x;
  int pt = bi & 127;
  int ct = (bi >> 7) & 1;
  int bl = bi >> 8;
  __shared__ float lds[32][33];
  int t = threadIdx.x;
  int j = t & 31, i0 = t >> 5;
  int p0 = pt << 5, c0 = ct << 5;
#pragma unroll
  for (int q = 0; q < 4; ++q) {
    int i = i0 + (q << 3);
    lds[i][j] = x2[((size_t)bl * NHW + p0 + i) * 64 + c0 + j];
  }
  __syncthreads();
#pragma unroll
  for (int q = 0; q < 4; ++q) {
    int i = i0 + (q << 3);
    out[((size_t)bl * 64 + c0 + i) * (size_t)NHW + p0 + j] = lds[j][i];
  }
}

extern "C" void kernel_launch(void* const* d_in, const int* in_sizes, int n_in,
                              void* d_out, int out_size, void* d_ws, size_t ws_size,
                              hipStream_t stream) {
  const float* img  = (const float*)d_in[0];
  const float* dz   = (const float*)d_in[1];
  const float* sg   = (const float*)d_in[2];
  const float* gn1g = (const float*)d_in[3];
  const float* gn1b = (const float*)d_in[4];
  const float* c1w  = (const float*)d_in[5];
  const float* c1b  = (const float*)d_in[6];
  const float* gn2g = (const float*)d_in[7];
  const float* gn2b = (const float*)d_in[8];
  const float* c2w  = (const float*)d_in[9];
  const float* c2b  = (const float*)d_in[10];
  const float* skw  = (const float*)d_in[11];
  const float* skb  = (const float*)d_in[12];
  const float* ln1g = (const float*)d_in[13];
  const float* ln1b = (const float*)d_in[14];
  const float* ln2g = (const float*)d_in[15];
  const float* ln2b = (const float*)d_in[16];
  const float* ipw  = (const float*)d_in[17];
  const float* dww  = (const float*)d_in[18];
  const float* dwb  = (const float*)d_in[19];
  const float* xpw  = (const float*)d_in[20];
  const float* dtw  = (const float*)d_in[21];
  const float* dtb  = (const float*)d_in[22];
  const float* Alog = (const float*)d_in[23];
  const float* Dsp  = (const float*)d_in[24];
  const float* ong  = (const float*)d_in[25];
  const float* onb  = (const float*)d_in[26];
  const float* opw  = (const float*)d_in[27];
  const float* f1w  = (const float*)d_in[28];
  const float* f1b  = (const float*)d_in[29];
  const float* f2w  = (const float*)d_in[30];
  const float* f2b  = (const float*)d_in[31];

  float* out = (float*)d_out;
  float* ws = (float*)d_ws;
  if (ws_size < F_TOTAL * sizeof(float)) return;

  float* xcat  = ws + F_XCAT;
  float* h1    = ws + F_H1;
  float* h2    = ws + F_H2;
  float* xres  = ws + F_XRES;
  float* xxin  = ws + F_XXIN;
  float* zbuf  = ws + F_Z;
  float* xxc   = ws + F_XXC;
  float* xdbl  = ws + F_XDBL;
  float* ysb   = ws + F_YS;
  float* ycomb = ws + F_YCOMB;
  float* x1    = ws + F_X1;
  float* x2    = ws + F_X2;
  float* stats = ws + F_STATS;
  ushortT* act1b = (ushortT*)(ws + F_ACT1);
  ushortT* act2b = (ushortT*)(ws + F_ACT2);
  // stats partials + conv weight packs live in X2 region (dead until mlp)
  double* part  = (double*)(ws + F_X2);              // 768 floats
  ushortT* wb1  = (ushortT*)(ws + F_X2 + 1024);      // 110592 ushorts
  ushortT* wb2  = wb1 + 110592;                      // 36864 ushorts
  // scan chunk arrays: P+H fill YS exactly (ys overwrites in pass3); HS in XCAT span
  float* chunkP  = ws + F_YS;                        // 6,291,456
  float* chunkH  = ws + F_YS + 6291456;              // 6,291,456
  float* chunkHS = ws + F_XCAT;                      // 6,291,456 (XCAT+ACT1, dead after inproj)
  // transposed small-GEMM weights
  float* wt_sk = ws + F_ACT1;                        // dead after skip
  float* wt_ip = ws + F_XCAT;                        // dead after inproj
  float* wt_op = ws + F_XXIN;                        // XXIN dead after dwconv
  float* wt_f1 = ws + F_XXIN + 8192;
  float* wt_f2 = ws + F_XXIN + 12288;

  // conv weight prepacks (no deps)
  wprep_kernel<<<432, 256, 0, stream>>>(c1w, wb1, NC3, 6);
  wprep_kernel<<<144, 256, 0, stream>>>(c2w, wb2, NC, 2);
  // stage 0: instance-norm stats
  stats1_kernel<<<NBL * 32, 256, 0, stream>>>(img, NC * NHW, part);
  stats2_kernel<<<NBL, 64, 0, stream>>>(part, NC * NHW, stats + 0, stats + 8);
  build_xcat_kernel<<<18432, 256, 0, stream>>>(img, dz, sg, stats, xcat);
  // gn1 + silu -> NHWC bf16
  stats1_kernel<<<NBL * 32, 256, 0, stream>>>(xcat, NC3 * NHW, part);
  stats2_kernel<<<NBL, 64, 0, stream>>>(part, NC3 * NHW, stats + 16, stats + 24);
  gnsilu_t_kernel<NC3><<<NBL * 64, 256, 0, stream>>>(xcat, gn1g, gn1b, stats + 16, act1b);
  conv_mfma_kernel<NC3><<<NBL * 64 * 2, 256, 0, stream>>>(act1b, wb1, c1b, h1);
  wtrans_kernel<<<48, 256, 0, stream>>>(skw, wt_sk, 64, 192);
  // gn2 + silu -> NHWC bf16
  stats1_kernel<<<NBL * 32, 256, 0, stream>>>(h1, NC * NHW, part);
  stats2_kernel<<<NBL, 64, 0, stream>>>(part, NC * NHW, stats + 32, stats + 40);
  gnsilu_t_kernel<NC><<<NBL * 64, 256, 0, stream>>>(h1, gn2g, gn2b, stats + 32, act2b);
  conv_mfma_kernel<NC><<<NBL * 64 * 2, 256, 0, stream>>>(act2b, wb2, c2b, h2);
  // skip 1x1 + residual + NHWC transpose
  skip_kernel<<<NBL * 64, 256, 0, stream>>>(xcat, h2, wt_sk, skb, xres);
  wtrans_kernel<<<64, 256, 0, stream>>>(ipw, wt_ip, 256, 64);
  // SS2D
  inproj_kernel<<<1536, 256, 0, stream>>>(xres, ln1g, ln1b, wt_ip, xxin, zbuf);
  dwconv_kernel<<<12288, 256, 0, stream>>>(xxin, dww, dwb, xxc);
  wtrans_kernel<<<32, 256, 0, stream>>>(opw, wt_op, 64, 128);
  wtrans_kernel<<<16, 256, 0, stream>>>(f1w, wt_f1, 64, 64);
  wtrans_kernel<<<16, 256, 0, stream>>>(f2w, wt_f2, 64, 64);
  xdbl_kernel<<<NBL * 2 * 64, 256, 0, stream>>>(xxc, xpw, xdbl);
  // chunked scan (128 chunks of 32)
  scan_pass1_kernel<<<24 * NCH, 128, 0, stream>>>(xdbl, xxc, dtw, dtb, Alog, chunkP, chunkH);
  scan_pass2_kernel<<<192, 256, 0, stream>>>(chunkP, chunkH, chunkHS);
  scan_pass3_kernel<<<24 * NCH, 128, 0, stream>>>(xdbl, xxc, dtw, dtb, Alog, chunkHS, ysb);
  combine_kernel<<<12288, 256, 0, stream>>>(ysb, xxc, Dsp, ycomb);
  outproj_kernel<<<1536, 256, 0, stream>>>(ycomb, zbuf, ong, onb, wt_op, xres, x1);
  // MLP + residual
  mlp_kernel<<<1536, 256, 0, stream>>>(x1, ln2g, ln2b, wt_f1, f1b, wt_f2, f2b, x2);
  // final transpose to NCHW output
  transpose_out_kernel<<<NBL * 256, 256, 0, stream>>>(x2, out);
}